// Round 3
// baseline (18094.313 us; speedup 1.0000x reference)
//
#include <hip/hip_runtime.h>
#include <stdint.h>

#define NN 50000
#define NE 800000

// canonical bf16 weight-block element offsets
#define O_WIN 0
#define O_BIN 2048
#define O_WL  2176
#define O_BL  67712
#define O_WR  68224
#define O_LNG 133760
#define O_LNB 134272
#define O_W1  134784
#define O_B1  168576
#define O_W2  168704
#define O_B2  176896
#define O_W3  176960
#define O_B3  177024
#define W_TOTAL 177025

// ws layout (bytes)
#define WS_FLAGS 0
#define WS_WC    256
#define WS_DEG   354560
#define WS_HB    554752
#define WS_AGG   13354752
#define WS_NEED  38954752

__device__ __forceinline__ float b2f(unsigned short u) {
  union { unsigned int i; float f; } v; v.i = ((unsigned int)u) << 16; return v.f;
}
__device__ __forceinline__ unsigned short f2b(float f) {
  union { float f; unsigned int i; } v; v.f = f;
  return (unsigned short)((v.i + 0x7fffu + ((v.i >> 16) & 1u)) >> 16);
}

// ---------------- fallback diagnostic: ws too small → constant 0.5 ----------
__global__ void k_fallback(unsigned short* __restrict__ out) {
  int gid = blockIdx.x * 256 + threadIdx.x;
  if (gid < NE) out[gid] = 0x3F00;  // bf16 0.5
}

// ---------------- dtype probe: flags[0]=inputs are fp32, flags[1]=ei int64 --
__global__ void k_probe(const unsigned short* __restrict__ x_u,
                        const int* __restrict__ ei32, int* __restrict__ flags) {
  const int t = threadIdx.x;  // 64 threads, 1 wave
  int insane = 0;
  for (int i = t; i < 512; i += 64) {
    float v = b2f(x_u[i]);
    if (!(fabsf(v) < 1e4f)) insane++;  // NaN/Inf/huge all fail the compare
  }
#pragma unroll
  for (int off = 1; off < 64; off <<= 1) insane += __shfl_xor(insane, off, 64);
  int nz = 0;
  for (int i = t; i < 128; i += 64) nz |= (ei32[2 * i + 1] != 0);
  unsigned long long m = __ballot(nz != 0);
  if (t == 0) {
    flags[0] = (insane >= 16) ? 1 : 0;  // fp32 float tensors
    flags[1] = (m == 0ULL) ? 1 : 0;     // int64 edge_index
  }
}

// ---------------- canonicalize the 13 weight tensors to bf16 ----------------
__global__ void k_cvt_w(const void* W_in, const void* b_in, const void* Wl,
                        const void* bl, const void* Wr, const void* lng,
                        const void* lnb, const void* W1, const void* b1,
                        const void* W2, const void* b2, const void* W3,
                        const void* b3, unsigned short* __restrict__ wc,
                        const int* __restrict__ flags) {
  const int gid = blockIdx.x * 256 + threadIdx.x;
  if (gid >= W_TOTAL) return;
  const int f32 = flags[0];
  const void* src; int off;
  if      (gid < O_BIN) { src = W_in; off = gid - O_WIN; }
  else if (gid < O_WL)  { src = b_in; off = gid - O_BIN; }
  else if (gid < O_BL)  { src = Wl;   off = gid - O_WL;  }
  else if (gid < O_WR)  { src = bl;   off = gid - O_BL;  }
  else if (gid < O_LNG) { src = Wr;   off = gid - O_WR;  }
  else if (gid < O_LNB) { src = lng;  off = gid - O_LNG; }
  else if (gid < O_W1)  { src = lnb;  off = gid - O_LNB; }
  else if (gid < O_B1)  { src = W1;   off = gid - O_W1;  }
  else if (gid < O_W2)  { src = b1;   off = gid - O_B1;  }
  else if (gid < O_B2)  { src = W2;   off = gid - O_W2;  }
  else if (gid < O_W3)  { src = b2;   off = gid - O_B2;  }
  else if (gid < O_B3)  { src = W3;   off = gid - O_W3;  }
  else                  { src = b3;   off = 0;           }
  wc[gid] = f32 ? f2b(((const float*)src)[off]) : ((const unsigned short*)src)[off];
}

// ---------------- in-degree --------------------------------------------------
__global__ void k_deg(const int* __restrict__ ei, float* __restrict__ deg,
                      const int* __restrict__ flags) {
  const int e = blockIdx.x * 256 + threadIdx.x;
  if (e >= NE) return;
  const int d = flags[1] ? ei[2 * (NE + e)] : ei[NE + e];
  atomicAdd(&deg[d], 1.0f);
}

// ---------------- input projection: hb = bf16(x @ W_in^T + b_in) -------------
__global__ void k_inproj(const void* __restrict__ x,
                         const unsigned short* __restrict__ wc,
                         unsigned short* __restrict__ hb,
                         const int* __restrict__ flags) {
  const int gid = blockIdx.x * 256 + threadIdx.x;  // NN*128 threads
  const int n = gid >> 7, j = gid & 127;
  float xv[16];
  if (flags[0]) {
    const float4* xp = (const float4*)((const float*)x + (size_t)n * 16);
#pragma unroll
    for (int q = 0; q < 4; q++) {
      float4 t = xp[q];
      xv[q * 4 + 0] = t.x; xv[q * 4 + 1] = t.y; xv[q * 4 + 2] = t.z; xv[q * 4 + 3] = t.w;
    }
  } else {
    const unsigned short* xu = (const unsigned short*)x + (size_t)n * 16;
#pragma unroll
    for (int q = 0; q < 2; q++) {
      union { int4 v; unsigned short u[8]; } t;
      t.v = *(const int4*)(xu + q * 8);
#pragma unroll
      for (int i = 0; i < 8; i++) xv[q * 8 + i] = b2f(t.u[i]);
    }
  }
  float s = b2f(wc[O_BIN + j]);
  const unsigned short* wrow = wc + O_WIN + j * 16;
#pragma unroll
  for (int q = 0; q < 2; q++) {
    union { int4 v; unsigned short u[8]; } w;
    w.v = *(const int4*)(wrow + q * 8);
#pragma unroll
    for (int i = 0; i < 8; i++) s += b2f(w.u[i]) * xv[q * 8 + i];
  }
  hb[gid] = f2b(s);
}

// ---------------- scatter-add bf16 hb[src] into fp32 agg[dst] ----------------
__global__ void k_scatter(const int* __restrict__ ei,
                          const unsigned short* __restrict__ hb,
                          float* __restrict__ agg, const int* __restrict__ flags) {
  const int gid = blockIdx.x * 256 + threadIdx.x;  // NE*16 threads
  const int e = gid >> 4;
  const int c8 = (gid & 15) * 8;
  const int i64 = flags[1];
  const int s = i64 ? ei[2 * e] : ei[e];
  const int d = i64 ? ei[2 * (NE + e)] : ei[NE + e];
  union { int4 v; unsigned short u[8]; } t;
  t.v = *(const int4*)(hb + (size_t)s * 128 + c8);
  float* a = agg + (size_t)d * 128 + c8;
#pragma unroll
  for (int i = 0; i < 8; i++) atomicAdd(a + i, b2f(t.u[i]));
}

// ---------------- SAGE layer, one node per block (128 threads) ---------------
__global__ __launch_bounds__(128) void k_sage(
    const float* __restrict__ agg, const float* __restrict__ deg,
    const unsigned short* __restrict__ wc, unsigned short* __restrict__ hb, int l) {
  __shared__ float u[256];
  __shared__ float red[4];
  const int j = threadIdx.x;
  const int n = blockIdx.x;
  const float rd = 1.0f / fmaxf(deg[n], 1.0f);
  u[j] = agg[(size_t)n * 128 + j] * rd;
  u[128 + j] = b2f(hb[(size_t)n * 128 + j]);
  __syncthreads();
  float acc = b2f(wc[O_BL + l * 128 + j]);
  const unsigned short* wl = wc + O_WL + ((size_t)l * 128 + j) * 128;
  const unsigned short* wr = wc + O_WR + ((size_t)l * 128 + j) * 128;
#pragma unroll
  for (int c = 0; c < 16; c++) {
    union { int4 v; unsigned short u8[8]; } w;
    w.v = *(const int4*)(wl + c * 8);
#pragma unroll
    for (int i = 0; i < 8; i++) acc += b2f(w.u8[i]) * u[c * 8 + i];
  }
#pragma unroll
  for (int c = 0; c < 16; c++) {
    union { int4 v; unsigned short u8[8]; } w;
    w.v = *(const int4*)(wr + c * 8);
#pragma unroll
    for (int i = 0; i < 8; i++) acc += b2f(w.u8[i]) * u[128 + c * 8 + i];
  }
  float s1 = acc, s2 = acc * acc;
#pragma unroll
  for (int off = 1; off < 64; off <<= 1) {
    s1 += __shfl_xor(s1, off, 64);
    s2 += __shfl_xor(s2, off, 64);
  }
  if ((j & 63) == 0) { red[(j >> 6) * 2] = s1; red[(j >> 6) * 2 + 1] = s2; }
  __syncthreads();
  s1 = red[0] + red[2];
  s2 = red[1] + red[3];
  const float mu = s1 * 0.0078125f;
  const float var = s2 * 0.0078125f - mu * mu;
  const float rstd = rsqrtf(var + 1e-5f);
  float o = (acc - mu) * rstd * b2f(wc[O_LNG + l * 128 + j]) + b2f(wc[O_LNB + l * 128 + j]);
  hb[(size_t)n * 128 + j] = f2b(fmaxf(o, 0.f));
}

// ---------------- simple edge head: 16 edges per block, fp32 VALU ------------
__global__ __launch_bounds__(256) void k_edge_simple(
    const unsigned short* __restrict__ hb, const int* __restrict__ ei,
    const void* __restrict__ ea, const unsigned short* __restrict__ wc,
    void* __restrict__ out, const int* __restrict__ flags) {
  __shared__ float U[16][264];
  __shared__ float e1s[16][128];
  __shared__ float e2s[16][64];
  const int tid = threadIdx.x;
  const int ebase = blockIdx.x * 16;
  const int f32 = flags[0], i64 = flags[1];
  for (int v = tid; v < 16 * 264; v += 256) {
    const int el = v / 264;
    const int k = v - el * 264;
    const int eg = ebase + el;
    float val;
    if (k < 128) {
      const int s = i64 ? ei[2 * eg] : ei[eg];
      val = b2f(hb[(size_t)s * 128 + k]);
    } else if (k < 256) {
      const int d = i64 ? ei[2 * (NE + eg)] : ei[NE + eg];
      val = b2f(hb[(size_t)d * 128 + (k - 128)]);
    } else {
      val = f32 ? ((const float*)ea)[(size_t)eg * 8 + (k - 256)]
                : b2f(((const unsigned short*)ea)[(size_t)eg * 8 + (k - 256)]);
    }
    U[el][k] = val;
  }
  __syncthreads();
  for (int rep = 0; rep < 8; rep++) {
    const int o = rep * 256 + tid;
    const int el = o >> 7, j = o & 127;
    float acc = b2f(wc[O_B1 + j]);
    const unsigned short* wrow = wc + O_W1 + (size_t)j * 264;
    const float* ur = &U[el][0];
    for (int c = 0; c < 33; c++) {
      union { int4 v; unsigned short u8[8]; } w;
      w.v = *(const int4*)(wrow + c * 8);
#pragma unroll
      for (int i = 0; i < 8; i++) acc += b2f(w.u8[i]) * ur[c * 8 + i];
    }
    e1s[el][j] = fmaxf(acc, 0.f);
  }
  __syncthreads();
  for (int rep = 0; rep < 4; rep++) {
    const int o = rep * 256 + tid;
    const int el = o >> 6, j = o & 63;
    float acc = b2f(wc[O_B2 + j]);
    const unsigned short* wrow = wc + O_W2 + (size_t)j * 128;
    const float* ur = &e1s[el][0];
    for (int c = 0; c < 16; c++) {
      union { int4 v; unsigned short u8[8]; } w;
      w.v = *(const int4*)(wrow + c * 8);
#pragma unroll
      for (int i = 0; i < 8; i++) acc += b2f(w.u8[i]) * ur[c * 8 + i];
    }
    e2s[el][j] = fmaxf(acc, 0.f);
  }
  __syncthreads();
  if (tid < 16) {
    float acc = b2f(wc[O_B3]);
    for (int k = 0; k < 64; k++) acc += b2f(wc[O_W3 + k]) * e2s[tid][k];
    if (f32) ((float*)out)[ebase + tid] = acc;
    else     ((unsigned short*)out)[ebase + tid] = f2b(acc);
  }
}

extern "C" void kernel_launch(void* const* d_in, const int* in_sizes, int n_in,
                              void* d_out, int out_size, void* d_ws, size_t ws_size,
                              hipStream_t stream) {
  const void* x    = d_in[0];
  const int*  ei   = (const int*)d_in[1];
  const void* ea   = d_in[2];
  const void* W_in = d_in[3];
  const void* b_in = d_in[4];
  const void* Wl   = d_in[5];
  const void* bl   = d_in[6];
  const void* Wr   = d_in[7];
  const void* lng  = d_in[8];
  const void* lnb  = d_in[9];
  const void* W1   = d_in[10];
  const void* b1   = d_in[11];
  const void* W2   = d_in[12];
  const void* b2   = d_in[13];
  const void* W3   = d_in[14];
  const void* b3   = d_in[15];

  char* ws = (char*)d_ws;
  int*            flags = (int*)(ws + WS_FLAGS);
  unsigned short* wc    = (unsigned short*)(ws + WS_WC);
  float*          deg   = (float*)(ws + WS_DEG);
  unsigned short* hb    = (unsigned short*)(ws + WS_HB);
  float*          agg   = (float*)(ws + WS_AGG);

  if (ws_size < WS_NEED) {  // diagnostic: error ≈ 1.35 signals this path
    k_fallback<<<3125, 256, 0, stream>>>((unsigned short*)d_out);
    return;
  }

  k_probe<<<1, 64, 0, stream>>>((const unsigned short*)x, ei, flags);
  k_cvt_w<<<(W_TOTAL + 255) / 256, 256, 0, stream>>>(
      W_in, b_in, Wl, bl, Wr, lng, lnb, W1, b1, W2, b2, W3, b3, wc, flags);
  hipMemsetAsync(deg, 0, NN * sizeof(float), stream);
  k_deg<<<3125, 256, 0, stream>>>(ei, deg, flags);
  k_inproj<<<NN * 128 / 256, 256, 0, stream>>>(x, wc, hb, flags);
  for (int l = 0; l < 4; l++) {
    hipMemsetAsync(agg, 0, (size_t)NN * 128 * 4, stream);
    k_scatter<<<NE * 16 / 256, 256, 0, stream>>>(ei, hb, agg, flags);
    k_sage<<<NN, 128, 0, stream>>>(agg, deg, wc, hb, l);
  }
  k_edge_simple<<<NE / 16, 256, 0, stream>>>(hb, ei, ea, wc, d_out, flags);
}

// Round 4
// 2759.612 us; speedup vs baseline: 6.5568x; 6.5568x over previous
//
#include <hip/hip_runtime.h>
#include <stdint.h>

#define NN 50000
#define NE 800000

// canonical bf16 weight-block element offsets
#define O_WIN 0
#define O_BIN 2048
#define O_WL  2176
#define O_BL  67712
#define O_WR  68224
#define O_LNG 133760
#define O_LNB 134272
#define O_W1  134784
#define O_B1  168576
#define O_W2  168704
#define O_B2  176896
#define O_W3  176960
#define O_B3  177024
#define W_TOTAL 177025

// ws layout (bytes)
#define WS_FLAGS 0          //      256 B
#define WS_WC    512        //  354,050 B
#define WS_CNT   355072     //  200,000 B
#define WS_ROWP  555520     //  200,004 B
#define WS_CUR   756224     //  200,000 B
#define WS_CSR   956928     // 3,200,000 B
#define WS_W1P   4157440    //    73,728 B
#define WS_HB0   4231680    // 12,800,000 B
#define WS_HB1   17032192   // 12,800,000 B
#define WS_NEED  29832192

typedef float f32x4 __attribute__((ext_vector_type(4)));
typedef short bf16x8 __attribute__((ext_vector_type(8)));
typedef short bf16x4 __attribute__((ext_vector_type(4)));

__device__ __forceinline__ float b2f(unsigned short u) {
  union { unsigned int i; float f; } v; v.i = ((unsigned int)u) << 16; return v.f;
}
__device__ __forceinline__ unsigned short f2b(float f) {
  union { float f; unsigned int i; } v; v.f = f;
  return (unsigned short)((v.i + 0x7fffu + ((v.i >> 16) & 1u)) >> 16);
}

// ---------------- fallback diagnostic: ws too small → constant 0.5 ----------
__global__ void k_fallback(unsigned short* __restrict__ out) {
  int gid = blockIdx.x * 256 + threadIdx.x;
  if (gid < NE) out[gid] = 0x3F00;
}

// ---------------- dtype probe: flags[0]=fp32 float tensors, flags[1]=int64 --
__global__ void k_probe(const unsigned short* __restrict__ x_u,
                        const int* __restrict__ ei32, int* __restrict__ flags) {
  const int t = threadIdx.x;  // 64 threads, 1 wave
  int insane = 0;
  for (int i = t; i < 512; i += 64) {
    float v = b2f(x_u[i]);
    if (!(fabsf(v) < 1e4f)) insane++;
  }
#pragma unroll
  for (int off = 1; off < 64; off <<= 1) insane += __shfl_xor(insane, off, 64);
  int nz = 0;
  for (int i = t; i < 128; i += 64) nz |= (ei32[2 * i + 1] != 0);
  unsigned long long m = __ballot(nz != 0);
  if (t == 0) {
    flags[0] = (insane >= 16) ? 1 : 0;
    flags[1] = (m == 0ULL) ? 1 : 0;
  }
}

// ---------------- canonicalize the 13 weight tensors to bf16 ----------------
__global__ void k_cvt_w(const void* W_in, const void* b_in, const void* Wl,
                        const void* bl, const void* Wr, const void* lng,
                        const void* lnb, const void* W1, const void* b1,
                        const void* W2, const void* b2, const void* W3,
                        const void* b3, unsigned short* __restrict__ wc,
                        const int* __restrict__ flags) {
  const int gid = blockIdx.x * 256 + threadIdx.x;
  if (gid >= W_TOTAL) return;
  const int f32 = flags[0];
  const void* src; int off;
  if      (gid < O_BIN) { src = W_in; off = gid - O_WIN; }
  else if (gid < O_WL)  { src = b_in; off = gid - O_BIN; }
  else if (gid < O_BL)  { src = Wl;   off = gid - O_WL;  }
  else if (gid < O_WR)  { src = bl;   off = gid - O_BL;  }
  else if (gid < O_LNG) { src = Wr;   off = gid - O_WR;  }
  else if (gid < O_LNB) { src = lng;  off = gid - O_LNG; }
  else if (gid < O_W1)  { src = lnb;  off = gid - O_LNB; }
  else if (gid < O_B1)  { src = W1;   off = gid - O_W1;  }
  else if (gid < O_W2)  { src = b1;   off = gid - O_B1;  }
  else if (gid < O_B2)  { src = W2;   off = gid - O_W2;  }
  else if (gid < O_W3)  { src = b2;   off = gid - O_B2;  }
  else if (gid < O_B3)  { src = W3;   off = gid - O_W3;  }
  else                  { src = b3;   off = 0;           }
  wc[gid] = f32 ? f2b(((const float*)src)[off]) : ((const unsigned short*)src)[off];
}

// ---------------- W1 padded copy: wc[128][264] -> W1p[128][288] -------------
__global__ void k_build_w1p(const unsigned short* __restrict__ wc,
                            unsigned short* __restrict__ W1p) {
  int gid = blockIdx.x * 256 + threadIdx.x;  // 128*288 = 36864
  if (gid >= 128 * 288) return;
  int j = gid / 288, k = gid - j * 288;
  W1p[gid] = (k < 264) ? wc[O_W1 + j * 264 + k] : (unsigned short)0;
}

// ---------------- CSR build: histogram -> scan -> fill ----------------------
__global__ void k_hist(const int* __restrict__ ei, int* __restrict__ cnt,
                       const int* __restrict__ flags) {
  const int e = blockIdx.x * 256 + threadIdx.x;
  if (e >= NE) return;
  const int d = flags[1] ? ei[2 * (NE + e)] : ei[NE + e];
  atomicAdd(&cnt[d], 1);
}

__global__ __launch_bounds__(1024) void k_scan(const int* __restrict__ cnt,
                                               int* __restrict__ rowptr) {
  __shared__ int wsum[16];
  __shared__ int carry;
  const int t = threadIdx.x, wv = t >> 6, ln = t & 63;
  if (t == 0) carry = 0;
  __syncthreads();
  for (int base = 0; base < NN; base += 1024) {
    const int i = base + t;
    const int v = (i < NN) ? cnt[i] : 0;
    int x = v;
#pragma unroll
    for (int off = 1; off < 64; off <<= 1) {
      int y = __shfl_up(x, off, 64);
      if (ln >= off) x += y;
    }
    if (ln == 63) wsum[wv] = x;
    __syncthreads();
    if (t < 16) {
      int w = wsum[t];
#pragma unroll
      for (int off = 1; off < 16; off <<= 1) {
        int y = __shfl_up(w, off, 64);
        if (t >= off) w += y;
      }
      wsum[t] = w;
    }
    __syncthreads();
    const int woff = wv ? wsum[wv - 1] : 0;
    if (i < NN) rowptr[i] = carry + woff + x - v;
    const int total = wsum[15];
    __syncthreads();
    if (t == 0) carry += total;
    __syncthreads();
  }
  if (t == 0) rowptr[NN] = NE;
}

__global__ void k_fill(const int* __restrict__ ei, const int* __restrict__ rowptr,
                       int* __restrict__ cursor, int* __restrict__ csr,
                       const int* __restrict__ flags) {
  const int e = blockIdx.x * 256 + threadIdx.x;
  if (e >= NE) return;
  const int i64 = flags[1];
  const int s = i64 ? ei[2 * e] : ei[e];
  const int d = i64 ? ei[2 * (NE + e)] : ei[NE + e];
  const int pos = atomicAdd(&cursor[d], 1);
  csr[rowptr[d] + pos] = s;
}

// ---------------- input projection: hb0 = bf16(x @ W_in^T + b_in) -----------
__global__ void k_inproj(const void* __restrict__ x,
                         const unsigned short* __restrict__ wc,
                         unsigned short* __restrict__ hb,
                         const int* __restrict__ flags) {
  const int gid = blockIdx.x * 256 + threadIdx.x;  // NN*128 threads
  const int n = gid >> 7, j = gid & 127;
  float xv[16];
  if (flags[0]) {
    const float4* xp = (const float4*)((const float*)x + (size_t)n * 16);
#pragma unroll
    for (int q = 0; q < 4; q++) {
      float4 t = xp[q];
      xv[q * 4 + 0] = t.x; xv[q * 4 + 1] = t.y; xv[q * 4 + 2] = t.z; xv[q * 4 + 3] = t.w;
    }
  } else {
    const unsigned short* xu = (const unsigned short*)x + (size_t)n * 16;
#pragma unroll
    for (int q = 0; q < 2; q++) {
      union { int4 v; unsigned short u[8]; } t;
      t.v = *(const int4*)(xu + q * 8);
#pragma unroll
      for (int i = 0; i < 8; i++) xv[q * 8 + i] = b2f(t.u[i]);
    }
  }
  float s = b2f(wc[O_BIN + j]);
  const unsigned short* wrow = wc + O_WIN + j * 16;
#pragma unroll
  for (int q = 0; q < 2; q++) {
    union { int4 v; unsigned short u[8]; } w;
    w.v = *(const int4*)(wrow + q * 8);
#pragma unroll
    for (int i = 0; i < 8; i++) s += b2f(w.u[i]) * xv[q * 8 + i];
  }
  hb[gid] = f2b(s);
}

// ---------------- SAGE layer w/ fused CSR gather, one node per block --------
__global__ __launch_bounds__(128) void k_sage(
    const unsigned short* __restrict__ hin, unsigned short* __restrict__ hout,
    const int* __restrict__ csr, const int* __restrict__ rowptr,
    const unsigned short* __restrict__ wc, int l) {
  __shared__ float u[256];
  __shared__ float red[4];
  const int j = threadIdx.x;
  const int n = blockIdx.x;
  const int rs = rowptr[n], re = rowptr[n + 1];
  float s = 0.f;
  for (int e = rs; e < re; e++) {
    const int src = csr[e];
    s += b2f(hin[(size_t)src * 128 + j]);
  }
  const int dg = re - rs;
  u[j] = s * (1.0f / (float)(dg > 1 ? dg : 1));
  u[128 + j] = b2f(hin[(size_t)n * 128 + j]);
  __syncthreads();
  float acc = b2f(wc[O_BL + l * 128 + j]);
  const unsigned short* wl = wc + O_WL + ((size_t)l * 128 + j) * 128;
  const unsigned short* wr = wc + O_WR + ((size_t)l * 128 + j) * 128;
#pragma unroll
  for (int c = 0; c < 16; c++) {
    union { int4 v; unsigned short u8[8]; } w;
    w.v = *(const int4*)(wl + c * 8);
#pragma unroll
    for (int i = 0; i < 8; i++) acc += b2f(w.u8[i]) * u[c * 8 + i];
  }
#pragma unroll
  for (int c = 0; c < 16; c++) {
    union { int4 v; unsigned short u8[8]; } w;
    w.v = *(const int4*)(wr + c * 8);
#pragma unroll
    for (int i = 0; i < 8; i++) acc += b2f(w.u8[i]) * u[128 + c * 8 + i];
  }
  float s1 = acc, s2 = acc * acc;
#pragma unroll
  for (int off = 1; off < 64; off <<= 1) {
    s1 += __shfl_xor(s1, off, 64);
    s2 += __shfl_xor(s2, off, 64);
  }
  if ((j & 63) == 0) { red[(j >> 6) * 2] = s1; red[(j >> 6) * 2 + 1] = s2; }
  __syncthreads();
  s1 = red[0] + red[2];
  s2 = red[1] + red[3];
  const float mu = s1 * 0.0078125f;
  const float var = s2 * 0.0078125f - mu * mu;
  const float rstd = rsqrtf(var + 1e-5f);
  float o = (acc - mu) * rstd * b2f(wc[O_LNG + l * 128 + j]) + b2f(wc[O_LNB + l * 128 + j]);
  hout[(size_t)n * 128 + j] = f2b(fmaxf(o, 0.f));
}

// ---------------- fused edge head: gather + 3-layer MLP via MFMA ------------
// LDS: Us[64][272B] Ud[64][272B] Ue[64][64B] E1[64][272B] E2[64][136B] = 65024B
__global__ __launch_bounds__(256, 1) void k_edge_mfma(
    const unsigned short* __restrict__ hb, const int* __restrict__ ei,
    const void* __restrict__ ea, const unsigned short* __restrict__ W1p,
    const unsigned short* __restrict__ wc, void* __restrict__ out,
    const int* __restrict__ flags) {
  __shared__ __align__(16) unsigned char sm[65024];
  unsigned char* const Us = sm;
  unsigned char* const Ud = sm + 17408;
  unsigned char* const Ue = sm + 34816;
  unsigned char* const E1 = sm + 38912;
  unsigned char* const E2 = sm + 56320;
  const int tid = threadIdx.x;
  const int wv = tid >> 6;
  const int L = tid & 63;
  const int l15 = L & 15;
  const int q = L >> 4;
  const int mpair = wv >> 1;   // which 32-edge half this wave computes
  const int nhalf = wv & 1;    // which 64-wide output half this wave computes
  const int f32 = flags[0], i64 = flags[1];

  // zero the K-padding region of Ue (bytes 16..63 of each 64B row), once
  for (int i = tid; i < 64 * 12; i += 256)
    *(int*)(Ue + (i / 12) * 64 + 16 + (i % 12) * 4) = 0;

  // register-resident weight fragments (loop-invariant across tiles)
  bf16x8 w1f[4][9];
#pragma unroll
  for (int nt = 0; nt < 4; nt++)
#pragma unroll
    for (int cc = 0; cc < 9; cc++) {
      const int jj = (nhalf * 4 + nt) * 16 + l15;
      w1f[nt][cc] = *(const bf16x8*)(W1p + jj * 288 + cc * 32 + q * 8);
    }
  bf16x8 w2f[2][4];
#pragma unroll
  for (int nt = 0; nt < 2; nt++)
#pragma unroll
    for (int cc = 0; cc < 4; cc++) {
      const int jj = (nhalf * 2 + nt) * 16 + l15;
      w2f[nt][cc] = *(const bf16x8*)(wc + O_W2 + jj * 128 + cc * 32 + q * 8);
    }
  float b1v[4], b2v[2], w3v[16];
#pragma unroll
  for (int nt = 0; nt < 4; nt++) b1v[nt] = b2f(wc[O_B1 + (nhalf * 4 + nt) * 16 + l15]);
#pragma unroll
  for (int nt = 0; nt < 2; nt++) b2v[nt] = b2f(wc[O_B2 + (nhalf * 2 + nt) * 16 + l15]);
#pragma unroll
  for (int i = 0; i < 16; i++) w3v[i] = b2f(wc[O_W3 + q * 16 + i]);
  const float b3f = b2f(wc[O_B3]);

  for (int t = blockIdx.x; t < NE / 64; t += gridDim.x) {
    __syncthreads();
    const int ebase = t * 64;
    // stage 64 edges: h[src] row, h[dst] row, edge_attr
    for (int u = tid; u < 64 * 33; u += 256) {
      const int el = u / 33;
      const int part = u - el * 33;
      const int eg = ebase + el;
      if (part < 16) {
        const int s = i64 ? ei[2 * eg] : ei[eg];
        *(int4*)(Us + el * 272 + part * 16) = *(const int4*)(hb + (size_t)s * 128 + part * 8);
      } else if (part < 32) {
        const int d = i64 ? ei[2 * (NE + eg)] : ei[NE + eg];
        *(int4*)(Ud + el * 272 + (part - 16) * 16) = *(const int4*)(hb + (size_t)d * 128 + (part - 16) * 8);
      } else {
        if (f32) {
          const float4* ep = (const float4*)((const float*)ea + (size_t)eg * 8);
          const float4 a = ep[0], b = ep[1];
          union { ushort4 v[2]; int4 i; } o;
          o.v[0].x = f2b(a.x); o.v[0].y = f2b(a.y); o.v[0].z = f2b(a.z); o.v[0].w = f2b(a.w);
          o.v[1].x = f2b(b.x); o.v[1].y = f2b(b.y); o.v[1].z = f2b(b.z); o.v[1].w = f2b(b.w);
          *(int4*)(Ue + el * 64) = o.i;
        } else {
          *(int4*)(Ue + el * 64) = *(const int4*)((const unsigned short*)ea + (size_t)eg * 8);
        }
      }
    }
    __syncthreads();

    // GEMM1: e1[64][128] = relu(U[64][288] @ W1p^T + b1)
    f32x4 acc1[2][4];
#pragma unroll
    for (int mt = 0; mt < 2; mt++)
#pragma unroll
      for (int nt = 0; nt < 4; nt++) acc1[mt][nt] = (f32x4)(0.0f);
#pragma unroll
    for (int cc = 0; cc < 9; cc++) {
#pragma unroll
      for (int mt = 0; mt < 2; mt++) {
        const int r = mpair * 32 + mt * 16 + l15;
        const unsigned char* ap;
        if (cc < 4)      ap = Us + r * 272 + (cc * 32 + q * 8) * 2;
        else if (cc < 8) ap = Ud + r * 272 + ((cc - 4) * 32 + q * 8) * 2;
        else             ap = Ue + r * 64 + q * 16;
        const bf16x8 a = *(const bf16x8*)ap;
#pragma unroll
        for (int nt = 0; nt < 4; nt++)
          acc1[mt][nt] = __builtin_amdgcn_mfma_f32_16x16x32_bf16(a, w1f[nt][cc], acc1[mt][nt], 0, 0, 0);
      }
    }
#pragma unroll
    for (int mt = 0; mt < 2; mt++)
#pragma unroll
      for (int nt = 0; nt < 4; nt++)
#pragma unroll
        for (int rg = 0; rg < 4; rg++) {
          const int er = mpair * 32 + mt * 16 + q * 4 + rg;
          const int jj = (nhalf * 4 + nt) * 16 + l15;
          *(unsigned short*)(E1 + er * 272 + jj * 2) =
              f2b(fmaxf(acc1[mt][nt][rg] + b1v[nt], 0.f));
        }
    __syncthreads();

    // GEMM2: e2[64][64] = relu(e1 @ W2^T + b2)
    f32x4 acc2[2][2];
#pragma unroll
    for (int mt = 0; mt < 2; mt++)
#pragma unroll
      for (int nt = 0; nt < 2; nt++) acc2[mt][nt] = (f32x4)(0.0f);
#pragma unroll
    for (int cc = 0; cc < 4; cc++) {
#pragma unroll
      for (int mt = 0; mt < 2; mt++) {
        const int r = mpair * 32 + mt * 16 + l15;
        const bf16x8 a = *(const bf16x8*)(E1 + r * 272 + (cc * 32 + q * 8) * 2);
#pragma unroll
        for (int nt = 0; nt < 2; nt++)
          acc2[mt][nt] = __builtin_amdgcn_mfma_f32_16x16x32_bf16(a, w2f[nt][cc], acc2[mt][nt], 0, 0, 0);
      }
    }
#pragma unroll
    for (int mt = 0; mt < 2; mt++)
#pragma unroll
      for (int nt = 0; nt < 2; nt++)
#pragma unroll
        for (int rg = 0; rg < 4; rg++) {
          const int er = mpair * 32 + mt * 16 + q * 4 + rg;
          const int jj = (nhalf * 2 + nt) * 16 + l15;
          *(unsigned short*)(E2 + er * 136 + jj * 2) =
              f2b(fmaxf(acc2[mt][nt][rg] + b2v[nt], 0.f));
        }
    __syncthreads();

    // GEMM3: logit = e2 @ W3^T + b3 (dot-64 via 4 lane-groups + shuffle)
    const int el = wv * 16 + l15;
    float acc = 0.f;
#pragma unroll
    for (int i4 = 0; i4 < 4; i4++) {
      const bf16x4 v = *(const bf16x4*)(E2 + el * 136 + q * 32 + i4 * 8);
      acc += b2f((unsigned short)v[0]) * w3v[i4 * 4 + 0];
      acc += b2f((unsigned short)v[1]) * w3v[i4 * 4 + 1];
      acc += b2f((unsigned short)v[2]) * w3v[i4 * 4 + 2];
      acc += b2f((unsigned short)v[3]) * w3v[i4 * 4 + 3];
    }
    acc += __shfl_xor(acc, 16, 64);
    acc += __shfl_xor(acc, 32, 64);
    if (q == 0) {
      const float r = acc + b3f;
      if (f32) ((float*)out)[ebase + el] = r;
      else     ((unsigned short*)out)[ebase + el] = f2b(r);
    }
  }
}

extern "C" void kernel_launch(void* const* d_in, const int* in_sizes, int n_in,
                              void* d_out, int out_size, void* d_ws, size_t ws_size,
                              hipStream_t stream) {
  const void* x    = d_in[0];
  const int*  ei   = (const int*)d_in[1];
  const void* ea   = d_in[2];

  char* ws = (char*)d_ws;
  int*            flags  = (int*)(ws + WS_FLAGS);
  unsigned short* wc     = (unsigned short*)(ws + WS_WC);
  int*            cnt    = (int*)(ws + WS_CNT);
  int*            rowptr = (int*)(ws + WS_ROWP);
  int*            cursor = (int*)(ws + WS_CUR);
  int*            csr    = (int*)(ws + WS_CSR);
  unsigned short* W1p    = (unsigned short*)(ws + WS_W1P);
  unsigned short* hb0    = (unsigned short*)(ws + WS_HB0);
  unsigned short* hb1    = (unsigned short*)(ws + WS_HB1);

  if (ws_size < WS_NEED) {  // diagnostic: error ≈ 1.35 signals this path
    k_fallback<<<3125, 256, 0, stream>>>((unsigned short*)d_out);
    return;
  }

  k_probe<<<1, 64, 0, stream>>>((const unsigned short*)x, ei, flags);
  k_cvt_w<<<(W_TOTAL + 255) / 256, 256, 0, stream>>>(
      d_in[3], d_in[4], d_in[5], d_in[6], d_in[7], d_in[8], d_in[9],
      d_in[10], d_in[11], d_in[12], d_in[13], d_in[14], d_in[15], wc, flags);
  k_build_w1p<<<144, 256, 0, stream>>>(wc, W1p);

  hipMemsetAsync(cnt, 0, NN * sizeof(int), stream);
  hipMemsetAsync(cursor, 0, NN * sizeof(int), stream);
  k_hist<<<3125, 256, 0, stream>>>(ei, cnt, flags);
  k_scan<<<1, 1024, 0, stream>>>(cnt, rowptr);
  k_fill<<<3125, 256, 0, stream>>>(ei, rowptr, cursor, csr, flags);

  k_inproj<<<NN * 128 / 256, 256, 0, stream>>>(x, wc, hb0, flags);
  k_sage<<<NN, 128, 0, stream>>>(hb0, hb1, csr, rowptr, wc, 0);
  k_sage<<<NN, 128, 0, stream>>>(hb1, hb0, csr, rowptr, wc, 1);
  k_sage<<<NN, 128, 0, stream>>>(hb0, hb1, csr, rowptr, wc, 2);
  k_sage<<<NN, 128, 0, stream>>>(hb1, hb0, csr, rowptr, wc, 3);

  k_edge_mfma<<<512, 256, 0, stream>>>(hb0, ei, ea, W1p, wc, d_out, flags);
}

// Round 6
// 876.907 us; speedup vs baseline: 20.6342x; 3.1470x over previous
//
#include <hip/hip_runtime.h>
#include <stdint.h>

#define NN 50000
#define NE 800000

// canonical bf16 weight-block element offsets
#define O_WIN 0
#define O_BIN 2048
#define O_WL  2176
#define O_BL  67712
#define O_WR  68224
#define O_LNG 133760
#define O_LNB 134272
#define O_W1  134784
#define O_B1  168576
#define O_W2  168704
#define O_B2  176896
#define O_W3  176960
#define O_B3  177024
#define W_TOTAL 177025

// ws layout (bytes)
#define WS_FLAGS 0          //      256 B
#define WS_WC    512        //  354,050 B
#define WS_CNT   355072     //  200,000 B
#define WS_ROWP  555520     //  200,004 B
#define WS_CUR   756224     //  200,000 B
#define WS_CSR   956928     // 3,200,000 B
#define WS_W1P   4157440    //    73,728 B
#define WS_HB0   4231680    // 12,800,000 B
#define WS_HB1   17032192   // 12,800,000 B
#define WS_NEED  29832192

typedef float f32x4 __attribute__((ext_vector_type(4)));
typedef short bf16x8 __attribute__((ext_vector_type(8)));
typedef short bf16x4 __attribute__((ext_vector_type(4)));

__device__ __forceinline__ float b2f(unsigned short u) {
  union { unsigned int i; float f; } v; v.i = ((unsigned int)u) << 16; return v.f;
}
__device__ __forceinline__ unsigned short f2b(float f) {
  union { float f; unsigned int i; } v; v.f = f;
  return (unsigned short)((v.i + 0x7fffu + ((v.i >> 16) & 1u)) >> 16);
}

// ---------------- fallback diagnostic: ws too small → constant 0.5 ----------
__global__ void k_fallback(unsigned short* __restrict__ out) {
  int gid = blockIdx.x * 256 + threadIdx.x;
  if (gid < NE) out[gid] = 0x3F00;
}

// ---------------- dtype probe: flags[0]=fp32 float tensors, flags[1]=int64 --
__global__ void k_probe(const unsigned short* __restrict__ x_u,
                        const int* __restrict__ ei32, int* __restrict__ flags) {
  const int t = threadIdx.x;  // 64 threads, 1 wave
  int insane = 0;
  for (int i = t; i < 512; i += 64) {
    float v = b2f(x_u[i]);
    if (!(fabsf(v) < 1e4f)) insane++;
  }
#pragma unroll
  for (int off = 1; off < 64; off <<= 1) insane += __shfl_xor(insane, off, 64);
  int nz = 0;
  for (int i = t; i < 128; i += 64) nz |= (ei32[2 * i + 1] != 0);
  unsigned long long m = __ballot(nz != 0);
  if (t == 0) {
    flags[0] = (insane >= 16) ? 1 : 0;
    flags[1] = (m == 0ULL) ? 1 : 0;
  }
}

// ---------------- canonicalize the 13 weight tensors to bf16 ----------------
__global__ void k_cvt_w(const void* W_in, const void* b_in, const void* Wl,
                        const void* bl, const void* Wr, const void* lng,
                        const void* lnb, const void* W1, const void* b1,
                        const void* W2, const void* b2, const void* W3,
                        const void* b3, unsigned short* __restrict__ wc,
                        const int* __restrict__ flags) {
  const int gid = blockIdx.x * 256 + threadIdx.x;
  if (gid >= W_TOTAL) return;
  const int f32 = flags[0];
  const void* src; int off;
  if      (gid < O_BIN) { src = W_in; off = gid - O_WIN; }
  else if (gid < O_WL)  { src = b_in; off = gid - O_BIN; }
  else if (gid < O_BL)  { src = Wl;   off = gid - O_WL;  }
  else if (gid < O_WR)  { src = bl;   off = gid - O_BL;  }
  else if (gid < O_LNG) { src = Wr;   off = gid - O_WR;  }
  else if (gid < O_LNB) { src = lng;  off = gid - O_LNG; }
  else if (gid < O_W1)  { src = lnb;  off = gid - O_LNB; }
  else if (gid < O_B1)  { src = W1;   off = gid - O_W1;  }
  else if (gid < O_W2)  { src = b1;   off = gid - O_B1;  }
  else if (gid < O_B2)  { src = W2;   off = gid - O_W2;  }
  else if (gid < O_W3)  { src = b2;   off = gid - O_B2;  }
  else if (gid < O_B3)  { src = W3;   off = gid - O_W3;  }
  else                  { src = b3;   off = 0;           }
  wc[gid] = f32 ? f2b(((const float*)src)[off]) : ((const unsigned short*)src)[off];
}

// ---------------- W1 padded copy: wc[128][264] -> W1p[128][288] -------------
__global__ void k_build_w1p(const unsigned short* __restrict__ wc,
                            unsigned short* __restrict__ W1p) {
  int gid = blockIdx.x * 256 + threadIdx.x;  // 128*288 = 36864
  if (gid >= 128 * 288) return;
  int j = gid / 288, k = gid - j * 288;
  W1p[gid] = (k < 264) ? wc[O_W1 + j * 264 + k] : (unsigned short)0;
}

// ---------------- CSR build: histogram -> scan -> fill -> sort --------------
__global__ void k_hist(const int* __restrict__ ei, int* __restrict__ cnt,
                       const int* __restrict__ flags) {
  const int e = blockIdx.x * 256 + threadIdx.x;
  if (e >= NE) return;
  const int d = flags[1] ? ei[2 * (NE + e)] : ei[NE + e];
  atomicAdd(&cnt[d], 1);
}

__global__ __launch_bounds__(1024) void k_scan(const int* __restrict__ cnt,
                                               int* __restrict__ rowptr) {
  __shared__ int wsum[16];
  __shared__ int carry;
  const int t = threadIdx.x, wv = t >> 6, ln = t & 63;
  if (t == 0) carry = 0;
  __syncthreads();
  for (int base = 0; base < NN; base += 1024) {
    const int i = base + t;
    const int v = (i < NN) ? cnt[i] : 0;
    int x = v;
#pragma unroll
    for (int off = 1; off < 64; off <<= 1) {
      int y = __shfl_up(x, off, 64);
      if (ln >= off) x += y;
    }
    if (ln == 63) wsum[wv] = x;
    __syncthreads();
    if (t < 16) {
      int w = wsum[t];
#pragma unroll
      for (int off = 1; off < 16; off <<= 1) {
        int y = __shfl_up(w, off, 64);
        if (t >= off) w += y;
      }
      wsum[t] = w;
    }
    __syncthreads();
    const int woff = wv ? wsum[wv - 1] : 0;
    if (i < NN) rowptr[i] = carry + woff + x - v;
    const int total = wsum[15];
    __syncthreads();
    if (t == 0) carry += total;
    __syncthreads();
  }
  if (t == 0) rowptr[NN] = NE;
}

__global__ void k_fill(const int* __restrict__ ei, const int* __restrict__ rowptr,
                       int* __restrict__ cursor, int* __restrict__ csr,
                       const int* __restrict__ flags) {
  const int e = blockIdx.x * 256 + threadIdx.x;
  if (e >= NE) return;
  const int i64 = flags[1];
  const int s = i64 ? ei[2 * e] : ei[e];
  const int d = i64 ? ei[2 * (NE + e)] : ei[NE + e];
  const int pos = atomicAdd(&cursor[d], 1);
  csr[rowptr[d] + pos] = s;
}

// canonicalize neighbor order (atomic fill order is nondeterministic; sorted
// rows make every downstream fp32 sum bitwise stable across graph replays)
__global__ void k_sortrows(int* __restrict__ csr, const int* __restrict__ rowptr) {
  const int n = blockIdx.x * 256 + threadIdx.x;
  if (n >= NN) return;
  const int rs = rowptr[n], re = rowptr[n + 1];
  for (int i = rs + 1; i < re; i++) {
    const int v = csr[i];
    int j = i - 1;
    while (j >= rs && csr[j] > v) { csr[j + 1] = csr[j]; j--; }
    csr[j + 1] = v;
  }
}

// ---------------- input projection: hb0 = bf16(x @ W_in^T + b_in) -----------
__global__ void k_inproj(const void* __restrict__ x,
                         const unsigned short* __restrict__ wc,
                         unsigned short* __restrict__ hb,
                         const int* __restrict__ flags) {
  const int gid = blockIdx.x * 256 + threadIdx.x;  // NN*128 threads
  const int n = gid >> 7, j = gid & 127;
  float xv[16];
  if (flags[0]) {
    const float4* xp = (const float4*)((const float*)x + (size_t)n * 16);
#pragma unroll
    for (int q = 0; q < 4; q++) {
      float4 t = xp[q];
      xv[q * 4 + 0] = t.x; xv[q * 4 + 1] = t.y; xv[q * 4 + 2] = t.z; xv[q * 4 + 3] = t.w;
    }
  } else {
    const unsigned short* xu = (const unsigned short*)x + (size_t)n * 16;
#pragma unroll
    for (int q = 0; q < 2; q++) {
      union { int4 v; unsigned short u[8]; } t;
      t.v = *(const int4*)(xu + q * 8);
#pragma unroll
      for (int i = 0; i < 8; i++) xv[q * 8 + i] = b2f(t.u[i]);
    }
  }
  float s = b2f(wc[O_BIN + j]);
  const unsigned short* wrow = wc + O_WIN + j * 16;
#pragma unroll
  for (int q = 0; q < 2; q++) {
    union { int4 v; unsigned short u[8]; } w;
    w.v = *(const int4*)(wrow + q * 8);
#pragma unroll
    for (int i = 0; i < 8; i++) s += b2f(w.u[i]) * xv[q * 8 + i];
  }
  hb[gid] = f2b(s);
}

// ---------------- SAGE layer: fused mean-gather + MFMA GEMM + LN + ReLU -----
// reads hin (any rows), writes hout (own 64-row tile only) — no aliasing.
__global__ __launch_bounds__(256) void k_sage_mfma(
    const unsigned short* __restrict__ hin, unsigned short* __restrict__ hout,
    const int* __restrict__ csr, const int* __restrict__ rowptr,
    const unsigned short* __restrict__ wc, int l) {
  __shared__ __align__(16) unsigned char As[64 * 528];  // 33792 B
  __shared__ float red1[64][4];
  __shared__ float red2[64][4];
  __shared__ float mr[64][2];
  const int tid = threadIdx.x;
  const int wv = tid >> 6;
  const int L = tid & 63;
  const int l15 = L & 15;
  const int q = L >> 4;
  const int n0 = blockIdx.x * 64;

  // register-resident weight fragments: wave wv covers output cols wv*32..+31
  bf16x8 wf[2][8];
  float blv[2], gv[2], bv[2];
#pragma unroll
  for (int nt = 0; nt < 2; nt++) {
    const int jj = (wv * 2 + nt) * 16 + l15;
#pragma unroll
    for (int kc = 0; kc < 8; kc++) {
      const unsigned short* src = (kc < 4)
          ? wc + O_WL + ((size_t)l * 128 + jj) * 128 + kc * 32 + q * 8
          : wc + O_WR + ((size_t)l * 128 + jj) * 128 + (kc - 4) * 32 + q * 8;
      wf[nt][kc] = *(const bf16x8*)src;
    }
    blv[nt] = b2f(wc[O_BL + l * 128 + jj]);
    gv[nt]  = b2f(wc[O_LNG + l * 128 + jj]);
    bv[nt]  = b2f(wc[O_LNB + l * 128 + jj]);
  }

  // stage h half of A (bytes 256..511 of each 528B row)
  for (int c = tid; c < 1024; c += 256) {
    const int row = c >> 4, p16 = c & 15;
    int node = n0 + row; if (node > NN - 1) node = NN - 1;
    *(int4*)(As + row * 528 + 256 + p16 * 16) =
        *(const int4*)(hin + (size_t)node * 128 + p16 * 8);
  }
  // fused mean aggregation: 4 threads per row, 32 channels each, fp32 sums
  {
    const int row = tid >> 2, seg = tid & 3;
    int node = n0 + row; if (node > NN - 1) node = NN - 1;
    const int rs = rowptr[node], re = rowptr[node + 1];
    float s[32];
#pragma unroll
    for (int i = 0; i < 32; i++) s[i] = 0.f;
    for (int e = rs; e < re; e++) {
      const unsigned int* hw = (const unsigned int*)(hin + (size_t)csr[e] * 128 + seg * 32);
#pragma unroll
      for (int i = 0; i < 16; i++) {
        const unsigned int u = hw[i];
        s[2 * i]     += b2f((unsigned short)(u & 0xffff));
        s[2 * i + 1] += b2f((unsigned short)(u >> 16));
      }
    }
    const int dg = re - rs;
    const float rd = 1.0f / (float)(dg > 1 ? dg : 1);
    unsigned int o[16];
#pragma unroll
    for (int i = 0; i < 16; i++)
      o[i] = (unsigned int)f2b(s[2 * i] * rd) | ((unsigned int)f2b(s[2 * i + 1] * rd) << 16);
#pragma unroll
    for (int k = 0; k < 4; k++)
      *(int4*)(As + row * 528 + seg * 64 + k * 16) = ((const int4*)o)[k];
  }
  __syncthreads();

  f32x4 acc[4][2];
#pragma unroll
  for (int mt = 0; mt < 4; mt++)
#pragma unroll
    for (int nt = 0; nt < 2; nt++) acc[mt][nt] = (f32x4)(0.0f);
#pragma unroll
  for (int kc = 0; kc < 8; kc++) {
#pragma unroll
    for (int mt = 0; mt < 4; mt++) {
      const bf16x8 a = *(const bf16x8*)(As + (mt * 16 + l15) * 528 + (kc * 32 + q * 8) * 2);
#pragma unroll
      for (int nt = 0; nt < 2; nt++)
        acc[mt][nt] = __builtin_amdgcn_mfma_f32_16x16x32_bf16(a, wf[nt][kc], acc[mt][nt], 0, 0, 0);
    }
  }
  // add bias, then per-row partial sums (over this wave's 32 cols)
#pragma unroll
  for (int mt = 0; mt < 4; mt++) {
#pragma unroll
    for (int rg = 0; rg < 4; rg++) {
      acc[mt][0][rg] += blv[0];
      acc[mt][1][rg] += blv[1];
      float s = acc[mt][0][rg] + acc[mt][1][rg];
      float s2 = acc[mt][0][rg] * acc[mt][0][rg] + acc[mt][1][rg] * acc[mt][1][rg];
#pragma unroll
      for (int m = 1; m < 16; m <<= 1) {
        s += __shfl_xor(s, m, 64);
        s2 += __shfl_xor(s2, m, 64);
      }
      if (l15 == 0) {
        const int row = mt * 16 + q * 4 + rg;
        red1[row][wv] = s; red2[row][wv] = s2;
      }
    }
  }
  __syncthreads();
  if (tid < 64) {
    const float s1 = red1[tid][0] + red1[tid][1] + red1[tid][2] + red1[tid][3];
    const float s2 = red2[tid][0] + red2[tid][1] + red2[tid][2] + red2[tid][3];
    const float mu = s1 * 0.0078125f;
    const float var = s2 * 0.0078125f - mu * mu;
    mr[tid][0] = mu;
    mr[tid][1] = rsqrtf(var + 1e-5f);
  }
  __syncthreads();
#pragma unroll
  for (int mt = 0; mt < 4; mt++) {
#pragma unroll
    for (int rg = 0; rg < 4; rg++) {
      const int row = mt * 16 + q * 4 + rg;
      const int node = n0 + row;
      if (node < NN) {
        const float mu = mr[row][0], rstd = mr[row][1];
#pragma unroll
        for (int nt = 0; nt < 2; nt++) {
          const float o = (acc[mt][nt][rg] - mu) * rstd * gv[nt] + bv[nt];
          hout[(size_t)node * 128 + (wv * 2 + nt) * 16 + l15] = f2b(fmaxf(o, 0.f));
        }
      }
    }
  }
}

// ---------------- edge head: direct-global A gather + MFMA MLP --------------
// LDS: Ue[64][64B]=4096  E1[64][272B]=17408  E2[64][136B]=8704  → 30208 B
__global__ __launch_bounds__(256) void k_edge_mfma(
    const unsigned short* __restrict__ hb, const int* __restrict__ ei,
    const void* __restrict__ ea, const unsigned short* __restrict__ W1p,
    const unsigned short* __restrict__ wc, void* __restrict__ out,
    const int* __restrict__ flags) {
  __shared__ __align__(16) unsigned char sm[30208];
  unsigned char* const Ue = sm;
  unsigned char* const E1 = sm + 4096;
  unsigned char* const E2 = sm + 21504;
  const int tid = threadIdx.x;
  const int wv = tid >> 6;
  const int L = tid & 63;
  const int l15 = L & 15;
  const int q = L >> 4;
  const int f32 = flags[0], i64 = flags[1];

  // zero the K-padding region of Ue (bytes 16..63 of each 64B row), once
  for (int i = tid; i < 64 * 12; i += 256)
    *(int*)(Ue + (i / 12) * 64 + 16 + (i % 12) * 4) = 0;

  // weights: wave wv covers GEMM1 cols wv*32..+31, GEMM2 cols wv*16..+15
  bf16x8 w1f[2][9];
  float b1v[2];
#pragma unroll
  for (int nt = 0; nt < 2; nt++) {
    const int jj = (wv * 2 + nt) * 16 + l15;
#pragma unroll
    for (int cc = 0; cc < 9; cc++)
      w1f[nt][cc] = *(const bf16x8*)(W1p + jj * 288 + cc * 32 + q * 8);
    b1v[nt] = b2f(wc[O_B1 + jj]);
  }
  bf16x8 w2f[4];
  const int jj2 = wv * 16 + l15;
#pragma unroll
  for (int kc = 0; kc < 4; kc++)
    w2f[kc] = *(const bf16x8*)(wc + O_W2 + jj2 * 128 + kc * 32 + q * 8);
  const float b2v = b2f(wc[O_B2 + jj2]);
  float w3v[16];
#pragma unroll
  for (int i = 0; i < 16; i++) w3v[i] = b2f(wc[O_W3 + q * 16 + i]);
  const float b3f = b2f(wc[O_B3]);

  for (int t = blockIdx.x; t < NE / 64; t += gridDim.x) {
    __syncthreads();  // protect Ue/E2 from previous tile's reads
    const int ebase = t * 64;
    // stage Ue (edge_attr → bf16)
    if (tid < 64) {
      const int eg = ebase + tid;
      if (f32) {
        const float4* ep = (const float4*)((const float*)ea + (size_t)eg * 8);
        const float4 a = ep[0], b = ep[1];
        union { ushort4 v[2]; int4 i; } o;
        o.v[0].x = f2b(a.x); o.v[0].y = f2b(a.y); o.v[0].z = f2b(a.z); o.v[0].w = f2b(a.w);
        o.v[1].x = f2b(b.x); o.v[1].y = f2b(b.y); o.v[1].z = f2b(b.z); o.v[1].w = f2b(b.w);
        *(int4*)(Ue + tid * 64) = o.i;
      } else {
        *(int4*)(Ue + tid * 64) = *(const int4*)((const unsigned short*)ea + (size_t)eg * 8);
      }
    }
    // per-lane edge endpoints for rows mt*16+l15
    int sidx[4], didx[4];
#pragma unroll
    for (int mt = 0; mt < 4; mt++) {
      const int eg = ebase + mt * 16 + l15;
      sidx[mt] = i64 ? ei[2 * eg] : ei[eg];
      didx[mt] = i64 ? ei[2 * (NE + eg)] : ei[NE + eg];
    }
    __syncthreads();  // Ue ready

    // GEMM1: e1[64][128], A-fragments straight from global (hb is LLC-hot)
    f32x4 acc1[4][2];
#pragma unroll
    for (int mt = 0; mt < 4; mt++)
#pragma unroll
      for (int nt = 0; nt < 2; nt++) acc1[mt][nt] = (f32x4)(0.0f);
#pragma unroll
    for (int cc = 0; cc < 4; cc++) {
#pragma unroll
      for (int mt = 0; mt < 4; mt++) {
        const bf16x8 a = *(const bf16x8*)(hb + (size_t)sidx[mt] * 128 + cc * 32 + q * 8);
#pragma unroll
        for (int nt = 0; nt < 2; nt++)
          acc1[mt][nt] = __builtin_amdgcn_mfma_f32_16x16x32_bf16(a, w1f[nt][cc], acc1[mt][nt], 0, 0, 0);
      }
    }
#pragma unroll
    for (int cc = 4; cc < 8; cc++) {
#pragma unroll
      for (int mt = 0; mt < 4; mt++) {
        const bf16x8 a = *(const bf16x8*)(hb + (size_t)didx[mt] * 128 + (cc - 4) * 32 + q * 8);
#pragma unroll
        for (int nt = 0; nt < 2; nt++)
          acc1[mt][nt] = __builtin_amdgcn_mfma_f32_16x16x32_bf16(a, w1f[nt][cc], acc1[mt][nt], 0, 0, 0);
      }
    }
#pragma unroll
    for (int mt = 0; mt < 4; mt++) {
      const bf16x8 a = *(const bf16x8*)(Ue + (mt * 16 + l15) * 64 + q * 16);
#pragma unroll
      for (int nt = 0; nt < 2; nt++)
        acc1[mt][nt] = __builtin_amdgcn_mfma_f32_16x16x32_bf16(a, w1f[nt][8], acc1[mt][nt], 0, 0, 0);
    }
#pragma unroll
    for (int mt = 0; mt < 4; mt++)
#pragma unroll
      for (int nt = 0; nt < 2; nt++)
#pragma unroll
        for (int rg = 0; rg < 4; rg++) {
          const int er = mt * 16 + q * 4 + rg;
          const int jj = (wv * 2 + nt) * 16 + l15;
          *(unsigned short*)(E1 + er * 272 + jj * 2) =
              f2b(fmaxf(acc1[mt][nt][rg] + b1v[nt], 0.f));
        }
    __syncthreads();

    // GEMM2: e2[64][64], wave covers 16 cols, all 64 rows
    f32x4 acc2[4];
#pragma unroll
    for (int mt = 0; mt < 4; mt++) acc2[mt] = (f32x4)(0.0f);
#pragma unroll
    for (int kc = 0; kc < 4; kc++) {
#pragma unroll
      for (int mt = 0; mt < 4; mt++) {
        const bf16x8 a = *(const bf16x8*)(E1 + (mt * 16 + l15) * 272 + (kc * 32 + q * 8) * 2);
        acc2[mt] = __builtin_amdgcn_mfma_f32_16x16x32_bf16(a, w2f[kc], acc2[mt], 0, 0, 0);
      }
    }
#pragma unroll
    for (int mt = 0; mt < 4; mt++)
#pragma unroll
      for (int rg = 0; rg < 4; rg++) {
        const int er = mt * 16 + q * 4 + rg;
        *(unsigned short*)(E2 + er * 136 + jj2 * 2) =
            f2b(fmaxf(acc2[mt][rg] + b2v, 0.f));
      }
    __syncthreads();

    // GEMM3: logit per edge, dot-64 via 4 lane-groups + shuffle
    const int el = wv * 16 + l15;
    float acc = 0.f;
#pragma unroll
    for (int i4 = 0; i4 < 4; i4++) {
      const bf16x4 v = *(const bf16x4*)(E2 + el * 136 + q * 32 + i4 * 8);
      acc += b2f((unsigned short)v[0]) * w3v[i4 * 4 + 0];
      acc += b2f((unsigned short)v[1]) * w3v[i4 * 4 + 1];
      acc += b2f((unsigned short)v[2]) * w3v[i4 * 4 + 2];
      acc += b2f((unsigned short)v[3]) * w3v[i4 * 4 + 3];
    }
    acc += __shfl_xor(acc, 16, 64);
    acc += __shfl_xor(acc, 32, 64);
    if (q == 0) {
      const float r = acc + b3f;
      if (f32) ((float*)out)[ebase + el] = r;
      else     ((unsigned short*)out)[ebase + el] = f2b(r);
    }
  }
}

extern "C" void kernel_launch(void* const* d_in, const int* in_sizes, int n_in,
                              void* d_out, int out_size, void* d_ws, size_t ws_size,
                              hipStream_t stream) {
  const void* x  = d_in[0];
  const int*  ei = (const int*)d_in[1];
  const void* ea = d_in[2];

  char* ws = (char*)d_ws;
  int*            flags  = (int*)(ws + WS_FLAGS);
  unsigned short* wc     = (unsigned short*)(ws + WS_WC);
  int*            cnt    = (int*)(ws + WS_CNT);
  int*            rowptr = (int*)(ws + WS_ROWP);
  int*            cursor = (int*)(ws + WS_CUR);
  int*            csr    = (int*)(ws + WS_CSR);
  unsigned short* W1p    = (unsigned short*)(ws + WS_W1P);
  unsigned short* hb0    = (unsigned short*)(ws + WS_HB0);
  unsigned short* hb1    = (unsigned short*)(ws + WS_HB1);

  if (ws_size < WS_NEED) {  // diagnostic: error ≈ 1.35 signals this path
    k_fallback<<<3125, 256, 0, stream>>>((unsigned short*)d_out);
    return;
  }

  k_probe<<<1, 64, 0, stream>>>((const unsigned short*)x, ei, flags);
  k_cvt_w<<<(W_TOTAL + 255) / 256, 256, 0, stream>>>(
      d_in[3], d_in[4], d_in[5], d_in[6], d_in[7], d_in[8], d_in[9],
      d_in[10], d_in[11], d_in[12], d_in[13], d_in[14], d_in[15], wc, flags);
  k_build_w1p<<<144, 256, 0, stream>>>(wc, W1p);

  hipMemsetAsync(cnt, 0, NN * sizeof(int), stream);
  hipMemsetAsync(cursor, 0, NN * sizeof(int), stream);
  k_hist<<<3125, 256, 0, stream>>>(ei, cnt, flags);
  k_scan<<<1, 1024, 0, stream>>>(cnt, rowptr);
  k_fill<<<3125, 256, 0, stream>>>(ei, rowptr, cursor, csr, flags);
  k_sortrows<<<(NN + 255) / 256, 256, 0, stream>>>(csr, rowptr);

  k_inproj<<<NN * 128 / 256, 256, 0, stream>>>(x, wc, hb0, flags);

  k_sage_mfma<<<782, 256, 0, stream>>>(hb0, hb1, csr, rowptr, wc, 0);
  k_sage_mfma<<<782, 256, 0, stream>>>(hb1, hb0, csr, rowptr, wc, 1);
  k_sage_mfma<<<782, 256, 0, stream>>>(hb0, hb1, csr, rowptr, wc, 2);
  k_sage_mfma<<<782, 256, 0, stream>>>(hb1, hb0, csr, rowptr, wc, 3);

  k_edge_mfma<<<1024, 256, 0, stream>>>(hb0, ei, ea, W1p, wc, d_out, flags);
}

// Round 7
// 851.761 us; speedup vs baseline: 21.2434x; 1.0295x over previous
//
#include <hip/hip_runtime.h>
#include <stdint.h>

#define NN 50000
#define NE 800000

// canonical bf16 weight-block element offsets
#define O_WIN 0
#define O_BIN 2048
#define O_WL  2176
#define O_BL  67712
#define O_WR  68224
#define O_LNG 133760
#define O_LNB 134272
#define O_W1  134784
#define O_B1  168576
#define O_W2  168704
#define O_B2  176896
#define O_W3  176960
#define O_B3  177024
#define W_TOTAL 177025

// ws layout (bytes) — total 36,230,656 ≤ 38.6 MB confirmed floor
#define WS_FLAGS 0          //      256 B
#define WS_WC    512        //  354,050 B
#define WS_CNT   355072     //  200,000 B
#define WS_ROWP  555520     //  200,004 B
#define WS_CUR   756224     //  200,000 B
#define WS_CSR   956928     // 3,200,000 B (src per CSR slot)
#define WS_EID   4156928    // 3,200,000 B (edge id per CSR slot)
#define WS_DST   7356928    // 3,200,000 B (dst per CSR slot)
#define WS_W1P   10556928   //     73,728 B
#define WS_HB0   10630656   // 12,800,000 B
#define WS_HB1   23430656   // 12,800,000 B
#define WS_NEED  36230656

typedef float f32x4 __attribute__((ext_vector_type(4)));
typedef short bf16x8 __attribute__((ext_vector_type(8)));
typedef short bf16x4 __attribute__((ext_vector_type(4)));

__device__ __forceinline__ float b2f(unsigned short u) {
  union { unsigned int i; float f; } v; v.i = ((unsigned int)u) << 16; return v.f;
}
__device__ __forceinline__ unsigned short f2b(float f) {
  union { float f; unsigned int i; } v; v.f = f;
  return (unsigned short)((v.i + 0x7fffu + ((v.i >> 16) & 1u)) >> 16);
}

// ---------------- fallback diagnostic: ws too small → constant 0.5 ----------
__global__ void k_fallback(unsigned short* __restrict__ out) {
  int gid = blockIdx.x * 256 + threadIdx.x;
  if (gid < NE) out[gid] = 0x3F00;
}

// ---------------- dtype probe: flags[0]=fp32 float tensors, flags[1]=int64 --
__global__ void k_probe(const unsigned short* __restrict__ x_u,
                        const int* __restrict__ ei32, int* __restrict__ flags) {
  const int t = threadIdx.x;  // 64 threads, 1 wave
  int insane = 0;
  for (int i = t; i < 512; i += 64) {
    float v = b2f(x_u[i]);
    if (!(fabsf(v) < 1e4f)) insane++;
  }
#pragma unroll
  for (int off = 1; off < 64; off <<= 1) insane += __shfl_xor(insane, off, 64);
  int nz = 0;
  for (int i = t; i < 128; i += 64) nz |= (ei32[2 * i + 1] != 0);
  unsigned long long m = __ballot(nz != 0);
  if (t == 0) {
    flags[0] = (insane >= 16) ? 1 : 0;
    flags[1] = (m == 0ULL) ? 1 : 0;
  }
}

// ---------------- canonicalize the 13 weight tensors to bf16 ----------------
__global__ void k_cvt_w(const void* W_in, const void* b_in, const void* Wl,
                        const void* bl, const void* Wr, const void* lng,
                        const void* lnb, const void* W1, const void* b1,
                        const void* W2, const void* b2, const void* W3,
                        const void* b3, unsigned short* __restrict__ wc,
                        const int* __restrict__ flags) {
  const int gid = blockIdx.x * 256 + threadIdx.x;
  if (gid >= W_TOTAL) return;
  const int f32 = flags[0];
  const void* src; int off;
  if      (gid < O_BIN) { src = W_in; off = gid - O_WIN; }
  else if (gid < O_WL)  { src = b_in; off = gid - O_BIN; }
  else if (gid < O_BL)  { src = Wl;   off = gid - O_WL;  }
  else if (gid < O_WR)  { src = bl;   off = gid - O_BL;  }
  else if (gid < O_LNG) { src = Wr;   off = gid - O_WR;  }
  else if (gid < O_LNB) { src = lng;  off = gid - O_LNG; }
  else if (gid < O_W1)  { src = lnb;  off = gid - O_LNB; }
  else if (gid < O_B1)  { src = W1;   off = gid - O_W1;  }
  else if (gid < O_W2)  { src = b1;   off = gid - O_B1;  }
  else if (gid < O_B2)  { src = W2;   off = gid - O_W2;  }
  else if (gid < O_W3)  { src = b2;   off = gid - O_B2;  }
  else if (gid < O_B3)  { src = W3;   off = gid - O_W3;  }
  else                  { src = b3;   off = 0;           }
  wc[gid] = f32 ? f2b(((const float*)src)[off]) : ((const unsigned short*)src)[off];
}

// ---------------- W1 padded copy: wc[128][264] -> W1p[128][288] -------------
__global__ void k_build_w1p(const unsigned short* __restrict__ wc,
                            unsigned short* __restrict__ W1p) {
  int gid = blockIdx.x * 256 + threadIdx.x;  // 128*288 = 36864
  if (gid >= 128 * 288) return;
  int j = gid / 288, k = gid - j * 288;
  W1p[gid] = (k < 264) ? wc[O_W1 + j * 264 + k] : (unsigned short)0;
}

// ---------------- CSR build: histogram -> scan -> fill -> sort --------------
__global__ void k_hist(const int* __restrict__ ei, int* __restrict__ cnt,
                       const int* __restrict__ flags) {
  const int e = blockIdx.x * 256 + threadIdx.x;
  if (e >= NE) return;
  const int d = flags[1] ? ei[2 * (NE + e)] : ei[NE + e];
  atomicAdd(&cnt[d], 1);
}

__global__ __launch_bounds__(1024) void k_scan(const int* __restrict__ cnt,
                                               int* __restrict__ rowptr) {
  __shared__ int wsum[16];
  __shared__ int carry;
  const int t = threadIdx.x, wv = t >> 6, ln = t & 63;
  if (t == 0) carry = 0;
  __syncthreads();
  for (int base = 0; base < NN; base += 1024) {
    const int i = base + t;
    const int v = (i < NN) ? cnt[i] : 0;
    int x = v;
#pragma unroll
    for (int off = 1; off < 64; off <<= 1) {
      int y = __shfl_up(x, off, 64);
      if (ln >= off) x += y;
    }
    if (ln == 63) wsum[wv] = x;
    __syncthreads();
    if (t < 16) {
      int w = wsum[t];
#pragma unroll
      for (int off = 1; off < 16; off <<= 1) {
        int y = __shfl_up(w, off, 64);
        if (t >= off) w += y;
      }
      wsum[t] = w;
    }
    __syncthreads();
    const int woff = wv ? wsum[wv - 1] : 0;
    if (i < NN) rowptr[i] = carry + woff + x - v;
    const int total = wsum[15];
    __syncthreads();
    if (t == 0) carry += total;
    __syncthreads();
  }
  if (t == 0) rowptr[NN] = NE;
}

__global__ void k_fill(const int* __restrict__ ei, const int* __restrict__ rowptr,
                       int* __restrict__ cursor, int* __restrict__ csr,
                       int* __restrict__ eidA, int* __restrict__ dstA,
                       const int* __restrict__ flags) {
  const int e = blockIdx.x * 256 + threadIdx.x;
  if (e >= NE) return;
  const int i64 = flags[1];
  const int s = i64 ? ei[2 * e] : ei[e];
  const int d = i64 ? ei[2 * (NE + e)] : ei[NE + e];
  const int pos = rowptr[d] + atomicAdd(&cursor[d], 1);
  csr[pos] = s;
  eidA[pos] = e;
  dstA[pos] = d;
}

// canonicalize neighbor order: sort (src,eid) pairs within each row so every
// downstream fp32 sum and output write is bitwise stable across graph replays
__global__ void k_sortrows(int* __restrict__ csr, int* __restrict__ eidA,
                           const int* __restrict__ rowptr) {
  const int n = blockIdx.x * 256 + threadIdx.x;
  if (n >= NN) return;
  const int rs = rowptr[n], re = rowptr[n + 1];
  for (int i = rs + 1; i < re; i++) {
    const int v = csr[i], id = eidA[i];
    int j = i - 1;
    while (j >= rs && (csr[j] > v || (csr[j] == v && eidA[j] > id))) {
      csr[j + 1] = csr[j]; eidA[j + 1] = eidA[j]; j--;
    }
    csr[j + 1] = v; eidA[j + 1] = id;
  }
}

// ---------------- input projection: hb0 = bf16(x @ W_in^T + b_in) -----------
__global__ void k_inproj(const void* __restrict__ x,
                         const unsigned short* __restrict__ wc,
                         unsigned short* __restrict__ hb,
                         const int* __restrict__ flags) {
  const int gid = blockIdx.x * 256 + threadIdx.x;  // NN*128 threads
  const int n = gid >> 7, j = gid & 127;
  float xv[16];
  if (flags[0]) {
    const float4* xp = (const float4*)((const float*)x + (size_t)n * 16);
#pragma unroll
    for (int q = 0; q < 4; q++) {
      float4 t = xp[q];
      xv[q * 4 + 0] = t.x; xv[q * 4 + 1] = t.y; xv[q * 4 + 2] = t.z; xv[q * 4 + 3] = t.w;
    }
  } else {
    const unsigned short* xu = (const unsigned short*)x + (size_t)n * 16;
#pragma unroll
    for (int q = 0; q < 2; q++) {
      union { int4 v; unsigned short u[8]; } t;
      t.v = *(const int4*)(xu + q * 8);
#pragma unroll
      for (int i = 0; i < 8; i++) xv[q * 8 + i] = b2f(t.u[i]);
    }
  }
  float s = b2f(wc[O_BIN + j]);
  const unsigned short* wrow = wc + O_WIN + j * 16;
#pragma unroll
  for (int q = 0; q < 2; q++) {
    union { int4 v; unsigned short u[8]; } w;
    w.v = *(const int4*)(wrow + q * 8);
#pragma unroll
    for (int i = 0; i < 8; i++) s += b2f(w.u[i]) * xv[q * 8 + i];
  }
  hb[gid] = f2b(s);
}

// ---------------- aggregation: mean of neighbor rows, one wave per node -----
// 50k waves for latency hiding; coalesced 256B row reads; 4-wide unroll.
// writes bf16 agg into the destination h-buffer (later overwritten in place
// by k_sage_mfma — deterministic because csr rows are sorted).
__global__ __launch_bounds__(256) void k_agg(
    const unsigned short* __restrict__ hin, const int* __restrict__ csr,
    const int* __restrict__ rowptr, unsigned short* __restrict__ aggb) {
  const int tid = threadIdx.x;
  const int n = blockIdx.x * 4 + (tid >> 6);  // 12500 blocks * 4 waves
  const int L = tid & 63;
  const int rs = rowptr[n], re = rowptr[n + 1];
  const unsigned int* hw = (const unsigned int*)hin;
  float s0 = 0.f, s1 = 0.f;
  int e = rs;
  for (; e + 4 <= re; e += 4) {
    const unsigned int u0 = hw[(size_t)csr[e] * 64 + L];
    const unsigned int u1 = hw[(size_t)csr[e + 1] * 64 + L];
    const unsigned int u2 = hw[(size_t)csr[e + 2] * 64 + L];
    const unsigned int u3 = hw[(size_t)csr[e + 3] * 64 + L];
    s0 += b2f((unsigned short)(u0 & 0xffff)); s1 += b2f((unsigned short)(u0 >> 16));
    s0 += b2f((unsigned short)(u1 & 0xffff)); s1 += b2f((unsigned short)(u1 >> 16));
    s0 += b2f((unsigned short)(u2 & 0xffff)); s1 += b2f((unsigned short)(u2 >> 16));
    s0 += b2f((unsigned short)(u3 & 0xffff)); s1 += b2f((unsigned short)(u3 >> 16));
  }
  for (; e < re; e++) {
    const unsigned int u0 = hw[(size_t)csr[e] * 64 + L];
    s0 += b2f((unsigned short)(u0 & 0xffff));
    s1 += b2f((unsigned short)(u0 >> 16));
  }
  const int dg = re - rs;
  const float rd = 1.0f / (float)(dg > 1 ? dg : 1);
  const unsigned int o = (unsigned int)f2b(s0 * rd) | ((unsigned int)f2b(s1 * rd) << 16);
  ((unsigned int*)aggb)[(size_t)n * 64 + L] = o;
}

// ---------------- SAGE layer: MFMA GEMM [agg|h] @ [Wl|Wr]^T + LN + ReLU -----
// hagg holds bf16 agg on entry (rows n0..n0+63 read only by this block),
// overwritten with the layer output.
__global__ __launch_bounds__(256) void k_sage_mfma(
    const unsigned short* __restrict__ hin, unsigned short* __restrict__ hagg,
    const unsigned short* __restrict__ wc, int l) {
  __shared__ __align__(16) unsigned char As[64 * 528];  // 33792 B
  __shared__ float red1[64][4];
  __shared__ float red2[64][4];
  __shared__ float mr[64][2];
  const int tid = threadIdx.x;
  const int wv = tid >> 6;
  const int L = tid & 63;
  const int l15 = L & 15;
  const int q = L >> 4;
  const int n0 = blockIdx.x * 64;

  // register-resident weight fragments: wave wv covers output cols wv*32..+31
  bf16x8 wf[2][8];
  float blv[2], gv[2], bv[2];
#pragma unroll
  for (int nt = 0; nt < 2; nt++) {
    const int jj = (wv * 2 + nt) * 16 + l15;
#pragma unroll
    for (int kc = 0; kc < 8; kc++) {
      const unsigned short* src = (kc < 4)
          ? wc + O_WL + ((size_t)l * 128 + jj) * 128 + kc * 32 + q * 8
          : wc + O_WR + ((size_t)l * 128 + jj) * 128 + (kc - 4) * 32 + q * 8;
      wf[nt][kc] = *(const bf16x8*)src;
    }
    blv[nt] = b2f(wc[O_BL + l * 128 + jj]);
    gv[nt]  = b2f(wc[O_LNG + l * 128 + jj]);
    bv[nt]  = b2f(wc[O_LNB + l * 128 + jj]);
  }

  // stage A = [agg | h] rows, 528B stride
  for (int c = tid; c < 2048; c += 256) {
    const int row = c >> 5, part = c & 31;
    int node = n0 + row; if (node > NN - 1) node = NN - 1;
    const unsigned short* src = (part < 16)
        ? hagg + (size_t)node * 128 + part * 8
        : hin + (size_t)node * 128 + (part - 16) * 8;
    *(int4*)(As + row * 528 + part * 16) = *(const int4*)src;
  }
  __syncthreads();

  f32x4 acc[4][2];
#pragma unroll
  for (int mt = 0; mt < 4; mt++)
#pragma unroll
    for (int nt = 0; nt < 2; nt++) acc[mt][nt] = (f32x4)(0.0f);
#pragma unroll
  for (int kc = 0; kc < 8; kc++) {
#pragma unroll
    for (int mt = 0; mt < 4; mt++) {
      const bf16x8 a = *(const bf16x8*)(As + (mt * 16 + l15) * 528 + (kc * 32 + q * 8) * 2);
#pragma unroll
      for (int nt = 0; nt < 2; nt++)
        acc[mt][nt] = __builtin_amdgcn_mfma_f32_16x16x32_bf16(a, wf[nt][kc], acc[mt][nt], 0, 0, 0);
    }
  }
  // add bias, then per-row partial sums (over this wave's 32 cols)
#pragma unroll
  for (int mt = 0; mt < 4; mt++) {
#pragma unroll
    for (int rg = 0; rg < 4; rg++) {
      acc[mt][0][rg] += blv[0];
      acc[mt][1][rg] += blv[1];
      float s = acc[mt][0][rg] + acc[mt][1][rg];
      float s2 = acc[mt][0][rg] * acc[mt][0][rg] + acc[mt][1][rg] * acc[mt][1][rg];
#pragma unroll
      for (int m = 1; m < 16; m <<= 1) {
        s += __shfl_xor(s, m, 64);
        s2 += __shfl_xor(s2, m, 64);
      }
      if (l15 == 0) {
        const int row = mt * 16 + q * 4 + rg;
        red1[row][wv] = s; red2[row][wv] = s2;
      }
    }
  }
  __syncthreads();
  if (tid < 64) {
    const float s1 = red1[tid][0] + red1[tid][1] + red1[tid][2] + red1[tid][3];
    const float s2 = red2[tid][0] + red2[tid][1] + red2[tid][2] + red2[tid][3];
    const float mu = s1 * 0.0078125f;
    const float var = s2 * 0.0078125f - mu * mu;
    mr[tid][0] = mu;
    mr[tid][1] = rsqrtf(var + 1e-5f);
  }
  __syncthreads();
#pragma unroll
  for (int mt = 0; mt < 4; mt++) {
#pragma unroll
    for (int rg = 0; rg < 4; rg++) {
      const int row = mt * 16 + q * 4 + rg;
      const int node = n0 + row;
      if (node < NN) {
        const float mu = mr[row][0], rstd = mr[row][1];
#pragma unroll
        for (int nt = 0; nt < 2; nt++) {
          const float o = (acc[mt][nt][rg] - mu) * rstd * gv[nt] + bv[nt];
          hagg[(size_t)node * 128 + (wv * 2 + nt) * 16 + l15] = f2b(fmaxf(o, 0.f));
        }
      }
    }
  }
}

// ---------------- edge head: dst-sorted tiles + direct-global MFMA MLP ------
// Edges processed in CSR (dst-sorted) order: a 64-edge tile hits ~4 distinct
// dst rows (L1/L2 resident) and contiguous index loads; out scattered by eid.
// LDS: Ue[64][64B]=4096  E1[64][272B]=17408  E2[64][136B]=8704  → 30208 B
__global__ __launch_bounds__(256) void k_edge_mfma(
    const unsigned short* __restrict__ hb, const int* __restrict__ csr,
    const int* __restrict__ eidA, const int* __restrict__ dstA,
    const void* __restrict__ ea, const unsigned short* __restrict__ W1p,
    const unsigned short* __restrict__ wc, void* __restrict__ out,
    const int* __restrict__ flags) {
  __shared__ __align__(16) unsigned char sm[30208];
  unsigned char* const Ue = sm;
  unsigned char* const E1 = sm + 4096;
  unsigned char* const E2 = sm + 21504;
  const int tid = threadIdx.x;
  const int wv = tid >> 6;
  const int L = tid & 63;
  const int l15 = L & 15;
  const int q = L >> 4;
  const int f32 = flags[0];

  // zero the K-padding region of Ue (bytes 16..63 of each 64B row), once
  for (int i = tid; i < 64 * 12; i += 256)
    *(int*)(Ue + (i / 12) * 64 + 16 + (i % 12) * 4) = 0;

  // weights: wave wv covers GEMM1 cols wv*32..+31, GEMM2 cols wv*16..+15
  bf16x8 w1f[2][9];
  float b1v[2];
#pragma unroll
  for (int nt = 0; nt < 2; nt++) {
    const int jj = (wv * 2 + nt) * 16 + l15;
#pragma unroll
    for (int cc = 0; cc < 9; cc++)
      w1f[nt][cc] = *(const bf16x8*)(W1p + jj * 288 + cc * 32 + q * 8);
    b1v[nt] = b2f(wc[O_B1 + jj]);
  }
  bf16x8 w2f[4];
  const int jj2 = wv * 16 + l15;
#pragma unroll
  for (int kc = 0; kc < 4; kc++)
    w2f[kc] = *(const bf16x8*)(wc + O_W2 + jj2 * 128 + kc * 32 + q * 8);
  const float b2v = b2f(wc[O_B2 + jj2]);
  float w3v[16];
#pragma unroll
  for (int i = 0; i < 16; i++) w3v[i] = b2f(wc[O_W3 + q * 16 + i]);
  const float b3f = b2f(wc[O_B3]);

  for (int t = blockIdx.x; t < NE / 64; t += gridDim.x) {
    __syncthreads();  // protect Ue/E2 from previous tile's reads
    const int pbase = t * 64;
    // stage Ue (edge_attr[eid] → bf16)
    if (tid < 64) {
      const int e = eidA[pbase + tid];
      if (f32) {
        const float4* ep = (const float4*)((const float*)ea + (size_t)e * 8);
        const float4 a = ep[0], b = ep[1];
        union { ushort4 v[2]; int4 i; } o;
        o.v[0].x = f2b(a.x); o.v[0].y = f2b(a.y); o.v[0].z = f2b(a.z); o.v[0].w = f2b(a.w);
        o.v[1].x = f2b(b.x); o.v[1].y = f2b(b.y); o.v[1].z = f2b(b.z); o.v[1].w = f2b(b.w);
        *(int4*)(Ue + tid * 64) = o.i;
      } else {
        *(int4*)(Ue + tid * 64) = *(const int4*)((const unsigned short*)ea + (size_t)e * 8);
      }
    }
    // per-lane edge endpoints for rows mt*16+l15 (contiguous index loads)
    int sidx[4], didx[4];
#pragma unroll
    for (int mt = 0; mt < 4; mt++) {
      const int p = pbase + mt * 16 + l15;
      sidx[mt] = csr[p];
      didx[mt] = dstA[p];
    }
    __syncthreads();  // Ue ready

    // GEMM1: e1[64][128], A-fragments straight from global
    f32x4 acc1[4][2];
#pragma unroll
    for (int mt = 0; mt < 4; mt++)
#pragma unroll
      for (int nt = 0; nt < 2; nt++) acc1[mt][nt] = (f32x4)(0.0f);
#pragma unroll
    for (int cc = 0; cc < 4; cc++) {
#pragma unroll
      for (int mt = 0; mt < 4; mt++) {
        const bf16x8 a = *(const bf16x8*)(hb + (size_t)sidx[mt] * 128 + cc * 32 + q * 8);
#pragma unroll
        for (int nt = 0; nt < 2; nt++)
          acc1[mt][nt] = __builtin_amdgcn_mfma_f32_16x16x32_bf16(a, w1f[nt][cc], acc1[mt][nt], 0, 0, 0);
      }
    }
#pragma unroll
    for (int cc = 4; cc < 8; cc++) {
#pragma unroll
      for (int mt = 0; mt < 4; mt++) {
        const bf16x8 a = *(const bf16x8*)(hb + (size_t)didx[mt] * 128 + (cc - 4) * 32 + q * 8);
#pragma unroll
        for (int nt = 0; nt < 2; nt++)
          acc1[mt][nt] = __builtin_amdgcn_mfma_f32_16x16x32_bf16(a, w1f[nt][cc], acc1[mt][nt], 0, 0, 0);
      }
    }
#pragma unroll
    for (int mt = 0; mt < 4; mt++) {
      const bf16x8 a = *(const bf16x8*)(Ue + (mt * 16 + l15) * 64 + q * 16);
#pragma unroll
      for (int nt = 0; nt < 2; nt++)
        acc1[mt][nt] = __builtin_amdgcn_mfma_f32_16x16x32_bf16(a, w1f[nt][8], acc1[mt][nt], 0, 0, 0);
    }
#pragma unroll
    for (int mt = 0; mt < 4; mt++)
#pragma unroll
      for (int nt = 0; nt < 2; nt++)
#pragma unroll
        for (int rg = 0; rg < 4; rg++) {
          const int er = mt * 16 + q * 4 + rg;
          const int jj = (wv * 2 + nt) * 16 + l15;
          *(unsigned short*)(E1 + er * 272 + jj * 2) =
              f2b(fmaxf(acc1[mt][nt][rg] + b1v[nt], 0.f));
        }
    __syncthreads();

    // GEMM2: e2[64][64], wave covers 16 cols, all 64 rows
    f32x4 acc2[4];
#pragma unroll
    for (int mt = 0; mt < 4; mt++) acc2[mt] = (f32x4)(0.0f);
#pragma unroll
    for (int kc = 0; kc < 4; kc++) {
#pragma unroll
      for (int mt = 0; mt < 4; mt++) {
        const bf16x8 a = *(const bf16x8*)(E1 + (mt * 16 + l15) * 272 + (kc * 32 + q * 8) * 2);
        acc2[mt] = __builtin_amdgcn_mfma_f32_16x16x32_bf16(a, w2f[kc], acc2[mt], 0, 0, 0);
      }
    }
#pragma unroll
    for (int mt = 0; mt < 4; mt++)
#pragma unroll
      for (int rg = 0; rg < 4; rg++) {
        const int er = mt * 16 + q * 4 + rg;
        *(unsigned short*)(E2 + er * 136 + jj2 * 2) =
            f2b(fmaxf(acc2[mt][rg] + b2v, 0.f));
      }
    __syncthreads();

    // GEMM3: logit per edge, dot-64 via 4 lane-groups + shuffle; scatter by eid
    const int el = wv * 16 + l15;
    float acc = 0.f;
#pragma unroll
    for (int i4 = 0; i4 < 4; i4++) {
      const bf16x4 v = *(const bf16x4*)(E2 + el * 136 + q * 32 + i4 * 8);
      acc += b2f((unsigned short)v[0]) * w3v[i4 * 4 + 0];
      acc += b2f((unsigned short)v[1]) * w3v[i4 * 4 + 1];
      acc += b2f((unsigned short)v[2]) * w3v[i4 * 4 + 2];
      acc += b2f((unsigned short)v[3]) * w3v[i4 * 4 + 3];
    }
    acc += __shfl_xor(acc, 16, 64);
    acc += __shfl_xor(acc, 32, 64);
    if (q == 0) {
      const int e = eidA[pbase + el];
      const float r = acc + b3f;
      if (f32) ((float*)out)[e] = r;
      else     ((unsigned short*)out)[e] = f2b(r);
    }
  }
}

extern "C" void kernel_launch(void* const* d_in, const int* in_sizes, int n_in,
                              void* d_out, int out_size, void* d_ws, size_t ws_size,
                              hipStream_t stream) {
  const void* x  = d_in[0];
  const int*  ei = (const int*)d_in[1];
  const void* ea = d_in[2];

  char* ws = (char*)d_ws;
  int*            flags  = (int*)(ws + WS_FLAGS);
  unsigned short* wc     = (unsigned short*)(ws + WS_WC);
  int*            cnt    = (int*)(ws + WS_CNT);
  int*            rowptr = (int*)(ws + WS_ROWP);
  int*            cursor = (int*)(ws + WS_CUR);
  int*            csr    = (int*)(ws + WS_CSR);
  int*            eidA   = (int*)(ws + WS_EID);
  int*            dstA   = (int*)(ws + WS_DST);
  unsigned short* W1p    = (unsigned short*)(ws + WS_W1P);
  unsigned short* hb0    = (unsigned short*)(ws + WS_HB0);
  unsigned short* hb1    = (unsigned short*)(ws + WS_HB1);

  if (ws_size < WS_NEED) {  // diagnostic: error ≈ 1.35 signals this path
    k_fallback<<<3125, 256, 0, stream>>>((unsigned short*)d_out);
    return;
  }

  k_probe<<<1, 64, 0, stream>>>((const unsigned short*)x, ei, flags);
  k_cvt_w<<<(W_TOTAL + 255) / 256, 256, 0, stream>>>(
      d_in[3], d_in[4], d_in[5], d_in[6], d_in[7], d_in[8], d_in[9],
      d_in[10], d_in[11], d_in[12], d_in[13], d_in[14], d_in[15], wc, flags);
  k_build_w1p<<<144, 256, 0, stream>>>(wc, W1p);

  hipMemsetAsync(cnt, 0, NN * sizeof(int), stream);
  hipMemsetAsync(cursor, 0, NN * sizeof(int), stream);
  k_hist<<<3125, 256, 0, stream>>>(ei, cnt, flags);
  k_scan<<<1, 1024, 0, stream>>>(cnt, rowptr);
  k_fill<<<3125, 256, 0, stream>>>(ei, rowptr, cursor, csr, eidA, dstA, flags);
  k_sortrows<<<(NN + 255) / 256, 256, 0, stream>>>(csr, eidA, rowptr);

  k_inproj<<<NN * 128 / 256, 256, 0, stream>>>(x, wc, hb0, flags);

  unsigned short* cur = hb0;
  unsigned short* nxt = hb1;
  for (int l = 0; l < 4; l++) {
    k_agg<<<12500, 256, 0, stream>>>(cur, csr, rowptr, nxt);
    k_sage_mfma<<<782, 256, 0, stream>>>(cur, nxt, wc, l);
    unsigned short* tmp = cur; cur = nxt; nxt = tmp;
  }
  // after 4 swaps, final h is back in hb0 (= cur)
  k_edge_mfma<<<3125, 256, 0, stream>>>(cur, csr, eidA, dstA, ea, W1p, wc, d_out, flags);
}

// Round 8
// 849.735 us; speedup vs baseline: 21.2941x; 1.0024x over previous
//
#include <hip/hip_runtime.h>
#include <stdint.h>

#define NN 50000
#define NE 800000

// canonical bf16 weight-block element offsets
#define O_WIN 0
#define O_BIN 2048
#define O_WL  2176
#define O_BL  67712
#define O_WR  68224
#define O_LNG 133760
#define O_LNB 134272
#define O_W1  134784
#define O_B1  168576
#define O_W2  168704
#define O_B2  176896
#define O_W3  176960
#define O_B3  177024
#define W_TOTAL 177025

// ws layout (bytes)
#define WS_FLAGS 0          //      256 B
#define WS_WC    512        //  354,050 B
#define WS_CNT   355072     //  200,000 B
#define WS_ROWP  555520     //  200,004 B
#define WS_CUR   756224     //  200,000 B
#define WS_CSR   956928     // 3,200,000 B (src per CSR slot)
#define WS_EID   4156928    // 3,200,000 B (edge id per CSR slot)
#define WS_DST   7356928    // 3,200,000 B (dst per CSR slot)
#define WS_W1P   10556928   //     73,728 B
#define WS_HB0   10630656   // 12,800,000 B
#define WS_HB1   23430656   // 12,800,000 B
#define WS_NEED  36230656

typedef float f32x4 __attribute__((ext_vector_type(4)));
typedef short bf16x8 __attribute__((ext_vector_type(8)));
typedef short bf16x4 __attribute__((ext_vector_type(4)));

__device__ __forceinline__ float b2f(unsigned short u) {
  union { unsigned int i; float f; } v; v.i = ((unsigned int)u) << 16; return v.f;
}
__device__ __forceinline__ unsigned short f2b(float f) {
  union { float f; unsigned int i; } v; v.f = f;
  return (unsigned short)((v.i + 0x7fffu + ((v.i >> 16) & 1u)) >> 16);
}

// ---------------- fallback diagnostic: ws too small → constant 0.5 ----------
__global__ void k_fallback(unsigned short* __restrict__ out) {
  int gid = blockIdx.x * 256 + threadIdx.x;
  if (gid < NE) out[gid] = 0x3F00;
}

// ---------------- dtype probe: flags[0]=fp32 float tensors, flags[1]=int64 --
__global__ void k_probe(const unsigned short* __restrict__ x_u,
                        const int* __restrict__ ei32, int* __restrict__ flags) {
  const int t = threadIdx.x;  // 64 threads, 1 wave
  int insane = 0;
  for (int i = t; i < 512; i += 64) {
    float v = b2f(x_u[i]);
    if (!(fabsf(v) < 1e4f)) insane++;
  }
#pragma unroll
  for (int off = 1; off < 64; off <<= 1) insane += __shfl_xor(insane, off, 64);
  int nz = 0;
  for (int i = t; i < 128; i += 64) nz |= (ei32[2 * i + 1] != 0);
  unsigned long long m = __ballot(nz != 0);
  if (t == 0) {
    flags[0] = (insane >= 16) ? 1 : 0;
    flags[1] = (m == 0ULL) ? 1 : 0;
  }
}

// ---------------- canonicalize the 13 weight tensors to bf16 ----------------
__global__ void k_cvt_w(const void* W_in, const void* b_in, const void* Wl,
                        const void* bl, const void* Wr, const void* lng,
                        const void* lnb, const void* W1, const void* b1,
                        const void* W2, const void* b2, const void* W3,
                        const void* b3, unsigned short* __restrict__ wc,
                        const int* __restrict__ flags) {
  const int gid = blockIdx.x * 256 + threadIdx.x;
  if (gid >= W_TOTAL) return;
  const int f32 = flags[0];
  const void* src; int off;
  if      (gid < O_BIN) { src = W_in; off = gid - O_WIN; }
  else if (gid < O_WL)  { src = b_in; off = gid - O_BIN; }
  else if (gid < O_BL)  { src = Wl;   off = gid - O_WL;  }
  else if (gid < O_WR)  { src = bl;   off = gid - O_BL;  }
  else if (gid < O_LNG) { src = Wr;   off = gid - O_WR;  }
  else if (gid < O_LNB) { src = lng;  off = gid - O_LNG; }
  else if (gid < O_W1)  { src = lnb;  off = gid - O_LNB; }
  else if (gid < O_B1)  { src = W1;   off = gid - O_W1;  }
  else if (gid < O_W2)  { src = b1;   off = gid - O_B1;  }
  else if (gid < O_B2)  { src = W2;   off = gid - O_W2;  }
  else if (gid < O_W3)  { src = b2;   off = gid - O_B2;  }
  else if (gid < O_B3)  { src = W3;   off = gid - O_W3;  }
  else                  { src = b3;   off = 0;           }
  wc[gid] = f32 ? f2b(((const float*)src)[off]) : ((const unsigned short*)src)[off];
}

// ---------------- W1 padded copy: wc[128][264] -> W1p[128][288] -------------
__global__ void k_build_w1p(const unsigned short* __restrict__ wc,
                            unsigned short* __restrict__ W1p) {
  int gid = blockIdx.x * 256 + threadIdx.x;  // 128*288 = 36864
  if (gid >= 128 * 288) return;
  int j = gid / 288, k = gid - j * 288;
  W1p[gid] = (k < 264) ? wc[O_W1 + j * 264 + k] : (unsigned short)0;
}

// ---------------- CSR build: histogram -> scan -> fill ----------------------
// (no sort needed: aggregation uses order-independent integer accumulation,
//  and every edge-head output depends only on its own slot's (src,dst,eid))
__global__ void k_hist(const int* __restrict__ ei, int* __restrict__ cnt,
                       const int* __restrict__ flags) {
  const int e = blockIdx.x * 256 + threadIdx.x;
  if (e >= NE) return;
  const int d = flags[1] ? ei[2 * (NE + e)] : ei[NE + e];
  atomicAdd(&cnt[d], 1);
}

__global__ __launch_bounds__(1024) void k_scan(const int* __restrict__ cnt,
                                               int* __restrict__ rowptr) {
  __shared__ int wsum[16];
  __shared__ int carry;
  const int t = threadIdx.x, wv = t >> 6, ln = t & 63;
  if (t == 0) carry = 0;
  __syncthreads();
  for (int base = 0; base < NN; base += 1024) {
    const int i = base + t;
    const int v = (i < NN) ? cnt[i] : 0;
    int x = v;
#pragma unroll
    for (int off = 1; off < 64; off <<= 1) {
      int y = __shfl_up(x, off, 64);
      if (ln >= off) x += y;
    }
    if (ln == 63) wsum[wv] = x;
    __syncthreads();
    if (t < 16) {
      int w = wsum[t];
#pragma unroll
      for (int off = 1; off < 16; off <<= 1) {
        int y = __shfl_up(w, off, 64);
        if (t >= off) w += y;
      }
      wsum[t] = w;
    }
    __syncthreads();
    const int woff = wv ? wsum[wv - 1] : 0;
    if (i < NN) rowptr[i] = carry + woff + x - v;
    const int total = wsum[15];
    __syncthreads();
    if (t == 0) carry += total;
    __syncthreads();
  }
  if (t == 0) rowptr[NN] = NE;
}

__global__ void k_fill(const int* __restrict__ ei, const int* __restrict__ rowptr,
                       int* __restrict__ cursor, int* __restrict__ csr,
                       int* __restrict__ eidA, int* __restrict__ dstA,
                       const int* __restrict__ flags) {
  const int e = blockIdx.x * 256 + threadIdx.x;
  if (e >= NE) return;
  const int i64 = flags[1];
  const int s = i64 ? ei[2 * e] : ei[e];
  const int d = i64 ? ei[2 * (NE + e)] : ei[NE + e];
  const int pos = rowptr[d] + atomicAdd(&cursor[d], 1);
  csr[pos] = s;
  eidA[pos] = e;
  dstA[pos] = d;
}

// ---------------- input projection: hb0 = bf16(x @ W_in^T + b_in) -----------
__global__ void k_inproj(const void* __restrict__ x,
                         const unsigned short* __restrict__ wc,
                         unsigned short* __restrict__ hb,
                         const int* __restrict__ flags) {
  const int gid = blockIdx.x * 256 + threadIdx.x;  // NN*128 threads
  const int n = gid >> 7, j = gid & 127;
  float xv[16];
  if (flags[0]) {
    const float4* xp = (const float4*)((const float*)x + (size_t)n * 16);
#pragma unroll
    for (int q = 0; q < 4; q++) {
      float4 t = xp[q];
      xv[q * 4 + 0] = t.x; xv[q * 4 + 1] = t.y; xv[q * 4 + 2] = t.z; xv[q * 4 + 3] = t.w;
    }
  } else {
    const unsigned short* xu = (const unsigned short*)x + (size_t)n * 16;
#pragma unroll
    for (int q = 0; q < 2; q++) {
      union { int4 v; unsigned short u[8]; } t;
      t.v = *(const int4*)(xu + q * 8);
#pragma unroll
      for (int i = 0; i < 8; i++) xv[q * 8 + i] = b2f(t.u[i]);
    }
  }
  float s = b2f(wc[O_BIN + j]);
  const unsigned short* wrow = wc + O_WIN + j * 16;
#pragma unroll
  for (int q = 0; q < 2; q++) {
    union { int4 v; unsigned short u[8]; } w;
    w.v = *(const int4*)(wrow + q * 8);
#pragma unroll
    for (int i = 0; i < 8; i++) s += b2f(w.u[i]) * xv[q * 8 + i];
  }
  hb[gid] = f2b(s);
}

// ---------------- aggregation: mean of neighbor rows, one wave per node -----
// fixed-point int64 accumulation (scale 2^24): exact integer sum is order-
// independent => bitwise-deterministic without sorting the CSR rows.
// |h| <= ~16 so int32 terms and the int64 sum cannot overflow; quantization
// error <= deg*2^-24 — invisible next to the bf16 rounding of the result.
__global__ __launch_bounds__(256) void k_agg(
    const unsigned short* __restrict__ hin, const int* __restrict__ csr,
    const int* __restrict__ rowptr, unsigned short* __restrict__ aggb) {
  const int tid = threadIdx.x;
  const int n = blockIdx.x * 4 + (tid >> 6);  // 12500 blocks * 4 waves
  const int L = tid & 63;
  const int rs = rowptr[n], re = rowptr[n + 1];
  const unsigned int* hw = (const unsigned int*)hin;
  long long t0 = 0, t1 = 0;
  int e = rs;
  for (; e + 4 <= re; e += 4) {
    const unsigned int u0 = hw[(size_t)csr[e] * 64 + L];
    const unsigned int u1 = hw[(size_t)csr[e + 1] * 64 + L];
    const unsigned int u2 = hw[(size_t)csr[e + 2] * 64 + L];
    const unsigned int u3 = hw[(size_t)csr[e + 3] * 64 + L];
    t0 += (int)(b2f((unsigned short)(u0 & 0xffff)) * 16777216.0f);
    t1 += (int)(b2f((unsigned short)(u0 >> 16)) * 16777216.0f);
    t0 += (int)(b2f((unsigned short)(u1 & 0xffff)) * 16777216.0f);
    t1 += (int)(b2f((unsigned short)(u1 >> 16)) * 16777216.0f);
    t0 += (int)(b2f((unsigned short)(u2 & 0xffff)) * 16777216.0f);
    t1 += (int)(b2f((unsigned short)(u2 >> 16)) * 16777216.0f);
    t0 += (int)(b2f((unsigned short)(u3 & 0xffff)) * 16777216.0f);
    t1 += (int)(b2f((unsigned short)(u3 >> 16)) * 16777216.0f);
  }
  for (; e < re; e++) {
    const unsigned int u0 = hw[(size_t)csr[e] * 64 + L];
    t0 += (int)(b2f((unsigned short)(u0 & 0xffff)) * 16777216.0f);
    t1 += (int)(b2f((unsigned short)(u0 >> 16)) * 16777216.0f);
  }
  const int dg = re - rs;
  const float rd = (1.0f / 16777216.0f) / (float)(dg > 1 ? dg : 1);
  const float s0 = (float)t0 * rd;
  const float s1 = (float)t1 * rd;
  const unsigned int o = (unsigned int)f2b(s0) | ((unsigned int)f2b(s1) << 16);
  ((unsigned int*)aggb)[(size_t)n * 64 + L] = o;
}

// ---------------- SAGE layer: MFMA GEMM [agg|h] @ [Wl|Wr]^T + LN + ReLU -----
// hagg holds bf16 agg on entry (rows n0..n0+63 read only by this block),
// overwritten with the layer output.
__global__ __launch_bounds__(256) void k_sage_mfma(
    const unsigned short* __restrict__ hin, unsigned short* __restrict__ hagg,
    const unsigned short* __restrict__ wc, int l) {
  __shared__ __align__(16) unsigned char As[64 * 528];  // 33792 B
  __shared__ float red1[64][4];
  __shared__ float red2[64][4];
  __shared__ float mr[64][2];
  const int tid = threadIdx.x;
  const int wv = tid >> 6;
  const int L = tid & 63;
  const int l15 = L & 15;
  const int q = L >> 4;
  const int n0 = blockIdx.x * 64;

  // register-resident weight fragments: wave wv covers output cols wv*32..+31
  bf16x8 wf[2][8];
  float blv[2], gv[2], bv[2];
#pragma unroll
  for (int nt = 0; nt < 2; nt++) {
    const int jj = (wv * 2 + nt) * 16 + l15;
#pragma unroll
    for (int kc = 0; kc < 8; kc++) {
      const unsigned short* src = (kc < 4)
          ? wc + O_WL + ((size_t)l * 128 + jj) * 128 + kc * 32 + q * 8
          : wc + O_WR + ((size_t)l * 128 + jj) * 128 + (kc - 4) * 32 + q * 8;
      wf[nt][kc] = *(const bf16x8*)src;
    }
    blv[nt] = b2f(wc[O_BL + l * 128 + jj]);
    gv[nt]  = b2f(wc[O_LNG + l * 128 + jj]);
    bv[nt]  = b2f(wc[O_LNB + l * 128 + jj]);
  }

  // stage A = [agg | h] rows, 528B stride
  for (int c = tid; c < 2048; c += 256) {
    const int row = c >> 5, part = c & 31;
    int node = n0 + row; if (node > NN - 1) node = NN - 1;
    const unsigned short* src = (part < 16)
        ? hagg + (size_t)node * 128 + part * 8
        : hin + (size_t)node * 128 + (part - 16) * 8;
    *(int4*)(As + row * 528 + part * 16) = *(const int4*)src;
  }
  __syncthreads();

  f32x4 acc[4][2];
#pragma unroll
  for (int mt = 0; mt < 4; mt++)
#pragma unroll
    for (int nt = 0; nt < 2; nt++) acc[mt][nt] = (f32x4)(0.0f);
#pragma unroll
  for (int kc = 0; kc < 8; kc++) {
#pragma unroll
    for (int mt = 0; mt < 4; mt++) {
      const bf16x8 a = *(const bf16x8*)(As + (mt * 16 + l15) * 528 + (kc * 32 + q * 8) * 2);
#pragma unroll
      for (int nt = 0; nt < 2; nt++)
        acc[mt][nt] = __builtin_amdgcn_mfma_f32_16x16x32_bf16(a, wf[nt][kc], acc[mt][nt], 0, 0, 0);
    }
  }
  // add bias, then per-row partial sums (over this wave's 32 cols)
#pragma unroll
  for (int mt = 0; mt < 4; mt++) {
#pragma unroll
    for (int rg = 0; rg < 4; rg++) {
      acc[mt][0][rg] += blv[0];
      acc[mt][1][rg] += blv[1];
      float s = acc[mt][0][rg] + acc[mt][1][rg];
      float s2 = acc[mt][0][rg] * acc[mt][0][rg] + acc[mt][1][rg] * acc[mt][1][rg];
#pragma unroll
      for (int m = 1; m < 16; m <<= 1) {
        s += __shfl_xor(s, m, 64);
        s2 += __shfl_xor(s2, m, 64);
      }
      if (l15 == 0) {
        const int row = mt * 16 + q * 4 + rg;
        red1[row][wv] = s; red2[row][wv] = s2;
      }
    }
  }
  __syncthreads();
  if (tid < 64) {
    const float s1 = red1[tid][0] + red1[tid][1] + red1[tid][2] + red1[tid][3];
    const float s2 = red2[tid][0] + red2[tid][1] + red2[tid][2] + red2[tid][3];
    const float mu = s1 * 0.0078125f;
    const float var = s2 * 0.0078125f - mu * mu;
    mr[tid][0] = mu;
    mr[tid][1] = rsqrtf(var + 1e-5f);
  }
  __syncthreads();
#pragma unroll
  for (int mt = 0; mt < 4; mt++) {
#pragma unroll
    for (int rg = 0; rg < 4; rg++) {
      const int row = mt * 16 + q * 4 + rg;
      const int node = n0 + row;
      if (node < NN) {
        const float mu = mr[row][0], rstd = mr[row][1];
#pragma unroll
        for (int nt = 0; nt < 2; nt++) {
          const float o = (acc[mt][nt][rg] - mu) * rstd * gv[nt] + bv[nt];
          hagg[(size_t)node * 128 + (wv * 2 + nt) * 16 + l15] = f2b(fmaxf(o, 0.f));
        }
      }
    }
  }
}

// ---------------- edge head: dst-sorted tiles, XCD-sliced, MFMA MLP ---------
// 8*391 blocks: XCD x (blockIdx&7) owns tiles [x*1563, x*1563+1562] so its
// 4 MB L2 sees a ~1.6 MB dst slice. GEMM3 is register-resident (quad shuffle
// + 1 KB Gp); Ue holds only the 16 real bytes per row (q>0 K-pad fragments
// are a zero register). LDS 19456 B -> 3 blocks/CU.
__global__ __launch_bounds__(256) void k_edge_mfma(
    const unsigned short* __restrict__ hb, const int* __restrict__ csr,
    const int* __restrict__ eidA, const int* __restrict__ dstA,
    const void* __restrict__ ea, const unsigned short* __restrict__ W1p,
    const unsigned short* __restrict__ wc, void* __restrict__ out,
    const int* __restrict__ flags) {
  __shared__ __align__(16) unsigned char sm[19456];
  unsigned char* const Ue = sm;           // 64 rows * 16 B
  unsigned char* const E1 = sm + 1024;    // 64 rows * 272 B
  float* const Gp = (float*)(sm + 18432); // [64][4]
  const int tid = threadIdx.x;
  const int wv = tid >> 6;
  const int L = tid & 63;
  const int l15 = L & 15;
  const int q = L >> 4;
  const int f32 = flags[0];

  // weights: wave wv covers GEMM1 cols wv*32..+31, GEMM2 cols wv*16..+15
  bf16x8 w1f[2][9];
  float b1v[2];
#pragma unroll
  for (int nt = 0; nt < 2; nt++) {
    const int jj = (wv * 2 + nt) * 16 + l15;
#pragma unroll
    for (int cc = 0; cc < 9; cc++)
      w1f[nt][cc] = *(const bf16x8*)(W1p + jj * 288 + cc * 32 + q * 8);
    b1v[nt] = b2f(wc[O_B1 + jj]);
  }
  bf16x8 w2f[4];
  const int jj2 = wv * 16 + l15;
#pragma unroll
  for (int kc = 0; kc < 4; kc++)
    w2f[kc] = *(const bf16x8*)(wc + O_W2 + jj2 * 128 + kc * 32 + q * 8);
  const float b2v = b2f(wc[O_B2 + jj2]);
  const float w3c = b2f(wc[O_W3 + jj2]);  // this lane's GEMM3 weight
  const float b3f = b2f(wc[O_B3]);
  const bf16x8 zfrag = {0, 0, 0, 0, 0, 0, 0, 0};

  const int xcd = blockIdx.x & 7;
  const int jb  = blockIdx.x >> 3;  // 0..390
  for (int k = 0; k < 4; k++) {
    const int tl = jb * 4 + k;                  // 0..1563
    const int t = xcd * 1563 + tl;
    if (tl >= 1563 || t >= 12500) break;        // uniform per block
    __syncthreads();  // protect Ue/E1/Gp from previous tile's readers
    const int pbase = t * 64;
    // stage Ue (edge_attr[eid] → bf16, 16 B/row)
    if (tid < 64) {
      const int e = eidA[pbase + tid];
      if (f32) {
        const float4* ep = (const float4*)((const float*)ea + (size_t)e * 8);
        const float4 a = ep[0], b = ep[1];
        union { ushort4 v[2]; int4 i; } o;
        o.v[0].x = f2b(a.x); o.v[0].y = f2b(a.y); o.v[0].z = f2b(a.z); o.v[0].w = f2b(a.w);
        o.v[1].x = f2b(b.x); o.v[1].y = f2b(b.y); o.v[1].z = f2b(b.z); o.v[1].w = f2b(b.w);
        *(int4*)(Ue + tid * 16) = o.i;
      } else {
        *(int4*)(Ue + tid * 16) = *(const int4*)((const unsigned short*)ea + (size_t)e * 8);
      }
    }
    // per-lane edge endpoints for rows mt*16+l15 (contiguous index loads)
    int sidx[4], didx[4];
#pragma unroll
    for (int mt = 0; mt < 4; mt++) {
      const int p = pbase + mt * 16 + l15;
      sidx[mt] = csr[p];
      didx[mt] = dstA[p];
    }
    __syncthreads();  // Ue ready

    // GEMM1: e1[64][128], A-fragments straight from global
    f32x4 acc1[4][2];
#pragma unroll
    for (int mt = 0; mt < 4; mt++)
#pragma unroll
      for (int nt = 0; nt < 2; nt++) acc1[mt][nt] = (f32x4)(0.0f);
#pragma unroll
    for (int cc = 0; cc < 4; cc++) {
#pragma unroll
      for (int mt = 0; mt < 4; mt++) {
        const bf16x8 a = *(const bf16x8*)(hb + (size_t)sidx[mt] * 128 + cc * 32 + q * 8);
#pragma unroll
        for (int nt = 0; nt < 2; nt++)
          acc1[mt][nt] = __builtin_amdgcn_mfma_f32_16x16x32_bf16(a, w1f[nt][cc], acc1[mt][nt], 0, 0, 0);
      }
    }
#pragma unroll
    for (int cc = 4; cc < 8; cc++) {
#pragma unroll
      for (int mt = 0; mt < 4; mt++) {
        const bf16x8 a = *(const bf16x8*)(hb + (size_t)didx[mt] * 128 + (cc - 4) * 32 + q * 8);
#pragma unroll
        for (int nt = 0; nt < 2; nt++)
          acc1[mt][nt] = __builtin_amdgcn_mfma_f32_16x16x32_bf16(a, w1f[nt][cc], acc1[mt][nt], 0, 0, 0);
      }
    }
#pragma unroll
    for (int mt = 0; mt < 4; mt++) {
      bf16x8 a = zfrag;  // K-pad block: only q==0 lanes carry real ea data
      if (q == 0) a = *(const bf16x8*)(Ue + (mt * 16 + l15) * 16);
#pragma unroll
      for (int nt = 0; nt < 2; nt++)
        acc1[mt][nt] = __builtin_amdgcn_mfma_f32_16x16x32_bf16(a, w1f[nt][8], acc1[mt][nt], 0, 0, 0);
    }
#pragma unroll
    for (int mt = 0; mt < 4; mt++)
#pragma unroll
      for (int nt = 0; nt < 2; nt++)
#pragma unroll
        for (int rg = 0; rg < 4; rg++) {
          const int er = mt * 16 + q * 4 + rg;
          const int jj = (wv * 2 + nt) * 16 + l15;
          *(unsigned short*)(E1 + er * 272 + jj * 2) =
              f2b(fmaxf(acc1[mt][nt][rg] + b1v[nt], 0.f));
        }
    __syncthreads();

    // GEMM2 + GEMM3 partials: e2 stays in registers (fp32), dot with w3
    f32x4 acc2[4];
#pragma unroll
    for (int mt = 0; mt < 4; mt++) acc2[mt] = (f32x4)(0.0f);
#pragma unroll
    for (int kc = 0; kc < 4; kc++) {
#pragma unroll
      for (int mt = 0; mt < 4; mt++) {
        const bf16x8 a = *(const bf16x8*)(E1 + (mt * 16 + l15) * 272 + (kc * 32 + q * 8) * 2);
        acc2[mt] = __builtin_amdgcn_mfma_f32_16x16x32_bf16(a, w2f[kc], acc2[mt], 0, 0, 0);
      }
    }
#pragma unroll
    for (int mt = 0; mt < 4; mt++) {
#pragma unroll
      for (int rg = 0; rg < 4; rg++) {
        float p = fmaxf(acc2[mt][rg] + b2v, 0.f) * w3c;
#pragma unroll
        for (int m = 1; m < 16; m <<= 1) p += __shfl_xor(p, m, 64);
        if (l15 == 0) Gp[(mt * 16 + q * 4 + rg) * 4 + wv] = p;
      }
    }
    __syncthreads();

    // final: sum the 4 wave-partials per edge, scatter by eid
    if (tid < 64) {
      const float* g = Gp + tid * 4;
      const float r = g[0] + g[1] + g[2] + g[3] + b3f;
      const int e = eidA[pbase + tid];
      if (f32) ((float*)out)[e] = r;
      else     ((unsigned short*)out)[e] = f2b(r);
    }
  }
}

extern "C" void kernel_launch(void* const* d_in, const int* in_sizes, int n_in,
                              void* d_out, int out_size, void* d_ws, size_t ws_size,
                              hipStream_t stream) {
  const void* x  = d_in[0];
  const int*  ei = (const int*)d_in[1];
  const void* ea = d_in[2];

  char* ws = (char*)d_ws;
  int*            flags  = (int*)(ws + WS_FLAGS);
  unsigned short* wc     = (unsigned short*)(ws + WS_WC);
  int*            cnt    = (int*)(ws + WS_CNT);
  int*            rowptr = (int*)(ws + WS_ROWP);
  int*            cursor = (int*)(ws + WS_CUR);
  int*            csr    = (int*)(ws + WS_CSR);
  int*            eidA   = (int*)(ws + WS_EID);
  int*            dstA   = (int*)(ws + WS_DST);
  unsigned short* W1p    = (unsigned short*)(ws + WS_W1P);
  unsigned short* hb0    = (unsigned short*)(ws + WS_HB0);
  unsigned short* hb1    = (unsigned short*)(ws + WS_HB1);

  if (ws_size < WS_NEED) {  // diagnostic: error ≈ 1.35 signals this path
    k_fallback<<<3125, 256, 0, stream>>>((unsigned short*)d_out);
    return;
  }

  k_probe<<<1, 64, 0, stream>>>((const unsigned short*)x, ei, flags);
  k_cvt_w<<<(W_TOTAL + 255) / 256, 256, 0, stream>>>(
      d_in[3], d_in[4], d_in[5], d_in[6], d_in[7], d_in[8], d_in[9],
      d_in[10], d_in[11], d_in[12], d_in[13], d_in[14], d_in[15], wc, flags);
  k_build_w1p<<<144, 256, 0, stream>>>(wc, W1p);

  hipMemsetAsync(cnt, 0, NN * sizeof(int), stream);
  hipMemsetAsync(cursor, 0, NN * sizeof(int), stream);
  k_hist<<<3125, 256, 0, stream>>>(ei, cnt, flags);
  k_scan<<<1, 1024, 0, stream>>>(cnt, rowptr);
  k_fill<<<3125, 256, 0, stream>>>(ei, rowptr, cursor, csr, eidA, dstA, flags);

  k_inproj<<<NN * 128 / 256, 256, 0, stream>>>(x, wc, hb0, flags);

  unsigned short* cur = hb0;
  unsigned short* nxt = hb1;
  for (int l = 0; l < 4; l++) {
    k_agg<<<12500, 256, 0, stream>>>(cur, csr, rowptr, nxt);
    k_sage_mfma<<<782, 256, 0, stream>>>(cur, nxt, wc, l);
    unsigned short* tmp = cur; cur = nxt; nxt = tmp;
  }
  // after 4 swaps, final h is back in hb0 (= cur)
  k_edge_mfma<<<3128, 256, 0, stream>>>(cur, csr, eidA, dstA, ea, W1p, wc, d_out, flags);
}

// Round 9
// 719.839 us; speedup vs baseline: 25.1366x; 1.1805x over previous
//
#include <hip/hip_runtime.h>
#include <stdint.h>

#define NN 50000
#define NE 800000

// canonical bf16 weight-block element offsets
#define O_WIN 0
#define O_BIN 2048
#define O_WL  2176
#define O_BL  67712
#define O_WR  68224
#define O_LNG 133760
#define O_LNB 134272
#define O_W1  134784
#define O_B1  168576
#define O_W2  168704
#define O_B2  176896
#define O_W3  176960
#define O_B3  177024
#define W_TOTAL 177025

// ws layout (bytes)
#define WS_FLAGS 0          //      256 B
#define WS_WC    512        //  354,050 B
#define WS_CNT   355072     //  200,000 B
#define WS_ROWP  555520     //  200,004 B
#define WS_CUR   756224     //  200,000 B
#define WS_CSR   956928     // 3,200,000 B (src per CSR slot)
#define WS_EID   4156928    // 3,200,000 B (edge id per CSR slot)
#define WS_DST   7356928    // 3,200,000 B (dst per CSR slot)
#define WS_W1P   10556928   //     73,728 B
#define WS_HB0   10630656   // 12,800,000 B
#define WS_HB1   23430656   // 12,800,000 B
#define WS_NEED  36230656

typedef float f32x4 __attribute__((ext_vector_type(4)));
typedef short bf16x8 __attribute__((ext_vector_type(8)));
typedef short bf16x4 __attribute__((ext_vector_type(4)));

__device__ __forceinline__ float b2f(unsigned short u) {
  union { unsigned int i; float f; } v; v.i = ((unsigned int)u) << 16; return v.f;
}
__device__ __forceinline__ unsigned short f2b(float f) {
  union { float f; unsigned int i; } v; v.f = f;
  return (unsigned short)((v.i + 0x7fffu + ((v.i >> 16) & 1u)) >> 16);
}

// ---------------- fallback diagnostic: ws too small → constant 0.5 ----------
__global__ void k_fallback(unsigned short* __restrict__ out) {
  int gid = blockIdx.x * 256 + threadIdx.x;
  if (gid < NE) out[gid] = 0x3F00;
}

// ---------------- dtype probe: flags[0]=fp32 float tensors, flags[1]=int64 --
__global__ void k_probe(const unsigned short* __restrict__ x_u,
                        const int* __restrict__ ei32, int* __restrict__ flags) {
  const int t = threadIdx.x;  // 64 threads, 1 wave
  int insane = 0;
  for (int i = t; i < 512; i += 64) {
    float v = b2f(x_u[i]);
    if (!(fabsf(v) < 1e4f)) insane++;
  }
#pragma unroll
  for (int off = 1; off < 64; off <<= 1) insane += __shfl_xor(insane, off, 64);
  int nz = 0;
  for (int i = t; i < 128; i += 64) nz |= (ei32[2 * i + 1] != 0);
  unsigned long long m = __ballot(nz != 0);
  if (t == 0) {
    flags[0] = (insane >= 16) ? 1 : 0;
    flags[1] = (m == 0ULL) ? 1 : 0;
  }
}

// ---------------- canonicalize the 13 weight tensors to bf16 ----------------
__global__ void k_cvt_w(const void* W_in, const void* b_in, const void* Wl,
                        const void* bl, const void* Wr, const void* lng,
                        const void* lnb, const void* W1, const void* b1,
                        const void* W2, const void* b2, const void* W3,
                        const void* b3, unsigned short* __restrict__ wc,
                        const int* __restrict__ flags) {
  const int gid = blockIdx.x * 256 + threadIdx.x;
  if (gid >= W_TOTAL) return;
  const int f32 = flags[0];
  const void* src; int off;
  if      (gid < O_BIN) { src = W_in; off = gid - O_WIN; }
  else if (gid < O_WL)  { src = b_in; off = gid - O_BIN; }
  else if (gid < O_BL)  { src = Wl;   off = gid - O_WL;  }
  else if (gid < O_WR)  { src = bl;   off = gid - O_BL;  }
  else if (gid < O_LNG) { src = Wr;   off = gid - O_WR;  }
  else if (gid < O_LNB) { src = lng;  off = gid - O_LNG; }
  else if (gid < O_W1)  { src = lnb;  off = gid - O_LNB; }
  else if (gid < O_B1)  { src = W1;   off = gid - O_W1;  }
  else if (gid < O_W2)  { src = b1;   off = gid - O_B1;  }
  else if (gid < O_B2)  { src = W2;   off = gid - O_W2;  }
  else if (gid < O_W3)  { src = b2;   off = gid - O_B2;  }
  else if (gid < O_B3)  { src = W3;   off = gid - O_W3;  }
  else                  { src = b3;   off = 0;           }
  wc[gid] = f32 ? f2b(((const float*)src)[off]) : ((const unsigned short*)src)[off];
}

// ---------------- W1 padded copy: wc[128][264] -> W1p[128][288] -------------
__global__ void k_build_w1p(const unsigned short* __restrict__ wc,
                            unsigned short* __restrict__ W1p) {
  int gid = blockIdx.x * 256 + threadIdx.x;  // 128*288 = 36864
  if (gid >= 128 * 288) return;
  int j = gid / 288, k = gid - j * 288;
  W1p[gid] = (k < 264) ? wc[O_W1 + j * 264 + k] : (unsigned short)0;
}

// ---------------- CSR build: histogram -> scan -> fill ----------------------
// (no sort: aggregation uses order-independent integer accumulation, and each
//  edge-head output depends only on its own slot's (src,dst,eid))
__global__ void k_hist(const int* __restrict__ ei, int* __restrict__ cnt,
                       const int* __restrict__ flags) {
  const int e = blockIdx.x * 256 + threadIdx.x;
  if (e >= NE) return;
  const int d = flags[1] ? ei[2 * (NE + e)] : ei[NE + e];
  atomicAdd(&cnt[d], 1);
}

__global__ __launch_bounds__(1024) void k_scan(const int* __restrict__ cnt,
                                               int* __restrict__ rowptr) {
  __shared__ int wsum[16];
  __shared__ int carry;
  const int t = threadIdx.x, wv = t >> 6, ln = t & 63;
  if (t == 0) carry = 0;
  __syncthreads();
  for (int base = 0; base < NN; base += 1024) {
    const int i = base + t;
    const int v = (i < NN) ? cnt[i] : 0;
    int x = v;
#pragma unroll
    for (int off = 1; off < 64; off <<= 1) {
      int y = __shfl_up(x, off, 64);
      if (ln >= off) x += y;
    }
    if (ln == 63) wsum[wv] = x;
    __syncthreads();
    if (t < 16) {
      int w = wsum[t];
#pragma unroll
      for (int off = 1; off < 16; off <<= 1) {
        int y = __shfl_up(w, off, 64);
        if (t >= off) w += y;
      }
      wsum[t] = w;
    }
    __syncthreads();
    const int woff = wv ? wsum[wv - 1] : 0;
    if (i < NN) rowptr[i] = carry + woff + x - v;
    const int total = wsum[15];
    __syncthreads();
    if (t == 0) carry += total;
    __syncthreads();
  }
  if (t == 0) rowptr[NN] = NE;
}

__global__ void k_fill(const int* __restrict__ ei, const int* __restrict__ rowptr,
                       int* __restrict__ cursor, int* __restrict__ csr,
                       int* __restrict__ eidA, int* __restrict__ dstA,
                       const int* __restrict__ flags) {
  const int e = blockIdx.x * 256 + threadIdx.x;
  if (e >= NE) return;
  const int i64 = flags[1];
  const int s = i64 ? ei[2 * e] : ei[e];
  const int d = i64 ? ei[2 * (NE + e)] : ei[NE + e];
  const int pos = rowptr[d] + atomicAdd(&cursor[d], 1);
  csr[pos] = s;
  eidA[pos] = e;
  dstA[pos] = d;
}

// ---------------- input projection: hb0 = bf16(x @ W_in^T + b_in) -----------
__global__ void k_inproj(const void* __restrict__ x,
                         const unsigned short* __restrict__ wc,
                         unsigned short* __restrict__ hb,
                         const int* __restrict__ flags) {
  const int gid = blockIdx.x * 256 + threadIdx.x;  // NN*128 threads
  const int n = gid >> 7, j = gid & 127;
  float xv[16];
  if (flags[0]) {
    const float4* xp = (const float4*)((const float*)x + (size_t)n * 16);
#pragma unroll
    for (int q = 0; q < 4; q++) {
      float4 t = xp[q];
      xv[q * 4 + 0] = t.x; xv[q * 4 + 1] = t.y; xv[q * 4 + 2] = t.z; xv[q * 4 + 3] = t.w;
    }
  } else {
    const unsigned short* xu = (const unsigned short*)x + (size_t)n * 16;
#pragma unroll
    for (int q = 0; q < 2; q++) {
      union { int4 v; unsigned short u[8]; } t;
      t.v = *(const int4*)(xu + q * 8);
#pragma unroll
      for (int i = 0; i < 8; i++) xv[q * 8 + i] = b2f(t.u[i]);
    }
  }
  float s = b2f(wc[O_BIN + j]);
  const unsigned short* wrow = wc + O_WIN + j * 16;
#pragma unroll
  for (int q = 0; q < 2; q++) {
    union { int4 v; unsigned short u[8]; } w;
    w.v = *(const int4*)(wrow + q * 8);
#pragma unroll
    for (int i = 0; i < 8; i++) s += b2f(w.u[i]) * xv[q * 8 + i];
  }
  hb[gid] = f2b(s);
}

// ---------------- aggregation: mean of neighbor rows, one wave per node -----
// fixed-point int64 accumulation (scale 2^24): exact integer sum is order-
// independent => bitwise-deterministic without sorting the CSR rows.
__global__ __launch_bounds__(256) void k_agg(
    const unsigned short* __restrict__ hin, const int* __restrict__ csr,
    const int* __restrict__ rowptr, unsigned short* __restrict__ aggb) {
  const int tid = threadIdx.x;
  const int n = blockIdx.x * 4 + (tid >> 6);  // 12500 blocks * 4 waves
  const int L = tid & 63;
  const int rs = rowptr[n], re = rowptr[n + 1];
  const unsigned int* hw = (const unsigned int*)hin;
  long long t0 = 0, t1 = 0;
  int e = rs;
  for (; e + 4 <= re; e += 4) {
    const unsigned int u0 = hw[(size_t)csr[e] * 64 + L];
    const unsigned int u1 = hw[(size_t)csr[e + 1] * 64 + L];
    const unsigned int u2 = hw[(size_t)csr[e + 2] * 64 + L];
    const unsigned int u3 = hw[(size_t)csr[e + 3] * 64 + L];
    t0 += (int)(b2f((unsigned short)(u0 & 0xffff)) * 16777216.0f);
    t1 += (int)(b2f((unsigned short)(u0 >> 16)) * 16777216.0f);
    t0 += (int)(b2f((unsigned short)(u1 & 0xffff)) * 16777216.0f);
    t1 += (int)(b2f((unsigned short)(u1 >> 16)) * 16777216.0f);
    t0 += (int)(b2f((unsigned short)(u2 & 0xffff)) * 16777216.0f);
    t1 += (int)(b2f((unsigned short)(u2 >> 16)) * 16777216.0f);
    t0 += (int)(b2f((unsigned short)(u3 & 0xffff)) * 16777216.0f);
    t1 += (int)(b2f((unsigned short)(u3 >> 16)) * 16777216.0f);
  }
  for (; e < re; e++) {
    const unsigned int u0 = hw[(size_t)csr[e] * 64 + L];
    t0 += (int)(b2f((unsigned short)(u0 & 0xffff)) * 16777216.0f);
    t1 += (int)(b2f((unsigned short)(u0 >> 16)) * 16777216.0f);
  }
  const int dg = re - rs;
  const float rd = (1.0f / 16777216.0f) / (float)(dg > 1 ? dg : 1);
  const float s0 = (float)t0 * rd;
  const float s1 = (float)t1 * rd;
  const unsigned int o = (unsigned int)f2b(s0) | ((unsigned int)f2b(s1) << 16);
  ((unsigned int*)aggb)[(size_t)n * 64 + L] = o;
}

// ---------------- SAGE layer: MFMA GEMM [agg|h] @ [Wl|Wr]^T + LN + ReLU -----
__global__ __launch_bounds__(256) void k_sage_mfma(
    const unsigned short* __restrict__ hin, unsigned short* __restrict__ hagg,
    const unsigned short* __restrict__ wc, int l) {
  __shared__ __align__(16) unsigned char As[64 * 528];  // 33792 B
  __shared__ float red1[64][4];
  __shared__ float red2[64][4];
  __shared__ float mr[64][2];
  const int tid = threadIdx.x;
  const int wv = tid >> 6;
  const int L = tid & 63;
  const int l15 = L & 15;
  const int q = L >> 4;
  const int n0 = blockIdx.x * 64;

  bf16x8 wf[2][8];
  float blv[2], gv[2], bv[2];
#pragma unroll
  for (int nt = 0; nt < 2; nt++) {
    const int jj = (wv * 2 + nt) * 16 + l15;
#pragma unroll
    for (int kc = 0; kc < 8; kc++) {
      const unsigned short* src = (kc < 4)
          ? wc + O_WL + ((size_t)l * 128 + jj) * 128 + kc * 32 + q * 8
          : wc + O_WR + ((size_t)l * 128 + jj) * 128 + (kc - 4) * 32 + q * 8;
      wf[nt][kc] = *(const bf16x8*)src;
    }
    blv[nt] = b2f(wc[O_BL + l * 128 + jj]);
    gv[nt]  = b2f(wc[O_LNG + l * 128 + jj]);
    bv[nt]  = b2f(wc[O_LNB + l * 128 + jj]);
  }

  for (int c = tid; c < 2048; c += 256) {
    const int row = c >> 5, part = c & 31;
    int node = n0 + row; if (node > NN - 1) node = NN - 1;
    const unsigned short* src = (part < 16)
        ? hagg + (size_t)node * 128 + part * 8
        : hin + (size_t)node * 128 + (part - 16) * 8;
    *(int4*)(As + row * 528 + part * 16) = *(const int4*)src;
  }
  __syncthreads();

  f32x4 acc[4][2];
#pragma unroll
  for (int mt = 0; mt < 4; mt++)
#pragma unroll
    for (int nt = 0; nt < 2; nt++) acc[mt][nt] = (f32x4)(0.0f);
#pragma unroll
  for (int kc = 0; kc < 8; kc++) {
#pragma unroll
    for (int mt = 0; mt < 4; mt++) {
      const bf16x8 a = *(const bf16x8*)(As + (mt * 16 + l15) * 528 + (kc * 32 + q * 8) * 2);
#pragma unroll
      for (int nt = 0; nt < 2; nt++)
        acc[mt][nt] = __builtin_amdgcn_mfma_f32_16x16x32_bf16(a, wf[nt][kc], acc[mt][nt], 0, 0, 0);
    }
  }
#pragma unroll
  for (int mt = 0; mt < 4; mt++) {
#pragma unroll
    for (int rg = 0; rg < 4; rg++) {
      acc[mt][0][rg] += blv[0];
      acc[mt][1][rg] += blv[1];
      float s = acc[mt][0][rg] + acc[mt][1][rg];
      float s2 = acc[mt][0][rg] * acc[mt][0][rg] + acc[mt][1][rg] * acc[mt][1][rg];
#pragma unroll
      for (int m = 1; m < 16; m <<= 1) {
        s += __shfl_xor(s, m, 64);
        s2 += __shfl_xor(s2, m, 64);
      }
      if (l15 == 0) {
        const int row = mt * 16 + q * 4 + rg;
        red1[row][wv] = s; red2[row][wv] = s2;
      }
    }
  }
  __syncthreads();
  if (tid < 64) {
    const float s1 = red1[tid][0] + red1[tid][1] + red1[tid][2] + red1[tid][3];
    const float s2 = red2[tid][0] + red2[tid][1] + red2[tid][2] + red2[tid][3];
    const float mu = s1 * 0.0078125f;
    const float var = s2 * 0.0078125f - mu * mu;
    mr[tid][0] = mu;
    mr[tid][1] = rsqrtf(var + 1e-5f);
  }
  __syncthreads();
#pragma unroll
  for (int mt = 0; mt < 4; mt++) {
#pragma unroll
    for (int rg = 0; rg < 4; rg++) {
      const int row = mt * 16 + q * 4 + rg;
      const int node = n0 + row;
      if (node < NN) {
        const float mu = mr[row][0], rstd = mr[row][1];
#pragma unroll
        for (int nt = 0; nt < 2; nt++) {
          const float o = (acc[mt][nt][rg] - mu) * rstd * gv[nt] + bv[nt];
          hagg[(size_t)node * 128 + (wv * 2 + nt) * 16 + l15] = f2b(fmaxf(o, 0.f));
        }
      }
    }
  }
}

// ---------------- edge head: dst-grouped tiles + direct-global MFMA MLP -----
// R7 structure (proven 230 µs) + grouped src prefetch: the 4 random src
// A-fragments of each mt-row are issued together before their MFMAs for
// memory-level parallelism; dst fragments stay inline (dst-grouped => L1-hot).
// LDS: Ue[64][64B]=4096  E1[64][272B]=17408  E2[64][136B]=8704  → 30208 B
__global__ __launch_bounds__(256) void k_edge_mfma(
    const unsigned short* __restrict__ hb, const int* __restrict__ csr,
    const int* __restrict__ eidA, const int* __restrict__ dstA,
    const void* __restrict__ ea, const unsigned short* __restrict__ W1p,
    const unsigned short* __restrict__ wc, void* __restrict__ out,
    const int* __restrict__ flags) {
  __shared__ __align__(16) unsigned char sm[30208];
  unsigned char* const Ue = sm;
  unsigned char* const E1 = sm + 4096;
  unsigned char* const E2 = sm + 21504;
  const int tid = threadIdx.x;
  const int wv = tid >> 6;
  const int L = tid & 63;
  const int l15 = L & 15;
  const int q = L >> 4;
  const int f32 = flags[0];

  // zero the K-padding region of Ue (bytes 16..63 of each 64B row), once
  for (int i = tid; i < 64 * 12; i += 256)
    *(int*)(Ue + (i / 12) * 64 + 16 + (i % 12) * 4) = 0;

  bf16x8 w1f[2][9];
  float b1v[2];
#pragma unroll
  for (int nt = 0; nt < 2; nt++) {
    const int jj = (wv * 2 + nt) * 16 + l15;
#pragma unroll
    for (int cc = 0; cc < 9; cc++)
      w1f[nt][cc] = *(const bf16x8*)(W1p + jj * 288 + cc * 32 + q * 8);
    b1v[nt] = b2f(wc[O_B1 + jj]);
  }
  bf16x8 w2f[4];
  const int jj2 = wv * 16 + l15;
#pragma unroll
  for (int kc = 0; kc < 4; kc++)
    w2f[kc] = *(const bf16x8*)(wc + O_W2 + jj2 * 128 + kc * 32 + q * 8);
  const float b2v = b2f(wc[O_B2 + jj2]);
  float w3v[16];
#pragma unroll
  for (int i = 0; i < 16; i++) w3v[i] = b2f(wc[O_W3 + q * 16 + i]);
  const float b3f = b2f(wc[O_B3]);

  for (int t = blockIdx.x; t < NE / 64; t += gridDim.x) {
    __syncthreads();  // protect Ue/E2 from previous tile's reads
    const int pbase = t * 64;
    // stage Ue (edge_attr[eid] → bf16)
    if (tid < 64) {
      const int e = eidA[pbase + tid];
      if (f32) {
        const float4* ep = (const float4*)((const float*)ea + (size_t)e * 8);
        const float4 a = ep[0], b = ep[1];
        union { ushort4 v[2]; int4 i; } o;
        o.v[0].x = f2b(a.x); o.v[0].y = f2b(a.y); o.v[0].z = f2b(a.z); o.v[0].w = f2b(a.w);
        o.v[1].x = f2b(b.x); o.v[1].y = f2b(b.y); o.v[1].z = f2b(b.z); o.v[1].w = f2b(b.w);
        *(int4*)(Ue + tid * 64) = o.i;
      } else {
        *(int4*)(Ue + tid * 64) = *(const int4*)((const unsigned short*)ea + (size_t)e * 8);
      }
    }
    // per-lane edge endpoints for rows mt*16+l15 (contiguous index loads)
    int sidx[4], didx[4];
#pragma unroll
    for (int mt = 0; mt < 4; mt++) {
      const int p = pbase + mt * 16 + l15;
      sidx[mt] = csr[p];
      didx[mt] = dstA[p];
    }
    __syncthreads();  // Ue ready

    // GEMM1: e1[64][128]. Src fragments grouped 4-wide per mt for MLP.
    f32x4 acc1[4][2];
#pragma unroll
    for (int mt = 0; mt < 4; mt++)
#pragma unroll
      for (int nt = 0; nt < 2; nt++) acc1[mt][nt] = (f32x4)(0.0f);
#pragma unroll
    for (int mt = 0; mt < 4; mt++) {
      const unsigned short* sp = hb + (size_t)sidx[mt] * 128 + q * 8;
      const bf16x8 s0 = *(const bf16x8*)(sp);
      const bf16x8 s1 = *(const bf16x8*)(sp + 32);
      const bf16x8 s2 = *(const bf16x8*)(sp + 64);
      const bf16x8 s3 = *(const bf16x8*)(sp + 96);
#pragma unroll
      for (int nt = 0; nt < 2; nt++) {
        acc1[mt][nt] = __builtin_amdgcn_mfma_f32_16x16x32_bf16(s0, w1f[nt][0], acc1[mt][nt], 0, 0, 0);
        acc1[mt][nt] = __builtin_amdgcn_mfma_f32_16x16x32_bf16(s1, w1f[nt][1], acc1[mt][nt], 0, 0, 0);
        acc1[mt][nt] = __builtin_amdgcn_mfma_f32_16x16x32_bf16(s2, w1f[nt][2], acc1[mt][nt], 0, 0, 0);
        acc1[mt][nt] = __builtin_amdgcn_mfma_f32_16x16x32_bf16(s3, w1f[nt][3], acc1[mt][nt], 0, 0, 0);
      }
    }
#pragma unroll
    for (int cc = 4; cc < 8; cc++) {
#pragma unroll
      for (int mt = 0; mt < 4; mt++) {
        const bf16x8 a = *(const bf16x8*)(hb + (size_t)didx[mt] * 128 + (cc - 4) * 32 + q * 8);
#pragma unroll
        for (int nt = 0; nt < 2; nt++)
          acc1[mt][nt] = __builtin_amdgcn_mfma_f32_16x16x32_bf16(a, w1f[nt][cc], acc1[mt][nt], 0, 0, 0);
      }
    }
#pragma unroll
    for (int mt = 0; mt < 4; mt++) {
      const bf16x8 a = *(const bf16x8*)(Ue + (mt * 16 + l15) * 64 + q * 16);
#pragma unroll
      for (int nt = 0; nt < 2; nt++)
        acc1[mt][nt] = __builtin_amdgcn_mfma_f32_16x16x32_bf16(a, w1f[nt][8], acc1[mt][nt], 0, 0, 0);
    }
#pragma unroll
    for (int mt = 0; mt < 4; mt++)
#pragma unroll
      for (int nt = 0; nt < 2; nt++)
#pragma unroll
        for (int rg = 0; rg < 4; rg++) {
          const int er = mt * 16 + q * 4 + rg;
          const int jj = (wv * 2 + nt) * 16 + l15;
          *(unsigned short*)(E1 + er * 272 + jj * 2) =
              f2b(fmaxf(acc1[mt][nt][rg] + b1v[nt], 0.f));
        }
    __syncthreads();

    // GEMM2: e2[64][64], wave covers 16 cols, all 64 rows
    f32x4 acc2[4];
#pragma unroll
    for (int mt = 0; mt < 4; mt++) acc2[mt] = (f32x4)(0.0f);
#pragma unroll
    for (int kc = 0; kc < 4; kc++) {
#pragma unroll
      for (int mt = 0; mt < 4; mt++) {
        const bf16x8 a = *(const bf16x8*)(E1 + (mt * 16 + l15) * 272 + (kc * 32 + q * 8) * 2);
        acc2[mt] = __builtin_amdgcn_mfma_f32_16x16x32_bf16(a, w2f[kc], acc2[mt], 0, 0, 0);
      }
    }
#pragma unroll
    for (int mt = 0; mt < 4; mt++)
#pragma unroll
      for (int rg = 0; rg < 4; rg++) {
        const int er = mt * 16 + q * 4 + rg;
        *(unsigned short*)(E2 + er * 136 + jj2 * 2) =
            f2b(fmaxf(acc2[mt][rg] + b2v, 0.f));
      }
    __syncthreads();

    // GEMM3: logit per edge, dot-64 via 4 lane-groups + shuffle; scatter by eid
    const int el = wv * 16 + l15;
    float acc = 0.f;
#pragma unroll
    for (int i4 = 0; i4 < 4; i4++) {
      const bf16x4 v = *(const bf16x4*)(E2 + el * 136 + q * 32 + i4 * 8);
      acc += b2f((unsigned short)v[0]) * w3v[i4 * 4 + 0];
      acc += b2f((unsigned short)v[1]) * w3v[i4 * 4 + 1];
      acc += b2f((unsigned short)v[2]) * w3v[i4 * 4 + 2];
      acc += b2f((unsigned short)v[3]) * w3v[i4 * 4 + 3];
    }
    acc += __shfl_xor(acc, 16, 64);
    acc += __shfl_xor(acc, 32, 64);
    if (q == 0) {
      const int e = eidA[pbase + el];
      const float r = acc + b3f;
      if (f32) ((float*)out)[e] = r;
      else     ((unsigned short*)out)[e] = f2b(r);
    }
  }
}

extern "C" void kernel_launch(void* const* d_in, const int* in_sizes, int n_in,
                              void* d_out, int out_size, void* d_ws, size_t ws_size,
                              hipStream_t stream) {
  const void* x  = d_in[0];
  const int*  ei = (const int*)d_in[1];
  const void* ea = d_in[2];

  char* ws = (char*)d_ws;
  int*            flags  = (int*)(ws + WS_FLAGS);
  unsigned short* wc     = (unsigned short*)(ws + WS_WC);
  int*            cnt    = (int*)(ws + WS_CNT);
  int*            rowptr = (int*)(ws + WS_ROWP);
  int*            cursor = (int*)(ws + WS_CUR);
  int*            csr    = (int*)(ws + WS_CSR);
  int*            eidA   = (int*)(ws + WS_EID);
  int*            dstA   = (int*)(ws + WS_DST);
  unsigned short* W1p    = (unsigned short*)(ws + WS_W1P);
  unsigned short* hb0    = (unsigned short*)(ws + WS_HB0);
  unsigned short* hb1    = (unsigned short*)(ws + WS_HB1);

  if (ws_size < WS_NEED) {  // diagnostic: error ≈ 1.35 signals this path
    k_fallback<<<3125, 256, 0, stream>>>((unsigned short*)d_out);
    return;
  }

  k_probe<<<1, 64, 0, stream>>>((const unsigned short*)x, ei, flags);
  k_cvt_w<<<(W_TOTAL + 255) / 256, 256, 0, stream>>>(
      d_in[3], d_in[4], d_in[5], d_in[6], d_in[7], d_in[8], d_in[9],
      d_in[10], d_in[11], d_in[12], d_in[13], d_in[14], d_in[15], wc, flags);
  k_build_w1p<<<144, 256, 0, stream>>>(wc, W1p);

  hipMemsetAsync(cnt, 0, NN * sizeof(int), stream);
  hipMemsetAsync(cursor, 0, NN * sizeof(int), stream);
  k_hist<<<3125, 256, 0, stream>>>(ei, cnt, flags);
  k_scan<<<1, 1024, 0, stream>>>(cnt, rowptr);
  k_fill<<<3125, 256, 0, stream>>>(ei, rowptr, cursor, csr, eidA, dstA, flags);

  k_inproj<<<NN * 128 / 256, 256, 0, stream>>>(x, wc, hb0, flags);

  unsigned short* cur = hb0;
  unsigned short* nxt = hb1;
  for (int l = 0; l < 4; l++) {
    k_agg<<<12500, 256, 0, stream>>>(cur, csr, rowptr, nxt);
    k_sage_mfma<<<782, 256, 0, stream>>>(cur, nxt, wc, l);
    unsigned short* tmp = cur; cur = nxt; nxt = tmp;
  }
  // after 4 swaps, final h is back in hb0 (= cur)
  k_edge_mfma<<<3125, 256, 0, stream>>>(cur, csr, eidA, dstA, ea, W1p, wc, d_out, flags);
}

// Round 10
// 664.427 us; speedup vs baseline: 27.2329x; 1.0834x over previous
//
#include <hip/hip_runtime.h>
#include <stdint.h>

#define NN 50000
#define NE 800000

// canonical bf16 weight-block element offsets
#define O_WIN 0
#define O_BIN 2048
#define O_WL  2176
#define O_BL  67712
#define O_WR  68224
#define O_LNG 133760
#define O_LNB 134272
#define O_W1  134784
#define O_B1  168576
#define O_W2  168704
#define O_B2  176896
#define O_W3  176960
#define O_B3  177024
#define W_TOTAL 177025

// ws layout (bytes)
#define WS_FLAGS 0          //      256 B
#define WS_WC    512        //  354,050 B
#define WS_CNT   355072     //  200,000 B
#define WS_ROWP  555520     //  200,004 B
#define WS_CUR   756224     //  200,000 B
#define WS_CSR   956928     // 3,200,000 B (src per CSR slot)
#define WS_EID   4156928    // 3,200,000 B (edge id per CSR slot)
#define WS_DST   7356928    // 3,200,000 B (dst per CSR slot)
#define WS_W1P   10556928   //     73,728 B
#define WS_HB0   10630656   // 12,800,000 B
#define WS_HB1   23430656   // 12,800,000 B
#define WS_NEED  36230656

typedef float f32x4 __attribute__((ext_vector_type(4)));
typedef short bf16x8 __attribute__((ext_vector_type(8)));
typedef short bf16x4 __attribute__((ext_vector_type(4)));

__device__ __forceinline__ float b2f(unsigned short u) {
  union { unsigned int i; float f; } v; v.i = ((unsigned int)u) << 16; return v.f;
}
__device__ __forceinline__ unsigned short f2b(float f) {
  union { float f; unsigned int i; } v; v.f = f;
  return (unsigned short)((v.i + 0x7fffu + ((v.i >> 16) & 1u)) >> 16);
}

// ---------------- fallback diagnostic: ws too small → constant 0.5 ----------
__global__ void k_fallback(unsigned short* __restrict__ out) {
  int gid = blockIdx.x * 256 + threadIdx.x;
  if (gid < NE) out[gid] = 0x3F00;
}

// ---------------- dtype probe: flags[0]=fp32 float tensors, flags[1]=int64 --
__global__ void k_probe(const unsigned short* __restrict__ x_u,
                        const int* __restrict__ ei32, int* __restrict__ flags) {
  const int t = threadIdx.x;  // 64 threads, 1 wave
  int insane = 0;
  for (int i = t; i < 512; i += 64) {
    float v = b2f(x_u[i]);
    if (!(fabsf(v) < 1e4f)) insane++;
  }
#pragma unroll
  for (int off = 1; off < 64; off <<= 1) insane += __shfl_xor(insane, off, 64);
  int nz = 0;
  for (int i = t; i < 128; i += 64) nz |= (ei32[2 * i + 1] != 0);
  unsigned long long m = __ballot(nz != 0);
  if (t == 0) {
    flags[0] = (insane >= 16) ? 1 : 0;
    flags[1] = (m == 0ULL) ? 1 : 0;
  }
}

// ---------------- canonicalize the 13 weight tensors to bf16 ----------------
__global__ void k_cvt_w(const void* W_in, const void* b_in, const void* Wl,
                        const void* bl, const void* Wr, const void* lng,
                        const void* lnb, const void* W1, const void* b1,
                        const void* W2, const void* b2, const void* W3,
                        const void* b3, unsigned short* __restrict__ wc,
                        const int* __restrict__ flags) {
  const int gid = blockIdx.x * 256 + threadIdx.x;
  if (gid >= W_TOTAL) return;
  const int f32 = flags[0];
  const void* src; int off;
  if      (gid < O_BIN) { src = W_in; off = gid - O_WIN; }
  else if (gid < O_WL)  { src = b_in; off = gid - O_BIN; }
  else if (gid < O_BL)  { src = Wl;   off = gid - O_WL;  }
  else if (gid < O_WR)  { src = bl;   off = gid - O_BL;  }
  else if (gid < O_LNG) { src = Wr;   off = gid - O_WR;  }
  else if (gid < O_LNB) { src = lng;  off = gid - O_LNG; }
  else if (gid < O_W1)  { src = lnb;  off = gid - O_LNB; }
  else if (gid < O_B1)  { src = W1;   off = gid - O_W1;  }
  else if (gid < O_W2)  { src = b1;   off = gid - O_B1;  }
  else if (gid < O_B2)  { src = W2;   off = gid - O_W2;  }
  else if (gid < O_W3)  { src = b2;   off = gid - O_B2;  }
  else if (gid < O_B3)  { src = W3;   off = gid - O_W3;  }
  else                  { src = b3;   off = 0;           }
  wc[gid] = f32 ? f2b(((const float*)src)[off]) : ((const unsigned short*)src)[off];
}

// ---------------- W1 padded copy: wc[128][264] -> W1p[128][288] -------------
__global__ void k_build_w1p(const unsigned short* __restrict__ wc,
                            unsigned short* __restrict__ W1p) {
  int gid = blockIdx.x * 256 + threadIdx.x;  // 128*288 = 36864
  if (gid >= 128 * 288) return;
  int j = gid / 288, k = gid - j * 288;
  W1p[gid] = (k < 264) ? wc[O_W1 + j * 264 + k] : (unsigned short)0;
}

// ---------------- CSR build: histogram -> scan -> fill ----------------------
// (no sort: aggregation uses order-independent integer accumulation, and each
//  edge-head output depends only on its own slot's (src,dst,eid))
__global__ void k_hist(const int* __restrict__ ei, int* __restrict__ cnt,
                       const int* __restrict__ flags) {
  const int e = blockIdx.x * 256 + threadIdx.x;
  if (e >= NE) return;
  const int d = flags[1] ? ei[2 * (NE + e)] : ei[NE + e];
  atomicAdd(&cnt[d], 1);
}

__global__ __launch_bounds__(1024) void k_scan(const int* __restrict__ cnt,
                                               int* __restrict__ rowptr) {
  __shared__ int wsum[16];
  __shared__ int carry;
  const int t = threadIdx.x, wv = t >> 6, ln = t & 63;
  if (t == 0) carry = 0;
  __syncthreads();
  for (int base = 0; base < NN; base += 1024) {
    const int i = base + t;
    const int v = (i < NN) ? cnt[i] : 0;
    int x = v;
#pragma unroll
    for (int off = 1; off < 64; off <<= 1) {
      int y = __shfl_up(x, off, 64);
      if (ln >= off) x += y;
    }
    if (ln == 63) wsum[wv] = x;
    __syncthreads();
    if (t < 16) {
      int w = wsum[t];
#pragma unroll
      for (int off = 1; off < 16; off <<= 1) {
        int y = __shfl_up(w, off, 64);
        if (t >= off) w += y;
      }
      wsum[t] = w;
    }
    __syncthreads();
    const int woff = wv ? wsum[wv - 1] : 0;
    if (i < NN) rowptr[i] = carry + woff + x - v;
    const int total = wsum[15];
    __syncthreads();
    if (t == 0) carry += total;
    __syncthreads();
  }
  if (t == 0) rowptr[NN] = NE;
}

__global__ void k_fill(const int* __restrict__ ei, const int* __restrict__ rowptr,
                       int* __restrict__ cursor, int* __restrict__ csr,
                       int* __restrict__ eidA, int* __restrict__ dstA,
                       const int* __restrict__ flags) {
  const int e = blockIdx.x * 256 + threadIdx.x;
  if (e >= NE) return;
  const int i64 = flags[1];
  const int s = i64 ? ei[2 * e] : ei[e];
  const int d = i64 ? ei[2 * (NE + e)] : ei[NE + e];
  const int pos = rowptr[d] + atomicAdd(&cursor[d], 1);
  csr[pos] = s;
  eidA[pos] = e;
  dstA[pos] = d;
}

// ---------------- input projection: hb0 = bf16(x @ W_in^T + b_in) -----------
__global__ void k_inproj(const void* __restrict__ x,
                         const unsigned short* __restrict__ wc,
                         unsigned short* __restrict__ hb,
                         const int* __restrict__ flags) {
  const int gid = blockIdx.x * 256 + threadIdx.x;  // NN*128 threads
  const int n = gid >> 7, j = gid & 127;
  float xv[16];
  if (flags[0]) {
    const float4* xp = (const float4*)((const float*)x + (size_t)n * 16);
#pragma unroll
    for (int q = 0; q < 4; q++) {
      float4 t = xp[q];
      xv[q * 4 + 0] = t.x; xv[q * 4 + 1] = t.y; xv[q * 4 + 2] = t.z; xv[q * 4 + 3] = t.w;
    }
  } else {
    const unsigned short* xu = (const unsigned short*)x + (size_t)n * 16;
#pragma unroll
    for (int q = 0; q < 2; q++) {
      union { int4 v; unsigned short u[8]; } t;
      t.v = *(const int4*)(xu + q * 8);
#pragma unroll
      for (int i = 0; i < 8; i++) xv[q * 8 + i] = b2f(t.u[i]);
    }
  }
  float s = b2f(wc[O_BIN + j]);
  const unsigned short* wrow = wc + O_WIN + j * 16;
#pragma unroll
  for (int q = 0; q < 2; q++) {
    union { int4 v; unsigned short u[8]; } w;
    w.v = *(const int4*)(wrow + q * 8);
#pragma unroll
    for (int i = 0; i < 8; i++) s += b2f(w.u[i]) * xv[q * 8 + i];
  }
  hb[gid] = f2b(s);
}

// ---------------- aggregation: mean of neighbor rows, one wave per node -----
// fixed-point int64 accumulation (scale 2^24): exact integer sum is order-
// independent => bitwise-deterministic without sorting the CSR rows.
__global__ __launch_bounds__(256) void k_agg(
    const unsigned short* __restrict__ hin, const int* __restrict__ csr,
    const int* __restrict__ rowptr, unsigned short* __restrict__ aggb) {
  const int tid = threadIdx.x;
  const int n = blockIdx.x * 4 + (tid >> 6);  // 12500 blocks * 4 waves
  const int L = tid & 63;
  const int rs = rowptr[n], re = rowptr[n + 1];
  const unsigned int* hw = (const unsigned int*)hin;
  long long t0 = 0, t1 = 0;
  int e = rs;
  for (; e + 4 <= re; e += 4) {
    const unsigned int u0 = hw[(size_t)csr[e] * 64 + L];
    const unsigned int u1 = hw[(size_t)csr[e + 1] * 64 + L];
    const unsigned int u2 = hw[(size_t)csr[e + 2] * 64 + L];
    const unsigned int u3 = hw[(size_t)csr[e + 3] * 64 + L];
    t0 += (int)(b2f((unsigned short)(u0 & 0xffff)) * 16777216.0f);
    t1 += (int)(b2f((unsigned short)(u0 >> 16)) * 16777216.0f);
    t0 += (int)(b2f((unsigned short)(u1 & 0xffff)) * 16777216.0f);
    t1 += (int)(b2f((unsigned short)(u1 >> 16)) * 16777216.0f);
    t0 += (int)(b2f((unsigned short)(u2 & 0xffff)) * 16777216.0f);
    t1 += (int)(b2f((unsigned short)(u2 >> 16)) * 16777216.0f);
    t0 += (int)(b2f((unsigned short)(u3 & 0xffff)) * 16777216.0f);
    t1 += (int)(b2f((unsigned short)(u3 >> 16)) * 16777216.0f);
  }
  for (; e < re; e++) {
    const unsigned int u0 = hw[(size_t)csr[e] * 64 + L];
    t0 += (int)(b2f((unsigned short)(u0 & 0xffff)) * 16777216.0f);
    t1 += (int)(b2f((unsigned short)(u0 >> 16)) * 16777216.0f);
  }
  const int dg = re - rs;
  const float rd = (1.0f / 16777216.0f) / (float)(dg > 1 ? dg : 1);
  const float s0 = (float)t0 * rd;
  const float s1 = (float)t1 * rd;
  const unsigned int o = (unsigned int)f2b(s0) | ((unsigned int)f2b(s1) << 16);
  ((unsigned int*)aggb)[(size_t)n * 64 + L] = o;
}

// ---------------- SAGE layer: MFMA GEMM [agg|h] @ [Wl|Wr]^T + LN + ReLU -----
__global__ __launch_bounds__(256) void k_sage_mfma(
    const unsigned short* __restrict__ hin, unsigned short* __restrict__ hagg,
    const unsigned short* __restrict__ wc, int l) {
  __shared__ __align__(16) unsigned char As[64 * 528];  // 33792 B
  __shared__ float red1[64][4];
  __shared__ float red2[64][4];
  __shared__ float mr[64][2];
  const int tid = threadIdx.x;
  const int wv = tid >> 6;
  const int L = tid & 63;
  const int l15 = L & 15;
  const int q = L >> 4;
  const int n0 = blockIdx.x * 64;

  bf16x8 wf[2][8];
  float blv[2], gv[2], bv[2];
#pragma unroll
  for (int nt = 0; nt < 2; nt++) {
    const int jj = (wv * 2 + nt) * 16 + l15;
#pragma unroll
    for (int kc = 0; kc < 8; kc++) {
      const unsigned short* src = (kc < 4)
          ? wc + O_WL + ((size_t)l * 128 + jj) * 128 + kc * 32 + q * 8
          : wc + O_WR + ((size_t)l * 128 + jj) * 128 + (kc - 4) * 32 + q * 8;
      wf[nt][kc] = *(const bf16x8*)src;
    }
    blv[nt] = b2f(wc[O_BL + l * 128 + jj]);
    gv[nt]  = b2f(wc[O_LNG + l * 128 + jj]);
    bv[nt]  = b2f(wc[O_LNB + l * 128 + jj]);
  }

  for (int c = tid; c < 2048; c += 256) {
    const int row = c >> 5, part = c & 31;
    int node = n0 + row; if (node > NN - 1) node = NN - 1;
    const unsigned short* src = (part < 16)
        ? hagg + (size_t)node * 128 + part * 8
        : hin + (size_t)node * 128 + (part - 16) * 8;
    *(int4*)(As + row * 528 + part * 16) = *(const int4*)src;
  }
  __syncthreads();

  f32x4 acc[4][2];
#pragma unroll
  for (int mt = 0; mt < 4; mt++)
#pragma unroll
    for (int nt = 0; nt < 2; nt++) acc[mt][nt] = (f32x4)(0.0f);
#pragma unroll
  for (int kc = 0; kc < 8; kc++) {
#pragma unroll
    for (int mt = 0; mt < 4; mt++) {
      const bf16x8 a = *(const bf16x8*)(As + (mt * 16 + l15) * 528 + (kc * 32 + q * 8) * 2);
#pragma unroll
      for (int nt = 0; nt < 2; nt++)
        acc[mt][nt] = __builtin_amdgcn_mfma_f32_16x16x32_bf16(a, wf[nt][kc], acc[mt][nt], 0, 0, 0);
    }
  }
#pragma unroll
  for (int mt = 0; mt < 4; mt++) {
#pragma unroll
    for (int rg = 0; rg < 4; rg++) {
      acc[mt][0][rg] += blv[0];
      acc[mt][1][rg] += blv[1];
      float s = acc[mt][0][rg] + acc[mt][1][rg];
      float s2 = acc[mt][0][rg] * acc[mt][0][rg] + acc[mt][1][rg] * acc[mt][1][rg];
#pragma unroll
      for (int m = 1; m < 16; m <<= 1) {
        s += __shfl_xor(s, m, 64);
        s2 += __shfl_xor(s2, m, 64);
      }
      if (l15 == 0) {
        const int row = mt * 16 + q * 4 + rg;
        red1[row][wv] = s; red2[row][wv] = s2;
      }
    }
  }
  __syncthreads();
  if (tid < 64) {
    const float s1 = red1[tid][0] + red1[tid][1] + red1[tid][2] + red1[tid][3];
    const float s2 = red2[tid][0] + red2[tid][1] + red2[tid][2] + red2[tid][3];
    const float mu = s1 * 0.0078125f;
    const float var = s2 * 0.0078125f - mu * mu;
    mr[tid][0] = mu;
    mr[tid][1] = rsqrtf(var + 1e-5f);
  }
  __syncthreads();
#pragma unroll
  for (int mt = 0; mt < 4; mt++) {
#pragma unroll
    for (int rg = 0; rg < 4; rg++) {
      const int row = mt * 16 + q * 4 + rg;
      const int node = n0 + row;
      if (node < NN) {
        const float mu = mr[row][0], rstd = mr[row][1];
#pragma unroll
        for (int nt = 0; nt < 2; nt++) {
          const float o = (acc[mt][nt][rg] - mu) * rstd * gv[nt] + bv[nt];
          hagg[(size_t)node * 128 + (wv * 2 + nt) * 16 + l15] = f2b(fmaxf(o, 0.f));
        }
      }
    }
  }
}

// ---------------- edge head: dst-grouped tiles + LDS-staged src MFMA MLP ----
// Src rows staged to LDS ONCE per block (was: each of 4 waves re-gathered all
// 64 rows — 4x redundant, thrashing the 32KB L1). Staging issues 4x16B loads
// per thread (high MLP); GEMM1 src A-frags then come from LDS (272B stride =
// 2-way bank aliasing = free). Dst stays direct-global (dst-grouped, L1-hot).
// LDS: Ue 4096 | Hs 17408 | E1 17408 | E2 8704 = 47616 B -> 3 blocks/CU.
__global__ __launch_bounds__(256) void k_edge_mfma(
    const unsigned short* __restrict__ hb, const int* __restrict__ csr,
    const int* __restrict__ eidA, const int* __restrict__ dstA,
    const void* __restrict__ ea, const unsigned short* __restrict__ W1p,
    const unsigned short* __restrict__ wc, void* __restrict__ out,
    const int* __restrict__ flags) {
  __shared__ __align__(16) unsigned char sm[47616];
  unsigned char* const Ue = sm;            // [64][64B]
  unsigned char* const Hs = sm + 4096;     // [64][272B]
  unsigned char* const E1 = sm + 21504;    // [64][272B]
  unsigned char* const E2 = sm + 38912;    // [64][136B]
  const int tid = threadIdx.x;
  const int wv = tid >> 6;
  const int L = tid & 63;
  const int l15 = L & 15;
  const int q = L >> 4;
  const int f32 = flags[0];

  // zero the K-padding region of Ue (bytes 16..63 of each 64B row), once
  for (int i = tid; i < 64 * 12; i += 256)
    *(int*)(Ue + (i / 12) * 64 + 16 + (i % 12) * 4) = 0;

  bf16x8 w1f[2][9];
  float b1v[2];
#pragma unroll
  for (int nt = 0; nt < 2; nt++) {
    const int jj = (wv * 2 + nt) * 16 + l15;
#pragma unroll
    for (int cc = 0; cc < 9; cc++)
      w1f[nt][cc] = *(const bf16x8*)(W1p + jj * 288 + cc * 32 + q * 8);
    b1v[nt] = b2f(wc[O_B1 + jj]);
  }
  bf16x8 w2f[4];
  const int jj2 = wv * 16 + l15;
#pragma unroll
  for (int kc = 0; kc < 4; kc++)
    w2f[kc] = *(const bf16x8*)(wc + O_W2 + jj2 * 128 + kc * 32 + q * 8);
  const float b2v = b2f(wc[O_B2 + jj2]);
  float w3v[16];
#pragma unroll
  for (int i = 0; i < 16; i++) w3v[i] = b2f(wc[O_W3 + q * 16 + i]);
  const float b3f = b2f(wc[O_B3]);

  for (int t = blockIdx.x; t < NE / 64; t += gridDim.x) {
    __syncthreads();  // protect Ue/Hs/E2 from previous tile's reads
    const int pbase = t * 64;
    // stage Ue (edge_attr[eid] → bf16)
    if (tid < 64) {
      const int e = eidA[pbase + tid];
      if (f32) {
        const float4* ep = (const float4*)((const float*)ea + (size_t)e * 8);
        const float4 a = ep[0], b = ep[1];
        union { ushort4 v[2]; int4 i; } o;
        o.v[0].x = f2b(a.x); o.v[0].y = f2b(a.y); o.v[0].z = f2b(a.z); o.v[0].w = f2b(a.w);
        o.v[1].x = f2b(b.x); o.v[1].y = f2b(b.y); o.v[1].z = f2b(b.z); o.v[1].w = f2b(b.w);
        *(int4*)(Ue + tid * 64) = o.i;
      } else {
        *(int4*)(Ue + tid * 64) = *(const int4*)((const unsigned short*)ea + (size_t)e * 8);
      }
    }
    // stage Hs: 64 src rows, each fetched exactly once per block.
    // thread tid: row r=tid>>2, 64B segment seg=tid&3, as 4x16B batched loads.
    {
      const int r = tid >> 2, seg = tid & 3;
      const int s = csr[pbase + r];
      const unsigned short* gsrc = hb + (size_t)s * 128 + seg * 32;
      unsigned char* ldst = Hs + r * 272 + seg * 64;
      const int4 v0 = ((const int4*)gsrc)[0];
      const int4 v1 = ((const int4*)gsrc)[1];
      const int4 v2 = ((const int4*)gsrc)[2];
      const int4 v3 = ((const int4*)gsrc)[3];
      ((int4*)ldst)[0] = v0; ((int4*)ldst)[1] = v1;
      ((int4*)ldst)[2] = v2; ((int4*)ldst)[3] = v3;
    }
    // per-lane dst endpoints for rows mt*16+l15 (contiguous index loads)
    int didx[4];
#pragma unroll
    for (int mt = 0; mt < 4; mt++) didx[mt] = dstA[pbase + mt * 16 + l15];
    __syncthreads();  // Ue/Hs ready

    // GEMM1: e1[64][128]; src A-frags from LDS, dst direct, ea from Ue
    f32x4 acc1[4][2];
#pragma unroll
    for (int mt = 0; mt < 4; mt++)
#pragma unroll
      for (int nt = 0; nt < 2; nt++) acc1[mt][nt] = (f32x4)(0.0f);
#pragma unroll
    for (int cc = 0; cc < 4; cc++) {
#pragma unroll
      for (int mt = 0; mt < 4; mt++) {
        const bf16x8 a = *(const bf16x8*)(Hs + (mt * 16 + l15) * 272 + (cc * 32 + q * 8) * 2);
#pragma unroll
        for (int nt = 0; nt < 2; nt++)
          acc1[mt][nt] = __builtin_amdgcn_mfma_f32_16x16x32_bf16(a, w1f[nt][cc], acc1[mt][nt], 0, 0, 0);
      }
    }
#pragma unroll
    for (int cc = 4; cc < 8; cc++) {
#pragma unroll
      for (int mt = 0; mt < 4; mt++) {
        const bf16x8 a = *(const bf16x8*)(hb + (size_t)didx[mt] * 128 + (cc - 4) * 32 + q * 8);
#pragma unroll
        for (int nt = 0; nt < 2; nt++)
          acc1[mt][nt] = __builtin_amdgcn_mfma_f32_16x16x32_bf16(a, w1f[nt][cc], acc1[mt][nt], 0, 0, 0);
      }
    }
#pragma unroll
    for (int mt = 0; mt < 4; mt++) {
      const bf16x8 a = *(const bf16x8*)(Ue + (mt * 16 + l15) * 64 + q * 16);
#pragma unroll
      for (int nt = 0; nt < 2; nt++)
        acc1[mt][nt] = __builtin_amdgcn_mfma_f32_16x16x32_bf16(a, w1f[nt][8], acc1[mt][nt], 0, 0, 0);
    }
#pragma unroll
    for (int mt = 0; mt < 4; mt++)
#pragma unroll
      for (int nt = 0; nt < 2; nt++)
#pragma unroll
        for (int rg = 0; rg < 4; rg++) {
          const int er = mt * 16 + q * 4 + rg;
          const int jj = (wv * 2 + nt) * 16 + l15;
          *(unsigned short*)(E1 + er * 272 + jj * 2) =
              f2b(fmaxf(acc1[mt][nt][rg] + b1v[nt], 0.f));
        }
    __syncthreads();

    // GEMM2: e2[64][64], wave covers 16 cols, all 64 rows
    f32x4 acc2[4];
#pragma unroll
    for (int mt = 0; mt < 4; mt++) acc2[mt] = (f32x4)(0.0f);
#pragma unroll
    for (int kc = 0; kc < 4; kc++) {
#pragma unroll
      for (int mt = 0; mt < 4; mt++) {
        const bf16x8 a = *(const bf16x8*)(E1 + (mt * 16 + l15) * 272 + (kc * 32 + q * 8) * 2);
        acc2[mt] = __builtin_amdgcn_mfma_f32_16x16x32_bf16(a, w2f[kc], acc2[mt], 0, 0, 0);
      }
    }
#pragma unroll
    for (int mt = 0; mt < 4; mt++)
#pragma unroll
      for (int rg = 0; rg < 4; rg++) {
        const int er = mt * 16 + q * 4 + rg;
        *(unsigned short*)(E2 + er * 136 + jj2 * 2) =
            f2b(fmaxf(acc2[mt][rg] + b2v, 0.f));
      }
    __syncthreads();

    // GEMM3: logit per edge, dot-64 via 4 lane-groups + shuffle; scatter by eid
    const int el = wv * 16 + l15;
    float acc = 0.f;
#pragma unroll
    for (int i4 = 0; i4 < 4; i4++) {
      const bf16x4 v = *(const bf16x4*)(E2 + el * 136 + q * 32 + i4 * 8);
      acc += b2f((unsigned short)v[0]) * w3v[i4 * 4 + 0];
      acc += b2f((unsigned short)v[1]) * w3v[i4 * 4 + 1];
      acc += b2f((unsigned short)v[2]) * w3v[i4 * 4 + 2];
      acc += b2f((unsigned short)v[3]) * w3v[i4 * 4 + 3];
    }
    acc += __shfl_xor(acc, 16, 64);
    acc += __shfl_xor(acc, 32, 64);
    if (q == 0) {
      const int e = eidA[pbase + el];
      const float r = acc + b3f;
      if (f32) ((float*)out)[e] = r;
      else     ((unsigned short*)out)[e] = f2b(r);
    }
  }
}

extern "C" void kernel_launch(void* const* d_in, const int* in_sizes, int n_in,
                              void* d_out, int out_size, void* d_ws, size_t ws_size,
                              hipStream_t stream) {
  const void* x  = d_in[0];
  const int*  ei = (const int*)d_in[1];
  const void* ea = d_in[2];

  char* ws = (char*)d_ws;
  int*            flags  = (int*)(ws + WS_FLAGS);
  unsigned short* wc     = (unsigned short*)(ws + WS_WC);
  int*            cnt    = (int*)(ws + WS_CNT);
  int*            rowptr = (int*)(ws + WS_ROWP);
  int*            cursor = (int*)(ws + WS_CUR);
  int*            csr    = (int*)(ws + WS_CSR);
  int*            eidA   = (int*)(ws + WS_EID);
  int*            dstA   = (int*)(ws + WS_DST);
  unsigned short* W1p    = (unsigned short*)(ws + WS_W1P);
  unsigned short* hb0    = (unsigned short*)(ws + WS_HB0);
  unsigned short* hb1    = (unsigned short*)(ws + WS_HB1);

  if (ws_size < WS_NEED) {  // diagnostic: error ≈ 1.35 signals this path
    k_fallback<<<3125, 256, 0, stream>>>((unsigned short*)d_out);
    return;
  }

  k_probe<<<1, 64, 0, stream>>>((const unsigned short*)x, ei, flags);
  k_cvt_w<<<(W_TOTAL + 255) / 256, 256, 0, stream>>>(
      d_in[3], d_in[4], d_in[5], d_in[6], d_in[7], d_in[8], d_in[9],
      d_in[10], d_in[11], d_in[12], d_in[13], d_in[14], d_in[15], wc, flags);
  k_build_w1p<<<144, 256, 0, stream>>>(wc, W1p);

  hipMemsetAsync(cnt, 0, NN * sizeof(int), stream);
  hipMemsetAsync(cursor, 0, NN * sizeof(int), stream);
  k_hist<<<3125, 256, 0, stream>>>(ei, cnt, flags);
  k_scan<<<1, 1024, 0, stream>>>(cnt, rowptr);
  k_fill<<<3125, 256, 0, stream>>>(ei, rowptr, cursor, csr, eidA, dstA, flags);

  k_inproj<<<NN * 128 / 256, 256, 0, stream>>>(x, wc, hb0, flags);

  unsigned short* cur = hb0;
  unsigned short* nxt = hb1;
  for (int l = 0; l < 4; l++) {
    k_agg<<<12500, 256, 0, stream>>>(cur, csr, rowptr, nxt);
    k_sage_mfma<<<782, 256, 0, stream>>>(cur, nxt, wc, l);
    unsigned short* tmp = cur; cur = nxt; nxt = tmp;
  }
  // after 4 swaps, final h is back in hb0 (= cur)
  k_edge_mfma<<<3125, 256, 0, stream>>>(cur, csr, eidA, dstA, ea, W1p, wc, d_out, flags);
}

// Round 11
// 653.521 us; speedup vs baseline: 27.6874x; 1.0167x over previous
//
#include <hip/hip_runtime.h>
#include <stdint.h>

#define NN 50000
#define NE 800000

// canonical bf16 weight-block element offsets
#define O_WIN 0
#define O_BIN 2048
#define O_WL  2176
#define O_BL  67712
#define O_WR  68224
#define O_LNG 133760
#define O_LNB 134272
#define O_W1  134784
#define O_B1  168576
#define O_W2  168704
#define O_B2  176896
#define O_W3  176960
#define O_B3  177024
#define W_TOTAL 177025

// ws layout (bytes)
#define WS_FLAGS 0          //      256 B
#define WS_WC    512        //  354,050 B
#define WS_CNT   355072     //  200,000 B
#define WS_ROWP  555520     //  200,004 B
#define WS_CUR   756224     //  200,000 B
#define WS_CSR   956928     // 3,200,000 B (src per CSR slot)
#define WS_EID   4156928    // 3,200,000 B (edge id per CSR slot)
#define WS_DST   7356928    // 3,200,000 B (dst per CSR slot)
#define WS_W1P   10556928   //     73,728 B
#define WS_HB0   10630656   // 12,800,000 B
#define WS_HB1   23430656   // 12,800,000 B (layer ping-pong; eab after layers)
#define WS_NEED  36230656

typedef float f32x4 __attribute__((ext_vector_type(4)));
typedef short bf16x8 __attribute__((ext_vector_type(8)));
typedef short bf16x4 __attribute__((ext_vector_type(4)));

__device__ __forceinline__ float b2f(unsigned short u) {
  union { unsigned int i; float f; } v; v.i = ((unsigned int)u) << 16; return v.f;
}
__device__ __forceinline__ unsigned short f2b(float f) {
  union { float f; unsigned int i; } v; v.f = f;
  return (unsigned short)((v.i + 0x7fffu + ((v.i >> 16) & 1u)) >> 16);
}

// ---------------- fallback diagnostic: ws too small → constant 0.5 ----------
__global__ void k_fallback(unsigned short* __restrict__ out) {
  int gid = blockIdx.x * 256 + threadIdx.x;
  if (gid < NE) out[gid] = 0x3F00;
}

// ---------------- dtype probe: flags[0]=fp32 float tensors, flags[1]=int64 --
__global__ void k_probe(const unsigned short* __restrict__ x_u,
                        const int* __restrict__ ei32, int* __restrict__ flags) {
  const int t = threadIdx.x;  // 64 threads, 1 wave
  int insane = 0;
  for (int i = t; i < 512; i += 64) {
    float v = b2f(x_u[i]);
    if (!(fabsf(v) < 1e4f)) insane++;
  }
#pragma unroll
  for (int off = 1; off < 64; off <<= 1) insane += __shfl_xor(insane, off, 64);
  int nz = 0;
  for (int i = t; i < 128; i += 64) nz |= (ei32[2 * i + 1] != 0);
  unsigned long long m = __ballot(nz != 0);
  if (t == 0) {
    flags[0] = (insane >= 16) ? 1 : 0;
    flags[1] = (m == 0ULL) ? 1 : 0;
  }
}

// ---------------- canonicalize the 13 weight tensors to bf16 ----------------
__global__ void k_cvt_w(const void* W_in, const void* b_in, const void* Wl,
                        const void* bl, const void* Wr, const void* lng,
                        const void* lnb, const void* W1, const void* b1,
                        const void* W2, const void* b2, const void* W3,
                        const void* b3, unsigned short* __restrict__ wc,
                        const int* __restrict__ flags) {
  const int gid = blockIdx.x * 256 + threadIdx.x;
  if (gid >= W_TOTAL) return;
  const int f32 = flags[0];
  const void* src; int off;
  if      (gid < O_BIN) { src = W_in; off = gid - O_WIN; }
  else if (gid < O_WL)  { src = b_in; off = gid - O_BIN; }
  else if (gid < O_BL)  { src = Wl;   off = gid - O_WL;  }
  else if (gid < O_WR)  { src = bl;   off = gid - O_BL;  }
  else if (gid < O_LNG) { src = Wr;   off = gid - O_WR;  }
  else if (gid < O_LNB) { src = lng;  off = gid - O_LNG; }
  else if (gid < O_W1)  { src = lnb;  off = gid - O_LNB; }
  else if (gid < O_B1)  { src = W1;   off = gid - O_W1;  }
  else if (gid < O_W2)  { src = b1;   off = gid - O_B1;  }
  else if (gid < O_B2)  { src = W2;   off = gid - O_W2;  }
  else if (gid < O_W3)  { src = b2;   off = gid - O_B2;  }
  else if (gid < O_B3)  { src = W3;   off = gid - O_W3;  }
  else                  { src = b3;   off = 0;           }
  wc[gid] = f32 ? f2b(((const float*)src)[off]) : ((const unsigned short*)src)[off];
}

// ---------------- W1 padded copy: wc[128][264] -> W1p[128][288] -------------
__global__ void k_build_w1p(const unsigned short* __restrict__ wc,
                            unsigned short* __restrict__ W1p) {
  int gid = blockIdx.x * 256 + threadIdx.x;  // 128*288 = 36864
  if (gid >= 128 * 288) return;
  int j = gid / 288, k = gid - j * 288;
  W1p[gid] = (k < 264) ? wc[O_W1 + j * 264 + k] : (unsigned short)0;
}

// ---------------- ea → bf16, original edge order (sequential, coalesced) ----
// Hoists the per-edge fp32→bf16 convert out of the edge head: edge then does
// random 16B reads from a 12.8MB LLC-resident array instead of random 32B
// reads shredding 25.6MB of fp32 (25% line utilization → ~100MB HBM fetch).
__global__ void k_cvt_ea(const void* __restrict__ ea,
                         unsigned short* __restrict__ eab,
                         const int* __restrict__ flags) {
  const int gid = blockIdx.x * 256 + threadIdx.x;  // NE threads, 8 elems each
  if (gid >= NE) return;
  if (flags[0]) {
    const float4* ep = (const float4*)((const float*)ea + (size_t)gid * 8);
    const float4 a = ep[0], b = ep[1];
    union { ushort4 v[2]; int4 i; } o;
    o.v[0].x = f2b(a.x); o.v[0].y = f2b(a.y); o.v[0].z = f2b(a.z); o.v[0].w = f2b(a.w);
    o.v[1].x = f2b(b.x); o.v[1].y = f2b(b.y); o.v[1].z = f2b(b.z); o.v[1].w = f2b(b.w);
    *(int4*)(eab + (size_t)gid * 8) = o.i;
  } else {
    *(int4*)(eab + (size_t)gid * 8) =
        *(const int4*)((const unsigned short*)ea + (size_t)gid * 8);
  }
}

// ---------------- CSR build: histogram -> scan -> fill ----------------------
__global__ void k_hist(const int* __restrict__ ei, int* __restrict__ cnt,
                       const int* __restrict__ flags) {
  const int e = blockIdx.x * 256 + threadIdx.x;
  if (e >= NE) return;
  const int d = flags[1] ? ei[2 * (NE + e)] : ei[NE + e];
  atomicAdd(&cnt[d], 1);
}

__global__ __launch_bounds__(1024) void k_scan(const int* __restrict__ cnt,
                                               int* __restrict__ rowptr) {
  __shared__ int wsum[16];
  __shared__ int carry;
  const int t = threadIdx.x, wv = t >> 6, ln = t & 63;
  if (t == 0) carry = 0;
  __syncthreads();
  for (int base = 0; base < NN; base += 1024) {
    const int i = base + t;
    const int v = (i < NN) ? cnt[i] : 0;
    int x = v;
#pragma unroll
    for (int off = 1; off < 64; off <<= 1) {
      int y = __shfl_up(x, off, 64);
      if (ln >= off) x += y;
    }
    if (ln == 63) wsum[wv] = x;
    __syncthreads();
    if (t < 16) {
      int w = wsum[t];
#pragma unroll
      for (int off = 1; off < 16; off <<= 1) {
        int y = __shfl_up(w, off, 64);
        if (t >= off) w += y;
      }
      wsum[t] = w;
    }
    __syncthreads();
    const int woff = wv ? wsum[wv - 1] : 0;
    if (i < NN) rowptr[i] = carry + woff + x - v;
    const int total = wsum[15];
    __syncthreads();
    if (t == 0) carry += total;
    __syncthreads();
  }
  if (t == 0) rowptr[NN] = NE;
}

__global__ void k_fill(const int* __restrict__ ei, const int* __restrict__ rowptr,
                       int* __restrict__ cursor, int* __restrict__ csr,
                       int* __restrict__ eidA, int* __restrict__ dstA,
                       const int* __restrict__ flags) {
  const int e = blockIdx.x * 256 + threadIdx.x;
  if (e >= NE) return;
  const int i64 = flags[1];
  const int s = i64 ? ei[2 * e] : ei[e];
  const int d = i64 ? ei[2 * (NE + e)] : ei[NE + e];
  const int pos = rowptr[d] + atomicAdd(&cursor[d], 1);
  csr[pos] = s;
  eidA[pos] = e;
  dstA[pos] = d;
}

// ---------------- input projection: hb0 = bf16(x @ W_in^T + b_in) -----------
__global__ void k_inproj(const void* __restrict__ x,
                         const unsigned short* __restrict__ wc,
                         unsigned short* __restrict__ hb,
                         const int* __restrict__ flags) {
  const int gid = blockIdx.x * 256 + threadIdx.x;  // NN*128 threads
  const int n = gid >> 7, j = gid & 127;
  float xv[16];
  if (flags[0]) {
    const float4* xp = (const float4*)((const float*)x + (size_t)n * 16);
#pragma unroll
    for (int q = 0; q < 4; q++) {
      float4 t = xp[q];
      xv[q * 4 + 0] = t.x; xv[q * 4 + 1] = t.y; xv[q * 4 + 2] = t.z; xv[q * 4 + 3] = t.w;
    }
  } else {
    const unsigned short* xu = (const unsigned short*)x + (size_t)n * 16;
#pragma unroll
    for (int q = 0; q < 2; q++) {
      union { int4 v; unsigned short u[8]; } t;
      t.v = *(const int4*)(xu + q * 8);
#pragma unroll
      for (int i = 0; i < 8; i++) xv[q * 8 + i] = b2f(t.u[i]);
    }
  }
  float s = b2f(wc[O_BIN + j]);
  const unsigned short* wrow = wc + O_WIN + j * 16;
#pragma unroll
  for (int q = 0; q < 2; q++) {
    union { int4 v; unsigned short u[8]; } w;
    w.v = *(const int4*)(wrow + q * 8);
#pragma unroll
    for (int i = 0; i < 8; i++) s += b2f(w.u[i]) * xv[q * 8 + i];
  }
  hb[gid] = f2b(s);
}

// ---------------- aggregation: mean of neighbor rows, one wave per node -----
// fixed-point int64 accumulation (scale 2^24): exact integer sum is order-
// independent => bitwise-deterministic without sorting the CSR rows.
// 8-wide unroll for more outstanding row-loads (latency/LLC-bound).
__global__ __launch_bounds__(256) void k_agg(
    const unsigned short* __restrict__ hin, const int* __restrict__ csr,
    const int* __restrict__ rowptr, unsigned short* __restrict__ aggb) {
  const int tid = threadIdx.x;
  const int n = blockIdx.x * 4 + (tid >> 6);  // 12500 blocks * 4 waves
  const int L = tid & 63;
  const int rs = rowptr[n], re = rowptr[n + 1];
  const unsigned int* hw = (const unsigned int*)hin;
  long long t0 = 0, t1 = 0;
  int e = rs;
  for (; e + 8 <= re; e += 8) {
    unsigned int u[8];
#pragma unroll
    for (int k = 0; k < 8; k++) u[k] = hw[(size_t)csr[e + k] * 64 + L];
#pragma unroll
    for (int k = 0; k < 8; k++) {
      t0 += (int)(b2f((unsigned short)(u[k] & 0xffff)) * 16777216.0f);
      t1 += (int)(b2f((unsigned short)(u[k] >> 16)) * 16777216.0f);
    }
  }
  for (; e + 2 <= re; e += 2) {
    const unsigned int u0 = hw[(size_t)csr[e] * 64 + L];
    const unsigned int u1 = hw[(size_t)csr[e + 1] * 64 + L];
    t0 += (int)(b2f((unsigned short)(u0 & 0xffff)) * 16777216.0f);
    t1 += (int)(b2f((unsigned short)(u0 >> 16)) * 16777216.0f);
    t0 += (int)(b2f((unsigned short)(u1 & 0xffff)) * 16777216.0f);
    t1 += (int)(b2f((unsigned short)(u1 >> 16)) * 16777216.0f);
  }
  if (e < re) {
    const unsigned int u0 = hw[(size_t)csr[e] * 64 + L];
    t0 += (int)(b2f((unsigned short)(u0 & 0xffff)) * 16777216.0f);
    t1 += (int)(b2f((unsigned short)(u0 >> 16)) * 16777216.0f);
  }
  const int dg = re - rs;
  const float rd = (1.0f / 16777216.0f) / (float)(dg > 1 ? dg : 1);
  const float s0 = (float)t0 * rd;
  const float s1 = (float)t1 * rd;
  const unsigned int o = (unsigned int)f2b(s0) | ((unsigned int)f2b(s1) << 16);
  ((unsigned int*)aggb)[(size_t)n * 64 + L] = o;
}

// ---------------- SAGE layer: MFMA GEMM [agg|h] @ [Wl|Wr]^T + LN + ReLU -----
__global__ __launch_bounds__(256) void k_sage_mfma(
    const unsigned short* __restrict__ hin, unsigned short* __restrict__ hagg,
    const unsigned short* __restrict__ wc, int l) {
  __shared__ __align__(16) unsigned char As[64 * 528];  // 33792 B
  __shared__ float red1[64][4];
  __shared__ float red2[64][4];
  __shared__ float mr[64][2];
  const int tid = threadIdx.x;
  const int wv = tid >> 6;
  const int L = tid & 63;
  const int l15 = L & 15;
  const int q = L >> 4;
  const int n0 = blockIdx.x * 64;

  bf16x8 wf[2][8];
  float blv[2], gv[2], bv[2];
#pragma unroll
  for (int nt = 0; nt < 2; nt++) {
    const int jj = (wv * 2 + nt) * 16 + l15;
#pragma unroll
    for (int kc = 0; kc < 8; kc++) {
      const unsigned short* src = (kc < 4)
          ? wc + O_WL + ((size_t)l * 128 + jj) * 128 + kc * 32 + q * 8
          : wc + O_WR + ((size_t)l * 128 + jj) * 128 + (kc - 4) * 32 + q * 8;
      wf[nt][kc] = *(const bf16x8*)src;
    }
    blv[nt] = b2f(wc[O_BL + l * 128 + jj]);
    gv[nt]  = b2f(wc[O_LNG + l * 128 + jj]);
    bv[nt]  = b2f(wc[O_LNB + l * 128 + jj]);
  }

  for (int c = tid; c < 2048; c += 256) {
    const int row = c >> 5, part = c & 31;
    int node = n0 + row; if (node > NN - 1) node = NN - 1;
    const unsigned short* src = (part < 16)
        ? hagg + (size_t)node * 128 + part * 8
        : hin + (size_t)node * 128 + (part - 16) * 8;
    *(int4*)(As + row * 528 + part * 16) = *(const int4*)src;
  }
  __syncthreads();

  f32x4 acc[4][2];
#pragma unroll
  for (int mt = 0; mt < 4; mt++)
#pragma unroll
    for (int nt = 0; nt < 2; nt++) acc[mt][nt] = (f32x4)(0.0f);
#pragma unroll
  for (int kc = 0; kc < 8; kc++) {
#pragma unroll
    for (int mt = 0; mt < 4; mt++) {
      const bf16x8 a = *(const bf16x8*)(As + (mt * 16 + l15) * 528 + (kc * 32 + q * 8) * 2);
#pragma unroll
      for (int nt = 0; nt < 2; nt++)
        acc[mt][nt] = __builtin_amdgcn_mfma_f32_16x16x32_bf16(a, wf[nt][kc], acc[mt][nt], 0, 0, 0);
    }
  }
#pragma unroll
  for (int mt = 0; mt < 4; mt++) {
#pragma unroll
    for (int rg = 0; rg < 4; rg++) {
      acc[mt][0][rg] += blv[0];
      acc[mt][1][rg] += blv[1];
      float s = acc[mt][0][rg] + acc[mt][1][rg];
      float s2 = acc[mt][0][rg] * acc[mt][0][rg] + acc[mt][1][rg] * acc[mt][1][rg];
#pragma unroll
      for (int m = 1; m < 16; m <<= 1) {
        s += __shfl_xor(s, m, 64);
        s2 += __shfl_xor(s2, m, 64);
      }
      if (l15 == 0) {
        const int row = mt * 16 + q * 4 + rg;
        red1[row][wv] = s; red2[row][wv] = s2;
      }
    }
  }
  __syncthreads();
  if (tid < 64) {
    const float s1 = red1[tid][0] + red1[tid][1] + red1[tid][2] + red1[tid][3];
    const float s2 = red2[tid][0] + red2[tid][1] + red2[tid][2] + red2[tid][3];
    const float mu = s1 * 0.0078125f;
    const float var = s2 * 0.0078125f - mu * mu;
    mr[tid][0] = mu;
    mr[tid][1] = rsqrtf(var + 1e-5f);
  }
  __syncthreads();
#pragma unroll
  for (int mt = 0; mt < 4; mt++) {
#pragma unroll
    for (int rg = 0; rg < 4; rg++) {
      const int row = mt * 16 + q * 4 + rg;
      const int node = n0 + row;
      if (node < NN) {
        const float mu = mr[row][0], rstd = mr[row][1];
#pragma unroll
        for (int nt = 0; nt < 2; nt++) {
          const float o = (acc[mt][nt][rg] - mu) * rstd * gv[nt] + bv[nt];
          hagg[(size_t)node * 128 + (wv * 2 + nt) * 16 + l15] = f2b(fmaxf(o, 0.f));
        }
      }
    }
  }
}

// ---------------- edge head: dst-grouped tiles + LDS-staged src MFMA MLP ----
// Src rows staged to LDS once per block; dst direct (dst-grouped, L1-hot);
// edge_attr from the pre-converted bf16 eab (12.8MB, LLC-resident random 16B).
// LDS: Ue 4096 | Hs 17408 | E1 17408 | E2 8704 = 47616 B.
__global__ __launch_bounds__(256) void k_edge_mfma(
    const unsigned short* __restrict__ hb, const int* __restrict__ csr,
    const int* __restrict__ eidA, const int* __restrict__ dstA,
    const unsigned short* __restrict__ eab, const unsigned short* __restrict__ W1p,
    const unsigned short* __restrict__ wc, void* __restrict__ out,
    const int* __restrict__ flags) {
  __shared__ __align__(16) unsigned char sm[47616];
  unsigned char* const Ue = sm;            // [64][64B]
  unsigned char* const Hs = sm + 4096;     // [64][272B]
  unsigned char* const E1 = sm + 21504;    // [64][272B]
  unsigned char* const E2 = sm + 38912;    // [64][136B]
  const int tid = threadIdx.x;
  const int wv = tid >> 6;
  const int L = tid & 63;
  const int l15 = L & 15;
  const int q = L >> 4;
  const int f32 = flags[0];

  // zero the K-padding region of Ue (bytes 16..63 of each 64B row), once
  for (int i = tid; i < 64 * 12; i += 256)
    *(int*)(Ue + (i / 12) * 64 + 16 + (i % 12) * 4) = 0;

  bf16x8 w1f[2][9];
  float b1v[2];
#pragma unroll
  for (int nt = 0; nt < 2; nt++) {
    const int jj = (wv * 2 + nt) * 16 + l15;
#pragma unroll
    for (int cc = 0; cc < 9; cc++)
      w1f[nt][cc] = *(const bf16x8*)(W1p + jj * 288 + cc * 32 + q * 8);
    b1v[nt] = b2f(wc[O_B1 + jj]);
  }
  bf16x8 w2f[4];
  const int jj2 = wv * 16 + l15;
#pragma unroll
  for (int kc = 0; kc < 4; kc++)
    w2f[kc] = *(const bf16x8*)(wc + O_W2 + jj2 * 128 + kc * 32 + q * 8);
  const float b2v = b2f(wc[O_B2 + jj2]);
  float w3v[16];
#pragma unroll
  for (int i = 0; i < 16; i++) w3v[i] = b2f(wc[O_W3 + q * 16 + i]);
  const float b3f = b2f(wc[O_B3]);

  for (int t = blockIdx.x; t < NE / 64; t += gridDim.x) {
    __syncthreads();  // protect Ue/Hs/E2 from previous tile's reads
    const int pbase = t * 64;
    // stage Ue (eab[eid], 16B random from LLC-resident bf16 array)
    if (tid < 64) {
      const int e = eidA[pbase + tid];
      *(int4*)(Ue + tid * 64) = *(const int4*)(eab + (size_t)e * 8);
    }
    // stage Hs: 64 src rows, each fetched exactly once per block.
    {
      const int r = tid >> 2, seg = tid & 3;
      const int s = csr[pbase + r];
      const unsigned short* gsrc = hb + (size_t)s * 128 + seg * 32;
      unsigned char* ldst = Hs + r * 272 + seg * 64;
      const int4 v0 = ((const int4*)gsrc)[0];
      const int4 v1 = ((const int4*)gsrc)[1];
      const int4 v2 = ((const int4*)gsrc)[2];
      const int4 v3 = ((const int4*)gsrc)[3];
      ((int4*)ldst)[0] = v0; ((int4*)ldst)[1] = v1;
      ((int4*)ldst)[2] = v2; ((int4*)ldst)[3] = v3;
    }
    // per-lane dst endpoints for rows mt*16+l15 (contiguous index loads)
    int didx[4];
#pragma unroll
    for (int mt = 0; mt < 4; mt++) didx[mt] = dstA[pbase + mt * 16 + l15];
    __syncthreads();  // Ue/Hs ready

    // GEMM1: e1[64][128]; src A-frags from LDS, dst direct, ea from Ue
    f32x4 acc1[4][2];
#pragma unroll
    for (int mt = 0; mt < 4; mt++)
#pragma unroll
      for (int nt = 0; nt < 2; nt++) acc1[mt][nt] = (f32x4)(0.0f);
#pragma unroll
    for (int cc = 0; cc < 4; cc++) {
#pragma unroll
      for (int mt = 0; mt < 4; mt++) {
        const bf16x8 a = *(const bf16x8*)(Hs + (mt * 16 + l15) * 272 + (cc * 32 + q * 8) * 2);
#pragma unroll
        for (int nt = 0; nt < 2; nt++)
          acc1[mt][nt] = __builtin_amdgcn_mfma_f32_16x16x32_bf16(a, w1f[nt][cc], acc1[mt][nt], 0, 0, 0);
      }
    }
#pragma unroll
    for (int cc = 4; cc < 8; cc++) {
#pragma unroll
      for (int mt = 0; mt < 4; mt++) {
        const bf16x8 a = *(const bf16x8*)(hb + (size_t)didx[mt] * 128 + (cc - 4) * 32 + q * 8);
#pragma unroll
        for (int nt = 0; nt < 2; nt++)
          acc1[mt][nt] = __builtin_amdgcn_mfma_f32_16x16x32_bf16(a, w1f[nt][cc], acc1[mt][nt], 0, 0, 0);
      }
    }
#pragma unroll
    for (int mt = 0; mt < 4; mt++) {
      const bf16x8 a = *(const bf16x8*)(Ue + (mt * 16 + l15) * 64 + q * 16);
#pragma unroll
      for (int nt = 0; nt < 2; nt++)
        acc1[mt][nt] = __builtin_amdgcn_mfma_f32_16x16x32_bf16(a, w1f[nt][8], acc1[mt][nt], 0, 0, 0);
    }
#pragma unroll
    for (int mt = 0; mt < 4; mt++)
#pragma unroll
      for (int nt = 0; nt < 2; nt++)
#pragma unroll
        for (int rg = 0; rg < 4; rg++) {
          const int er = mt * 16 + q * 4 + rg;
          const int jj = (wv * 2 + nt) * 16 + l15;
          *(unsigned short*)(E1 + er * 272 + jj * 2) =
              f2b(fmaxf(acc1[mt][nt][rg] + b1v[nt], 0.f));
        }
    __syncthreads();

    // GEMM2: e2[64][64], wave covers 16 cols, all 64 rows
    f32x4 acc2[4];
#pragma unroll
    for (int mt = 0; mt < 4; mt++) acc2[mt] = (f32x4)(0.0f);
#pragma unroll
    for (int kc = 0; kc < 4; kc++) {
#pragma unroll
      for (int mt = 0; mt < 4; mt++) {
        const bf16x8 a = *(const bf16x8*)(E1 + (mt * 16 + l15) * 272 + (kc * 32 + q * 8) * 2);
        acc2[mt] = __builtin_amdgcn_mfma_f32_16x16x32_bf16(a, w2f[kc], acc2[mt], 0, 0, 0);
      }
    }
#pragma unroll
    for (int mt = 0; mt < 4; mt++)
#pragma unroll
      for (int rg = 0; rg < 4; rg++) {
        const int er = mt * 16 + q * 4 + rg;
        *(unsigned short*)(E2 + er * 136 + jj2 * 2) =
            f2b(fmaxf(acc2[mt][rg] + b2v, 0.f));
      }
    __syncthreads();

    // GEMM3: logit per edge, dot-64 via 4 lane-groups + shuffle; scatter by eid
    const int el = wv * 16 + l15;
    float acc = 0.f;
#pragma unroll
    for (int i4 = 0; i4 < 4; i4++) {
      const bf16x4 v = *(const bf16x4*)(E2 + el * 136 + q * 32 + i4 * 8);
      acc += b2f((unsigned short)v[0]) * w3v[i4 * 4 + 0];
      acc += b2f((unsigned short)v[1]) * w3v[i4 * 4 + 1];
      acc += b2f((unsigned short)v[2]) * w3v[i4 * 4 + 2];
      acc += b2f((unsigned short)v[3]) * w3v[i4 * 4 + 3];
    }
    acc += __shfl_xor(acc, 16, 64);
    acc += __shfl_xor(acc, 32, 64);
    if (q == 0) {
      const int e = eidA[pbase + el];
      const float r = acc + b3f;
      if (f32) ((float*)out)[e] = r;
      else     ((unsigned short*)out)[e] = f2b(r);
    }
  }
}

extern "C" void kernel_launch(void* const* d_in, const int* in_sizes, int n_in,
                              void* d_out, int out_size, void* d_ws, size_t ws_size,
                              hipStream_t stream) {
  const void* x  = d_in[0];
  const int*  ei = (const int*)d_in[1];
  const void* ea = d_in[2];

  char* ws = (char*)d_ws;
  int*            flags  = (int*)(ws + WS_FLAGS);
  unsigned short* wc     = (unsigned short*)(ws + WS_WC);
  int*            cnt    = (int*)(ws + WS_CNT);
  int*            rowptr = (int*)(ws + WS_ROWP);
  int*            cursor = (int*)(ws + WS_CUR);
  int*            csr    = (int*)(ws + WS_CSR);
  int*            eidA   = (int*)(ws + WS_EID);
  int*            dstA   = (int*)(ws + WS_DST);
  unsigned short* W1p    = (unsigned short*)(ws + WS_W1P);
  unsigned short* hb0    = (unsigned short*)(ws + WS_HB0);
  unsigned short* hb1    = (unsigned short*)(ws + WS_HB1);

  if (ws_size < WS_NEED) {  // diagnostic: error ≈ 1.35 signals this path
    k_fallback<<<3125, 256, 0, stream>>>((unsigned short*)d_out);
    return;
  }

  k_probe<<<1, 64, 0, stream>>>((const unsigned short*)x, ei, flags);
  k_cvt_w<<<(W_TOTAL + 255) / 256, 256, 0, stream>>>(
      d_in[3], d_in[4], d_in[5], d_in[6], d_in[7], d_in[8], d_in[9],
      d_in[10], d_in[11], d_in[12], d_in[13], d_in[14], d_in[15], wc, flags);
  k_build_w1p<<<144, 256, 0, stream>>>(wc, W1p);

  hipMemsetAsync(cnt, 0, NN * sizeof(int), stream);
  hipMemsetAsync(cursor, 0, NN * sizeof(int), stream);
  k_hist<<<3125, 256, 0, stream>>>(ei, cnt, flags);
  k_scan<<<1, 1024, 0, stream>>>(cnt, rowptr);
  k_fill<<<3125, 256, 0, stream>>>(ei, rowptr, cursor, csr, eidA, dstA, flags);

  k_inproj<<<NN * 128 / 256, 256, 0, stream>>>(x, wc, hb0, flags);

  unsigned short* cur = hb0;
  unsigned short* nxt = hb1;
  for (int l = 0; l < 4; l++) {
    k_agg<<<12500, 256, 0, stream>>>(cur, csr, rowptr, nxt);
    k_sage_mfma<<<782, 256, 0, stream>>>(cur, nxt, wc, l);
    unsigned short* tmp = cur; cur = nxt; nxt = tmp;
  }
  // after 4 swaps, final h is in hb0 (= cur); hb1 (= nxt) is free → reuse as eab
  unsigned short* eab = nxt;
  k_cvt_ea<<<3125, 256, 0, stream>>>(ea, eab, flags);
  k_edge_mfma<<<3125, 256, 0, stream>>>(cur, csr, eidA, dstA, eab, W1p, wc, d_out, flags);
}